// Round 1
// baseline (582.509 us; speedup 1.0000x reference)
//
#include <hip/hip_runtime.h>
#include <math.h>

#define PI_F 3.14159265358979323846f
#define TWO_PI_F 6.28318530717958647692f

// problem sizes
constexpr int Bn = 32, Cn = 64, On = 64, Hn = 128, Wn = 128;
constexpr int KT_LD = 132;   // Ktab row stride (floats), 16B-aligned rows

// workspace float offsets
constexpr size_t WSO_KTAB  = 0;                        // 40*132 = 5280
constexpr size_t WSO_CFTH  = 5280;                     // 128*8  = 1024
constexpr size_t WSO_FLAT  = 6304;                     // 32*2048 = 65536
constexpr size_t WSO_CORR  = 71840;                    // 32*64 = 2048
constexpr size_t WSO_BIG   = 81920;
constexpr size_t SZ_QTR    = (size_t)2097152;          // 2M floats
constexpr size_t WSO_CFT1  = WSO_BIG;                  // [2048][128][8]
constexpr size_t WSO_XF    = WSO_BIG + SZ_QTR;         // [32][64][32][16][2]
constexpr size_t WSO_Y     = WSO_BIG;                  // alias: cft1+xf dead by stage D
constexpr size_t WSO_OUTFT = WSO_BIG + 4 * SZ_QTR;     // [32][64][32][16][2]
// total ws floats = 81920 + 4*2097152 + 2097152 = 10,567,680  (~42.3 MB)

__device__ __forceinline__ float tcoordf(int i) { return (float)i * (1.0f / 127.0f); }

// ---------------- tables: CFT gather matrices + DFT twiddle rows ----------------
__global__ void k_tables(float* __restrict__ ws) {
  float* Ktab = ws + WSO_KTAB;
  float* cftH = ws + WSO_CFTH;
  int t = threadIdx.x;

  // CFT columns: oid = (pass, w, f)
  for (int oid = t; oid < 2 * 128 * 4; oid += 256) {
    int p = oid >> 9;
    int rem = oid & 511;
    int w = rem >> 2, f = rem & 3;
    float fval;
    if (p == 0) fval = (float)f;                       // W pass: fw = [0,1,2,3]
    else fval = (f == 0) ? 0.f : (f == 1) ? 1.f : (f == 2) ? -2.f : -1.f; // H pass fsel
    float accR = 0.f, accI = 0.f;
    float wp = fval * (TWO_PI_F * 0.125f);
    for (int l = 0; l < 4; l++) {
      float start = 0.25f * (float)l;
      for (int m = 0; m < 8; m++) {
        float node_m = -cosf((2.f * m + 1.f) * PI_F / 16.f);
        float tseg = start + 0.125f * (node_m + 1.0f);
        int ri = (int)(tseg * 127.0f) - 2; if (ri < 0) ri = 0;
        while (ri < 127 && tcoordf(ri) < tseg) ri++;
        int le = ri - 1; if (le < 0) le = 0;
        if (le != w && ri != w) continue;
        float tl = tcoordf(le), tr = tcoordf(ri);
        float den = (tr - tl < 1e-8f) ? 1.0f : (tr - tl);
        float wrv = (tseg - tl) / den;
        float wlv = 1.0f - wrv;
        // quadrature weights Wr/Wi for node index m, frequency f
        float Wr = 0.f, Wi = 0.f;
        for (int mm = 0; mm < 8; mm++) {
          float nmm = -cosf((2.f * mm + 1.f) * PI_F / 16.f);
          float Tk = cosf((float)m * acosf(nmm));
          float ang = nmm * wp;
          Wr += Tk * cosf(ang);
          Wi += Tk * (-sinf(ang));
        }
        Wr *= 0.125f; Wi *= 0.125f;
        float ph = -TWO_PI_F * start * fval;
        float cr = cosf(ph), ci = sinf(ph);
        float coefR = Wr * cr - Wi * ci;
        float coefI = Wr * ci + Wi * cr;
        float wgt = 0.f;
        if (le == w) wgt += wlv;
        if (ri == w) wgt += wrv;
        accR += wgt * coefR;
        accI += wgt * coefI;
      }
    }
    if (p == 0) { Ktab[(32 + f) * KT_LD + w] = accR; Ktab[(36 + f) * KT_LD + w] = accI; }
    else        { cftH[w * 8 + f] = accR;            cftH[w * 8 + 4 + f] = accI; }
  }

  // DFT rows: out 2*kx+{0,1} : cos / -sin of 2*pi*kx*w/128
  for (int oid = t; oid < 32 * 128; oid += 256) {
    int out = oid >> 7, w = oid & 127;
    int kx = out >> 1;
    int r = (kx * w) & 127;
    float ang = TWO_PI_F * (float)r * (1.0f / 128.0f);
    Ktab[out * KT_LD + w] = (out & 1) ? (-sinf(ang)) : cosf(ang);
  }
}

// ---------------- stage A: row DFT (16 kx modes) + CFT W-pass, fused ----------------
// grid 4096: 64 rows/block of the [B*C*H, 128] row matrix. K via wave-uniform scalar loads.
__global__ __launch_bounds__(256) void k_stageA(const float* __restrict__ x,
                                                const float* __restrict__ Ktab,
                                                float* __restrict__ xw,
                                                float* __restrict__ cft1) {
  __shared__ float tile[64 * 129];
  int t = threadIdx.x;
  const float* xblk = x + (size_t)blockIdx.x * 64 * 128;
  #pragma unroll
  for (int k2 = 0; k2 < 8; k2++) {
    int f4 = t + k2 * 256;             // 2048 float4
    int row = f4 >> 5, c4 = f4 & 31;
    const float4 v = *reinterpret_cast<const float4*>(xblk + row * 128 + c4 * 4);
    float* dst = &tile[row * 129 + c4 * 4];
    dst[0] = v.x; dst[1] = v.y; dst[2] = v.z; dst[3] = v.w;
  }
  __syncthreads();

  int p = t & 63;
  int gu = __builtin_amdgcn_readfirstlane(t >> 6);   // wave-uniform out-group 0..3
  const float* Kb = Ktab + (size_t)gu * 10 * KT_LD;
  float acc[10];
  #pragma unroll
  for (int i = 0; i < 10; i++) acc[i] = 0.f;
  const float* r0 = &tile[p * 129];
  #pragma unroll 4
  for (int w = 0; w < 128; w++) {
    float s0 = r0[w];
    #pragma unroll
    for (int i = 0; i < 10; i++) acc[i] = fmaf(s0, Kb[i * KT_LD + w], acc[i]);
  }

  int bc = blockIdx.x >> 1;
  int h = ((blockIdx.x & 1) << 6) + p;
  #pragma unroll
  for (int i = 0; i < 10; i++) {
    int j = gu * 10 + i;
    if (j < 32) {
      int kx = j >> 1, ri = j & 1;
      xw[(((size_t)bc * 128 + h) * 16 + kx) * 2 + ri] = acc[i];
    } else {
      cft1[((size_t)bc * 128 + h) * 8 + (j - 32)] = acc[i];
    }
  }
}

// ---------------- stage B: forward DFT over h (32 ky modes) via phasor rotation ----------------
__global__ __launch_bounds__(256) void k_stageB(const float* __restrict__ xw,
                                                float* __restrict__ xf) {
  int t = threadIdx.x;
  int bc = blockIdx.x;
  int kx = t & 15, jg = t >> 4;        // jg 0..15, j = jg*2+q
  float pr[2], pq[2], sr[2], si[2], aR[2], aI[2];
  #pragma unroll
  for (int q = 0; q < 2; q++) {
    int j = jg * 2 + q;
    int ky = (j < 16) ? j : j + 96;
    float ang = TWO_PI_F * (float)ky * (1.0f / 128.0f);
    sr[q] = cosf(ang); si[q] = -sinf(ang);   // e^{-2pi i ky/128}
    pr[q] = 1.f; pq[q] = 0.f; aR[q] = 0.f; aI[q] = 0.f;
  }
  const float* base = xw + (size_t)bc * 128 * 32 + kx * 2;
  for (int h = 0; h < 128; h++) {
    const float2 v = *reinterpret_cast<const float2*>(base + h * 32);
    #pragma unroll
    for (int q = 0; q < 2; q++) {
      aR[q] = fmaf(v.x, pr[q], fmaf(-v.y, pq[q], aR[q]));
      aI[q] = fmaf(v.x, pq[q], fmaf(v.y, pr[q], aI[q]));
      float npr = pr[q] * sr[q] - pq[q] * si[q];
      float npi = pr[q] * si[q] + pq[q] * sr[q];
      pr[q] = npr; pq[q] = npi;
    }
  }
  #pragma unroll
  for (int q = 0; q < 2; q++) {
    int j = jg * 2 + q;
    float2* o = reinterpret_cast<float2*>(xf + (((size_t)bc * 32 + j) * 16 + kx) * 2);
    *o = make_float2(aR[q], aI[q]);
  }
}

// ---------------- CFT H-pass: cft1 -> flat ----------------
__global__ void k_cfth(const float* __restrict__ cft1, const float* __restrict__ cftH,
                       float* __restrict__ flat) {
  int t = threadIdx.x;
  int bc = blockIdx.x * 2 + (t >> 5);
  int tt = t & 31;
  int f1 = tt >> 3, f2 = (tt >> 1) & 3, ri = tt & 1;
  const float* s = cft1 + (size_t)bc * 1024;
  float acc = 0.f;
  for (int h = 0; h < 128; h++) {
    float r = s[h * 8 + f2], im = s[h * 8 + 4 + f2];
    float kr = cftH[h * 8 + f1], ki = cftH[h * 8 + 4 + f1];
    float e0 = (ri == 0) ? kr : ki;
    float e1 = (ri == 0) ? -ki : kr;
    acc = fmaf(r, e0, fmaf(im, e1, acc));
  }
  int b = bc >> 6, c = bc & 63;
  flat[(size_t)b * 2048 + ((c * 4 + f1) * 4 + f2) * 2 + ri] = acc;
}

// ---------------- MLP: flat -> corr (exact-erf GELU) ----------------
__global__ __launch_bounds__(256) void k_mlp(const float* __restrict__ flat,
                                             const float* __restrict__ w1,
                                             const float* __restrict__ b1,
                                             const float* __restrict__ w2,
                                             const float* __restrict__ b2,
                                             float* __restrict__ corr) {
  __shared__ float fs[2048];
  __shared__ float hs[256];
  int b = blockIdx.x, t = threadIdx.x;
  #pragma unroll
  for (int k = 0; k < 8; k++) fs[t + k * 256] = flat[(size_t)b * 2048 + t + k * 256];
  __syncthreads();
  float acc = b1[t];
  for (int k = 0; k < 2048; k++) acc = fmaf(fs[k], w1[(size_t)k * 256 + t], acc);
  float ge = 0.5f * acc * (1.0f + erff(acc * 0.70710678118654752f));
  hs[t] = ge;
  __syncthreads();
  if (t < 64) {
    float a2 = b2[t];
    for (int k = 0; k < 256; k++) a2 = fmaf(hs[k], w2[(size_t)k * 64 + t], a2);
    corr[(size_t)b * 64 + t] = a2;
  }
}

// ---------------- stage C: mode-mixing einsum over C ----------------
// grid 1024 = (j, b) with XCD-chunk swizzle so same-j blocks share an XCD's L2 W-slice.
__global__ __launch_bounds__(256) void k_stageC(const float* __restrict__ xf,
                                                const float* __restrict__ w1,
                                                const float* __restrict__ w2,
                                                float* __restrict__ outft) {
  __shared__ float xfs[64 * 32];       // [c][kx*2+ri]
  int bid = blockIdx.x;
  int sw = (bid & 7) * 128 + (bid >> 3);   // bijective (1024 % 8 == 0)
  int j = sw >> 5, b = sw & 31;
  int t = threadIdx.x;
  #pragma unroll
  for (int k2 = 0; k2 < 4; k2++) {
    int id = t + k2 * 256;             // 1024 float2
    int c = id >> 4, kxi = id & 15;
    const float2 v = *reinterpret_cast<const float2*>(
        xf + (((size_t)b * 64 + c) * 32 + j) * 32 + kxi * 2);
    reinterpret_cast<float2*>(xfs)[id] = v;
  }
  __syncthreads();
  int kx = t & 15, og = t >> 4;
  const float* wsel = (j < 16) ? w1 : w2;
  int jr = (j < 16) ? j : j - 16;
  float aR[4], aI[4];
  #pragma unroll
  for (int i = 0; i < 4; i++) { aR[i] = 0.f; aI[i] = 0.f; }
  for (int c = 0; c < 64; c++) {
    float xr = xfs[c * 32 + kx * 2], xi = xfs[c * 32 + kx * 2 + 1];
    #pragma unroll
    for (int i = 0; i < 4; i++) {
      int o = og * 4 + i;
      const float2 wv = *reinterpret_cast<const float2*>(
          wsel + ((((size_t)c * 64 + o) * 16 + jr) * 16 + kx) * 2);
      aR[i] = fmaf(xr, wv.x, fmaf(-xi, wv.y, aR[i]));
      aI[i] = fmaf(xr, wv.y, fmaf(xi, wv.x, aI[i]));
    }
  }
  #pragma unroll
  for (int i = 0; i < 4; i++) {
    int o = og * 4 + i;
    float2* dst = reinterpret_cast<float2*>(outft + (((size_t)b * 64 + o) * 32 + j) * 32 + kx * 2);
    *dst = make_float2(aR[i], aI[i]);
  }
}

// ---------------- stage D: inverse DFT over ky (32 modes -> 128 h), 1/H folded ----------------
__global__ __launch_bounds__(256) void k_stageD(const float* __restrict__ outft,
                                                float* __restrict__ y) {
  int bo = blockIdx.x;
  int t = threadIdx.x;
  int kx = t & 15, hg = t >> 4;
  int h0 = hg * 8;
  float aR[8], aI[8];
  #pragma unroll
  for (int k = 0; k < 8; k++) { aR[k] = 0.f; aI[k] = 0.f; }
  const float* src = outft + (size_t)bo * 1024 + kx * 2;
  for (int jj = 0; jj < 32; jj++) {
    const float2 c = *reinterpret_cast<const float2*>(src + jj * 32);
    int ky = (jj < 16) ? jj : jj + 96;
    int r0 = (ky * h0) & 127;
    float angb = TWO_PI_F * (1.0f / 128.0f) * (float)r0;
    float br = cosf(angb), bi = sinf(angb);     // e^{+2pi i ky h0/128}
    float angs = TWO_PI_F * (1.0f / 128.0f) * (float)(ky & 127);
    float strr = cosf(angs), sti = sinf(angs);  // e^{+2pi i ky/128}
    #pragma unroll
    for (int k = 0; k < 8; k++) {
      aR[k] = fmaf(c.x, br, fmaf(-c.y, bi, aR[k]));
      aI[k] = fmaf(c.x, bi, fmaf(c.y, br, aI[k]));
      float nbr = br * strr - bi * sti;
      float nbi = br * sti + bi * strr;
      br = nbr; bi = nbi;
    }
  }
  float* dst = y + ((size_t)bo * 128 + h0) * 32 + kx * 2;
  #pragma unroll
  for (int k = 0; k < 8; k++) {
    *reinterpret_cast<float2*>(dst + k * 32) =
        make_float2(aR[k] * 0.0078125f, aI[k] * 0.0078125f);
  }
}

// ---------------- stage E: inverse rfft over w (c2r: Im(DC) dropped) + corr ----------------
__global__ __launch_bounds__(256) void k_stageE(const float* __restrict__ y,
                                                const float* __restrict__ corr,
                                                float* __restrict__ out) {
  int bo = blockIdx.x;
  int t = threadIdx.x;
  int w = t & 127, hh = t >> 7;
  float cph[16], sph[16];
  #pragma unroll
  for (int kx = 0; kx < 16; kx++) {
    int r = (kx * w) & 127;
    float ang = TWO_PI_F * (1.0f / 128.0f) * (float)r;
    cph[kx] = cosf(ang); sph[kx] = sinf(ang);
  }
  float corrv = corr[bo];
  const float* ybase = y + (size_t)bo * 128 * 32;
  float* obase = out + (size_t)bo * 128 * 128;
  for (int k = 0; k < 64; k++) {
    int h = 2 * k + hh;                 // wave-uniform h -> scalar y loads
    const float* yr = ybase + h * 32;
    float acc = yr[0];                  // DC: real part only (c2r semantics)
    #pragma unroll
    for (int kx = 1; kx < 16; kx++) {
      float a = 2.0f * yr[kx * 2];
      float bim = 2.0f * yr[kx * 2 + 1];
      acc = fmaf(a, cph[kx], acc);
      acc = fmaf(-bim, sph[kx], acc);
    }
    obase[h * 128 + w] = acc * 0.0078125f + corrv;
  }
}

extern "C" void kernel_launch(void* const* d_in, const int* in_sizes, int n_in,
                              void* d_out, int out_size, void* d_ws, size_t ws_size,
                              hipStream_t stream) {
  const float* x   = (const float*)d_in[0];
  const float* w1  = (const float*)d_in[1];
  const float* w2  = (const float*)d_in[2];
  const float* l1w = (const float*)d_in[3];
  const float* l1b = (const float*)d_in[4];
  const float* l2w = (const float*)d_in[5];
  const float* l2b = (const float*)d_in[6];
  float* out = (float*)d_out;
  float* ws  = (float*)d_ws;

  float* Ktab  = ws + WSO_KTAB;
  float* cftH  = ws + WSO_CFTH;
  float* flat  = ws + WSO_FLAT;
  float* corr  = ws + WSO_CORR;
  float* cft1  = ws + WSO_CFT1;
  float* xf    = ws + WSO_XF;
  float* y     = ws + WSO_Y;
  float* outft = ws + WSO_OUTFT;
  float* xw    = out;   // d_out used as scratch for xw; fully rewritten by stage E

  k_tables<<<dim3(1), dim3(256), 0, stream>>>(ws);
  k_stageA<<<dim3(4096), dim3(256), 0, stream>>>(x, Ktab, xw, cft1);
  k_stageB<<<dim3(2048), dim3(256), 0, stream>>>(xw, xf);
  k_cfth<<<dim3(1024), dim3(64), 0, stream>>>(cft1, cftH, flat);
  k_mlp<<<dim3(32), dim3(256), 0, stream>>>(flat, l1w, l1b, l2w, l2b, corr);
  k_stageC<<<dim3(1024), dim3(256), 0, stream>>>(xf, w1, w2, outft);
  k_stageD<<<dim3(2048), dim3(256), 0, stream>>>(outft, y);
  k_stageE<<<dim3(2048), dim3(256), 0, stream>>>(y, corr, out);
}

// Round 2
// 482.499 us; speedup vs baseline: 1.2073x; 1.2073x over previous
//
#include <hip/hip_runtime.h>
#include <math.h>

#define PI_F 3.14159265358979323846f
#define TWO_PI_F 6.28318530717958647692f

// problem sizes
constexpr int Bn = 32, Cn = 64, On = 64, Hn = 128, Wn = 128;
constexpr int KT_LD = 132;   // Ktab row stride (floats), 16B-aligned rows

// workspace float offsets
constexpr size_t WSO_KTAB  = 0;                        // 40*132 = 5280
constexpr size_t WSO_CFTH  = 5280;                     // 128*8  = 1024
constexpr size_t WSO_FLAT  = 6304;                     // 32*2048 = 65536
constexpr size_t WSO_CORR  = 71840;                    // 32*64 = 2048
constexpr size_t WSO_BIG   = 81920;
constexpr size_t SZ_QTR    = (size_t)2097152;          // 2M floats
constexpr size_t WSO_CFT1  = WSO_BIG;                  // [2048][128][8]
constexpr size_t WSO_XF    = WSO_BIG + SZ_QTR;         // [32][64][32][16][2]
constexpr size_t WSO_Y     = WSO_BIG;                  // alias: cft1+xf dead by stage D
constexpr size_t WSO_OUTFT = WSO_BIG + 4 * SZ_QTR;     // [32][64][32][16][2]

__device__ __forceinline__ float tcoordf(int i) { return (float)i * (1.0f / 127.0f); }

// ---------------- tables: CFT gather matrices + DFT twiddle rows ----------------
// Restructured: quadrature weights (p,f,m) and segment phases (p,f,l) computed
// ONCE into LDS (they don't depend on w), then the 1024-output gather loop is
// transcendental-free. DFT rows via hardware __sincosf.
__global__ void k_tables(float* __restrict__ ws) {
  float* Ktab = ws + WSO_KTAB;
  float* cftH = ws + WSO_CFTH;
  int t = threadIdx.x;

  __shared__ float sNodes[8];
  __shared__ float sWr[2][4][8], sWi[2][4][8];   // [pass][f][m]
  __shared__ float sCr[2][4][4], sCi[2][4][4];   // [pass][f][l]

  if (t < 8) sNodes[t] = -cosf((2.f * (float)t + 1.f) * PI_F / 16.f);
  __syncthreads();

  if (t < 64) {
    int p = t >> 5, rem = t & 31, f = rem >> 3, m = rem & 7;
    float fval = (p == 0) ? (float)f
                          : ((f == 0) ? 0.f : (f == 1) ? 1.f : (f == 2) ? -2.f : -1.f);
    float wp = fval * (TWO_PI_F * 0.125f);
    float Wr = 0.f, Wi = 0.f;
    for (int mm = 0; mm < 8; mm++) {
      float nmm = sNodes[mm];
      float Tk = cosf((float)m * acosf(nmm));
      Wr += Tk * cosf(nmm * wp);
      Wi += Tk * (-sinf(nmm * wp));
    }
    sWr[p][f][m] = Wr * 0.125f;
    sWi[p][f][m] = Wi * 0.125f;
  } else if (t < 96) {
    int id = t - 64, p = id >> 4, f = (id >> 2) & 3, l = id & 3;
    float fval = (p == 0) ? (float)f
                          : ((f == 0) ? 0.f : (f == 1) ? 1.f : (f == 2) ? -2.f : -1.f);
    float ph = -TWO_PI_F * (0.25f * (float)l) * fval;
    sCr[p][f][l] = cosf(ph);
    sCi[p][f][l] = sinf(ph);
  }
  __syncthreads();

  // CFT columns: oid = (pass, w, f) — transcendental-free gather
  for (int oid = t; oid < 2 * 128 * 4; oid += 256) {
    int p = oid >> 9;
    int rem = oid & 511;
    int w = rem >> 2, f = rem & 3;
    float accR = 0.f, accI = 0.f;
    for (int l = 0; l < 4; l++) {
      float start = 0.25f * (float)l;
      for (int m = 0; m < 8; m++) {
        float tseg = start + 0.125f * (sNodes[m] + 1.0f);
        int ri = (int)(tseg * 127.0f) - 2; if (ri < 0) ri = 0;
        while (ri < 127 && tcoordf(ri) < tseg) ri++;
        int le = ri - 1; if (le < 0) le = 0;
        if (le != w && ri != w) continue;
        float tl = tcoordf(le), tr = tcoordf(ri);
        float den = (tr - tl < 1e-8f) ? 1.0f : (tr - tl);
        float wrv = (tseg - tl) / den;
        float wlv = 1.0f - wrv;
        float Wr = sWr[p][f][m], Wi = sWi[p][f][m];
        float cr = sCr[p][f][l], ci = sCi[p][f][l];
        float coefR = Wr * cr - Wi * ci;
        float coefI = Wr * ci + Wi * cr;
        float wgt = 0.f;
        if (le == w) wgt += wlv;
        if (ri == w) wgt += wrv;
        accR += wgt * coefR;
        accI += wgt * coefI;
      }
    }
    if (p == 0) { Ktab[(32 + f) * KT_LD + w] = accR; Ktab[(36 + f) * KT_LD + w] = accI; }
    else        { cftH[w * 8 + f] = accR;            cftH[w * 8 + 4 + f] = accI; }
  }

  // DFT rows: out 2*kx+{0,1} : cos / -sin of 2*pi*kx*w/128 (angle pre-reduced)
  for (int oid = t; oid < 32 * 128; oid += 256) {
    int out = oid >> 7, w = oid & 127;
    int kx = out >> 1;
    int r = (kx * w) & 127;
    float ang = TWO_PI_F * (float)r * (1.0f / 128.0f);
    float s, c;
    __sincosf(ang, &s, &c);
    Ktab[out * KT_LD + w] = (out & 1) ? (-s) : c;
  }
}

// ---------------- stage A: row DFT (16 kx modes) + CFT W-pass, fused ----------------
__global__ __launch_bounds__(256) void k_stageA(const float* __restrict__ x,
                                                const float* __restrict__ Ktab,
                                                float* __restrict__ xw,
                                                float* __restrict__ cft1) {
  __shared__ float tile[64 * 129];
  int t = threadIdx.x;
  const float* xblk = x + (size_t)blockIdx.x * 64 * 128;
  #pragma unroll
  for (int k2 = 0; k2 < 8; k2++) {
    int f4 = t + k2 * 256;             // 2048 float4
    int row = f4 >> 5, c4 = f4 & 31;
    const float4 v = *reinterpret_cast<const float4*>(xblk + row * 128 + c4 * 4);
    float* dst = &tile[row * 129 + c4 * 4];
    dst[0] = v.x; dst[1] = v.y; dst[2] = v.z; dst[3] = v.w;
  }
  __syncthreads();

  int p = t & 63;
  int gu = __builtin_amdgcn_readfirstlane(t >> 6);   // wave-uniform out-group 0..3
  const float* Kb = Ktab + (size_t)gu * 10 * KT_LD;
  float acc[10];
  #pragma unroll
  for (int i = 0; i < 10; i++) acc[i] = 0.f;
  const float* r0 = &tile[p * 129];
  #pragma unroll 4
  for (int w = 0; w < 128; w++) {
    float s0 = r0[w];
    #pragma unroll
    for (int i = 0; i < 10; i++) acc[i] = fmaf(s0, Kb[i * KT_LD + w], acc[i]);
  }

  int bc = blockIdx.x >> 1;
  int h = ((blockIdx.x & 1) << 6) + p;
  #pragma unroll
  for (int i = 0; i < 10; i++) {
    int j = gu * 10 + i;
    if (j < 32) {
      int kx = j >> 1, ri = j & 1;
      xw[(((size_t)bc * 128 + h) * 16 + kx) * 2 + ri] = acc[i];
    } else {
      cft1[((size_t)bc * 128 + h) * 8 + (j - 32)] = acc[i];
    }
  }
}

// ---------------- stage B: forward DFT over h (32 ky modes) via phasor rotation ----------------
__global__ __launch_bounds__(256) void k_stageB(const float* __restrict__ xw,
                                                float* __restrict__ xf) {
  int t = threadIdx.x;
  int bc = blockIdx.x;
  int kx = t & 15, jg = t >> 4;        // jg 0..15, j = jg*2+q
  float pr[2], pq[2], sr[2], si[2], aR[2], aI[2];
  #pragma unroll
  for (int q = 0; q < 2; q++) {
    int j = jg * 2 + q;
    int ky = (j < 16) ? j : j + 96;
    float ang = TWO_PI_F * (float)ky * (1.0f / 128.0f);
    float s, c;
    __sincosf(ang, &s, &c);
    sr[q] = c; si[q] = -s;             // e^{-2pi i ky/128}
    pr[q] = 1.f; pq[q] = 0.f; aR[q] = 0.f; aI[q] = 0.f;
  }
  const float* base = xw + (size_t)bc * 128 * 32 + kx * 2;
  for (int h = 0; h < 128; h++) {
    const float2 v = *reinterpret_cast<const float2*>(base + h * 32);
    #pragma unroll
    for (int q = 0; q < 2; q++) {
      aR[q] = fmaf(v.x, pr[q], fmaf(-v.y, pq[q], aR[q]));
      aI[q] = fmaf(v.x, pq[q], fmaf(v.y, pr[q], aI[q]));
      float npr = pr[q] * sr[q] - pq[q] * si[q];
      float npi = pr[q] * si[q] + pq[q] * sr[q];
      pr[q] = npr; pq[q] = npi;
    }
  }
  #pragma unroll
  for (int q = 0; q < 2; q++) {
    int j = jg * 2 + q;
    float2* o = reinterpret_cast<float2*>(xf + (((size_t)bc * 32 + j) * 16 + kx) * 2);
    *o = make_float2(aR[q], aI[q]);
  }
}

// ---------------- CFT H-pass: cft1 -> flat ----------------
__global__ void k_cfth(const float* __restrict__ cft1, const float* __restrict__ cftH,
                       float* __restrict__ flat) {
  int t = threadIdx.x;
  int bc = blockIdx.x * 2 + (t >> 5);
  int tt = t & 31;
  int f1 = tt >> 3, f2 = (tt >> 1) & 3, ri = tt & 1;
  const float* s = cft1 + (size_t)bc * 1024;
  float acc = 0.f;
  for (int h = 0; h < 128; h++) {
    float r = s[h * 8 + f2], im = s[h * 8 + 4 + f2];
    float kr = cftH[h * 8 + f1], ki = cftH[h * 8 + 4 + f1];
    float e0 = (ri == 0) ? kr : ki;
    float e1 = (ri == 0) ? -ki : kr;
    acc = fmaf(r, e0, fmaf(im, e1, acc));
  }
  int b = bc >> 6, c = bc & 63;
  flat[(size_t)b * 2048 + ((c * 4 + f1) * 4 + f2) * 2 + ri] = acc;
}

// ---------------- MLP: flat -> corr (exact-erf GELU) ----------------
__global__ __launch_bounds__(256) void k_mlp(const float* __restrict__ flat,
                                             const float* __restrict__ w1,
                                             const float* __restrict__ b1,
                                             const float* __restrict__ w2,
                                             const float* __restrict__ b2,
                                             float* __restrict__ corr) {
  __shared__ float fs[2048];
  __shared__ float hs[256];
  int b = blockIdx.x, t = threadIdx.x;
  #pragma unroll
  for (int k = 0; k < 8; k++) fs[t + k * 256] = flat[(size_t)b * 2048 + t + k * 256];
  __syncthreads();
  float acc = b1[t];
  for (int k = 0; k < 2048; k++) acc = fmaf(fs[k], w1[(size_t)k * 256 + t], acc);
  float ge = 0.5f * acc * (1.0f + erff(acc * 0.70710678118654752f));
  hs[t] = ge;
  __syncthreads();
  if (t < 64) {
    float a2 = b2[t];
    for (int k = 0; k < 256; k++) a2 = fmaf(hs[k], w2[(size_t)k * 64 + t], a2);
    corr[(size_t)b * 64 + t] = a2;
  }
}

// ---------------- stage C: mode-mixing einsum over C ----------------
__global__ __launch_bounds__(256) void k_stageC(const float* __restrict__ xf,
                                                const float* __restrict__ w1,
                                                const float* __restrict__ w2,
                                                float* __restrict__ outft) {
  __shared__ float xfs[64 * 32];       // [c][kx*2+ri]
  int bid = blockIdx.x;
  int sw = (bid & 7) * 128 + (bid >> 3);   // bijective (1024 % 8 == 0)
  int j = sw >> 5, b = sw & 31;
  int t = threadIdx.x;
  #pragma unroll
  for (int k2 = 0; k2 < 4; k2++) {
    int id = t + k2 * 256;             // 1024 float2
    int c = id >> 4, kxi = id & 15;
    const float2 v = *reinterpret_cast<const float2*>(
        xf + (((size_t)b * 64 + c) * 32 + j) * 32 + kxi * 2);
    reinterpret_cast<float2*>(xfs)[id] = v;
  }
  __syncthreads();
  int kx = t & 15, og = t >> 4;
  const float* wsel = (j < 16) ? w1 : w2;
  int jr = (j < 16) ? j : j - 16;
  float aR[4], aI[4];
  #pragma unroll
  for (int i = 0; i < 4; i++) { aR[i] = 0.f; aI[i] = 0.f; }
  for (int c = 0; c < 64; c++) {
    float xr = xfs[c * 32 + kx * 2], xi = xfs[c * 32 + kx * 2 + 1];
    #pragma unroll
    for (int i = 0; i < 4; i++) {
      int o = og * 4 + i;
      const float2 wv = *reinterpret_cast<const float2*>(
          wsel + ((((size_t)c * 64 + o) * 16 + jr) * 16 + kx) * 2);
      aR[i] = fmaf(xr, wv.x, fmaf(-xi, wv.y, aR[i]));
      aI[i] = fmaf(xr, wv.y, fmaf(xi, wv.x, aI[i]));
    }
  }
  #pragma unroll
  for (int i = 0; i < 4; i++) {
    int o = og * 4 + i;
    float2* dst = reinterpret_cast<float2*>(outft + (((size_t)b * 64 + o) * 32 + j) * 32 + kx * 2);
    *dst = make_float2(aR[i], aI[i]);
  }
}

// ---------------- stage D: inverse DFT over ky (32 modes -> 128 h), 1/H folded ----------------
__global__ __launch_bounds__(256) void k_stageD(const float* __restrict__ outft,
                                                float* __restrict__ y) {
  int bo = blockIdx.x;
  int t = threadIdx.x;
  int kx = t & 15, hg = t >> 4;
  int h0 = hg * 8;
  float aR[8], aI[8];
  #pragma unroll
  for (int k = 0; k < 8; k++) { aR[k] = 0.f; aI[k] = 0.f; }
  const float* src = outft + (size_t)bo * 1024 + kx * 2;
  for (int jj = 0; jj < 32; jj++) {
    const float2 c = *reinterpret_cast<const float2*>(src + jj * 32);
    int ky = (jj < 16) ? jj : jj + 96;
    int r0 = (ky * h0) & 127;
    float angb = TWO_PI_F * (1.0f / 128.0f) * (float)r0;
    float br, bi;
    __sincosf(angb, &bi, &br);                  // bi=sin, br=cos (e^{+2pi i ky h0/128})
    float angs = TWO_PI_F * (1.0f / 128.0f) * (float)(ky & 127);
    float sti, strr;
    __sincosf(angs, &sti, &strr);               // e^{+2pi i ky/128}
    #pragma unroll
    for (int k = 0; k < 8; k++) {
      aR[k] = fmaf(c.x, br, fmaf(-c.y, bi, aR[k]));
      aI[k] = fmaf(c.x, bi, fmaf(c.y, br, aI[k]));
      float nbr = br * strr - bi * sti;
      float nbi = br * sti + bi * strr;
      br = nbr; bi = nbi;
    }
  }
  float* dst = y + ((size_t)bo * 128 + h0) * 32 + kx * 2;
  #pragma unroll
  for (int k = 0; k < 8; k++) {
    *reinterpret_cast<float2*>(dst + k * 32) =
        make_float2(aR[k] * 0.0078125f, aI[k] * 0.0078125f);
  }
}

// ---------------- stage E: inverse rfft over w (c2r: Im(DC) dropped) + corr ----------------
__global__ __launch_bounds__(256) void k_stageE(const float* __restrict__ y,
                                                const float* __restrict__ corr,
                                                float* __restrict__ out) {
  int bo = blockIdx.x;
  int t = threadIdx.x;
  int w = t & 127, hh = t >> 7;
  float cph[16], sph[16];
  #pragma unroll
  for (int kx = 0; kx < 16; kx++) {
    int r = (kx * w) & 127;
    float ang = TWO_PI_F * (1.0f / 128.0f) * (float)r;
    float s, c;
    __sincosf(ang, &s, &c);
    cph[kx] = c; sph[kx] = s;
  }
  float corrv = corr[bo];
  const float* ybase = y + (size_t)bo * 128 * 32;
  float* obase = out + (size_t)bo * 128 * 128;
  for (int k = 0; k < 64; k++) {
    int h = 2 * k + hh;                 // wave-uniform h -> scalar y loads
    const float* yr = ybase + h * 32;
    float acc = yr[0];                  // DC: real part only (c2r semantics)
    #pragma unroll
    for (int kx = 1; kx < 16; kx++) {
      float a = 2.0f * yr[kx * 2];
      float bim = 2.0f * yr[kx * 2 + 1];
      acc = fmaf(a, cph[kx], acc);
      acc = fmaf(-bim, sph[kx], acc);
    }
    obase[h * 128 + w] = acc * 0.0078125f + corrv;
  }
}

extern "C" void kernel_launch(void* const* d_in, const int* in_sizes, int n_in,
                              void* d_out, int out_size, void* d_ws, size_t ws_size,
                              hipStream_t stream) {
  const float* x   = (const float*)d_in[0];
  const float* w1  = (const float*)d_in[1];
  const float* w2  = (const float*)d_in[2];
  const float* l1w = (const float*)d_in[3];
  const float* l1b = (const float*)d_in[4];
  const float* l2w = (const float*)d_in[5];
  const float* l2b = (const float*)d_in[6];
  float* out = (float*)d_out;
  float* ws  = (float*)d_ws;

  float* Ktab  = ws + WSO_KTAB;
  float* cftH  = ws + WSO_CFTH;
  float* flat  = ws + WSO_FLAT;
  float* corr  = ws + WSO_CORR;
  float* cft1  = ws + WSO_CFT1;
  float* xf    = ws + WSO_XF;
  float* y     = ws + WSO_Y;
  float* outft = ws + WSO_OUTFT;
  float* xw    = out;   // d_out used as scratch for xw; fully rewritten by stage E

  k_tables<<<dim3(1), dim3(256), 0, stream>>>(ws);
  k_stageA<<<dim3(4096), dim3(256), 0, stream>>>(x, Ktab, xw, cft1);
  k_stageB<<<dim3(2048), dim3(256), 0, stream>>>(xw, xf);
  k_cfth<<<dim3(1024), dim3(64), 0, stream>>>(cft1, cftH, flat);
  k_mlp<<<dim3(32), dim3(256), 0, stream>>>(flat, l1w, l1b, l2w, l2b, corr);
  k_stageC<<<dim3(1024), dim3(256), 0, stream>>>(xf, w1, w2, outft);
  k_stageD<<<dim3(2048), dim3(256), 0, stream>>>(outft, y);
  k_stageE<<<dim3(2048), dim3(256), 0, stream>>>(y, corr, out);
}

// Round 3
// 410.111 us; speedup vs baseline: 1.4204x; 1.1765x over previous
//
#include <hip/hip_runtime.h>
#include <math.h>

#define PI_F 3.14159265358979323846f
#define TWO_PI_F 6.28318530717958647692f

// problem sizes
constexpr int Bn = 32, Cn = 64, On = 64, Hn = 128, Wn = 128;

// workspace float offsets
constexpr size_t WSO_FLAT  = 6304;                     // 32*2048
constexpr size_t WSO_CORR  = 71840;                    // 32*64
constexpr size_t WSO_BIG   = 81920;
constexpr size_t SZ_QTR    = (size_t)2097152;          // 2M floats
constexpr size_t WSO_CFT1  = WSO_BIG;                  // [2048][128][8]
constexpr size_t WSO_XF    = WSO_BIG + SZ_QTR;         // [32][64][32][16][2]
constexpr size_t WSO_Y     = WSO_BIG;                  // alias: cft1+xf dead by stage D
constexpr size_t WSO_OUTFT = WSO_BIG + 4 * SZ_QTR;     // [32][64][32][16][2]

// ================= compile-time tables =================
// ktab rows 0..31: DFT (row 2kx+0 = cos, 2kx+1 = -sin of 2*pi*kx*w/128)
// ktab rows 32..39: CFT W-pass (32+f real, 36+f imag), f = fw 0..3
// cfth[w][f(0..3)]=real, [w][4+f]=imag, fsel = {0,1,-2,-1}
struct Tabs {
  float ktab[40][128];
  float cfth[128][8];
};

constexpr double D_PI = 3.14159265358979323846;

constexpr double d_red(double x) {
  while (x >  D_PI) x -= 2.0 * D_PI;
  while (x < -D_PI) x += 2.0 * D_PI;
  return x;
}
constexpr double d_sin(double x) {
  x = d_red(x);
  double x2 = x * x, t = x, s = x;
  for (int n = 1; n <= 10; n++) { t *= -x2 / (double)((2 * n) * (2 * n + 1)); s += t; }
  return s;
}
constexpr double d_cos(double x) {
  x = d_red(x);
  double x2 = x * x, t = 1.0, s = 1.0;
  for (int n = 1; n <= 10; n++) { t *= -x2 / (double)((2 * n - 1) * (2 * n)); s += t; }
  return s;
}

constexpr Tabs make_tabs() {
  Tabs T{};
  // base twiddles for multiples of 2pi/128
  double twc[128] = {}, tws[128] = {};
  for (int r = 0; r < 128; r++) {
    double a = 2.0 * D_PI * (double)r / 128.0;
    twc[r] = d_cos(a); tws[r] = d_sin(a);
  }
  for (int kx = 0; kx < 16; kx++)
    for (int w = 0; w < 128; w++) {
      int r = (kx * w) & 127;
      T.ktab[2 * kx][w]     = (float)twc[r];
      T.ktab[2 * kx + 1][w] = (float)(-tws[r]);
    }
  // chebyshev nodes; arccos(node_m) = pi - theta_m exactly
  double node[8] = {}, theta[8] = {};
  for (int m = 0; m < 8; m++) { theta[m] = (2.0 * m + 1.0) * D_PI / 16.0; node[m] = -d_cos(theta[m]); }
  double Tch[8][8] = {};
  for (int k = 0; k < 8; k++)
    for (int m = 0; m < 8; m++) Tch[k][m] = d_cos((double)k * (D_PI - theta[m]));
  // interpolation stencils (float semantics to match reference searchsorted on linspace)
  int LE[4][8] = {}, RI[4][8] = {};
  float WL[4][8] = {}, WR[4][8] = {};
  for (int l = 0; l < 4; l++)
    for (int m = 0; m < 8; m++) {
      float tseg = (float)(0.25 * (double)l + 0.125 * (node[m] + 1.0));
      int ri = (int)(tseg * 127.0f) - 2; if (ri < 0) ri = 0;
      while (ri < 127 && ((float)ri * (1.0f / 127.0f)) < tseg) ri++;
      int le = ri - 1; if (le < 0) le = 0;
      float tl = (float)le * (1.0f / 127.0f), tr = (float)ri * (1.0f / 127.0f);
      float den = (tr - tl < 1e-8f) ? 1.0f : (tr - tl);
      float wr = (tseg - tl) / den;
      LE[l][m] = le; RI[l][m] = ri; WR[l][m] = wr; WL[l][m] = 1.0f - wr;
    }
  // two CFT passes: p=0 (W axis, f=fw 0..3), p=1 (H axis, fsel {0,1,-2,-1})
  for (int p = 0; p < 2; p++)
    for (int f = 0; f < 4; f++) {
      double fval = (p == 0) ? (double)f
                             : ((f == 0) ? 0.0 : (f == 1) ? 1.0 : (f == 2) ? -2.0 : -1.0);
      double wp = fval * (2.0 * D_PI * 0.125);
      double Wr[8] = {}, Wi[8] = {};
      for (int k = 0; k < 8; k++) {
        double sr = 0.0, si = 0.0;
        for (int m = 0; m < 8; m++) {
          sr += Tch[k][m] * d_cos(node[m] * wp);
          si += Tch[k][m] * (-d_sin(node[m] * wp));
        }
        Wr[k] = sr * 0.125; Wi[k] = si * 0.125;
      }
      for (int l = 0; l < 4; l++) {
        double ph = -2.0 * D_PI * (0.25 * (double)l) * fval;
        double cr = d_cos(ph), ci = d_sin(ph);
        for (int m = 0; m < 8; m++) {
          double coefR = Wr[m] * cr - Wi[m] * ci;
          double coefI = Wr[m] * ci + Wi[m] * cr;
          int le = LE[l][m], ri = RI[l][m];
          if (p == 0) {
            T.ktab[32 + f][le] += (float)(WL[l][m] * coefR);
            T.ktab[36 + f][le] += (float)(WL[l][m] * coefI);
            T.ktab[32 + f][ri] += (float)(WR[l][m] * coefR);
            T.ktab[36 + f][ri] += (float)(WR[l][m] * coefI);
          } else {
            T.cfth[le][f]     += (float)(WL[l][m] * coefR);
            T.cfth[le][4 + f] += (float)(WL[l][m] * coefI);
            T.cfth[ri][f]     += (float)(WR[l][m] * coefR);
            T.cfth[ri][4 + f] += (float)(WR[l][m] * coefI);
          }
        }
      }
    }
  return T;
}

__constant__ Tabs g_tabs = make_tabs();

// ---------------- stage A: row DFT (16 kx modes) + CFT W-pass, fused ----------------
__global__ __launch_bounds__(256) void k_stageA(const float* __restrict__ x,
                                                float* __restrict__ xw,
                                                float* __restrict__ cft1) {
  __shared__ float tile[64 * 129];
  int t = threadIdx.x;
  const float* xblk = x + (size_t)blockIdx.x * 64 * 128;
  #pragma unroll
  for (int k2 = 0; k2 < 8; k2++) {
    int f4 = t + k2 * 256;             // 2048 float4
    int row = f4 >> 5, c4 = f4 & 31;
    const float4 v = *reinterpret_cast<const float4*>(xblk + row * 128 + c4 * 4);
    float* dst = &tile[row * 129 + c4 * 4];
    dst[0] = v.x; dst[1] = v.y; dst[2] = v.z; dst[3] = v.w;
  }
  __syncthreads();

  int p = t & 63;
  int gu = __builtin_amdgcn_readfirstlane(t >> 6);   // wave-uniform out-group 0..3
  const float* Kb = &g_tabs.ktab[0][0] + (size_t)gu * 10 * 128;
  float acc[10];
  #pragma unroll
  for (int i = 0; i < 10; i++) acc[i] = 0.f;
  const float* r0 = &tile[p * 129];
  #pragma unroll 4
  for (int w = 0; w < 128; w++) {
    float s0 = r0[w];
    #pragma unroll
    for (int i = 0; i < 10; i++) acc[i] = fmaf(s0, Kb[i * 128 + w], acc[i]);
  }

  int bc = blockIdx.x >> 1;
  int h = ((blockIdx.x & 1) << 6) + p;
  #pragma unroll
  for (int i = 0; i < 10; i++) {
    int j = gu * 10 + i;
    if (j < 32) {
      int kx = j >> 1, ri = j & 1;
      xw[(((size_t)bc * 128 + h) * 16 + kx) * 2 + ri] = acc[i];
    } else {
      cft1[((size_t)bc * 128 + h) * 8 + (j - 32)] = acc[i];
    }
  }
}

// ---------------- stage B: forward DFT over h (32 ky modes) via phasor rotation ----------------
__global__ __launch_bounds__(256) void k_stageB(const float* __restrict__ xw,
                                                float* __restrict__ xf) {
  int t = threadIdx.x;
  int bc = blockIdx.x;
  int kx = t & 15, jg = t >> 4;        // jg 0..15, j = jg*2+q
  float pr[2], pq[2], sr[2], si[2], aR[2], aI[2];
  #pragma unroll
  for (int q = 0; q < 2; q++) {
    int j = jg * 2 + q;
    int ky = (j < 16) ? j : j + 96;
    float ang = TWO_PI_F * (float)ky * (1.0f / 128.0f);
    float s, c;
    __sincosf(ang, &s, &c);
    sr[q] = c; si[q] = -s;             // e^{-2pi i ky/128}
    pr[q] = 1.f; pq[q] = 0.f; aR[q] = 0.f; aI[q] = 0.f;
  }
  const float* base = xw + (size_t)bc * 128 * 32 + kx * 2;
  for (int h = 0; h < 128; h++) {
    const float2 v = *reinterpret_cast<const float2*>(base + h * 32);
    #pragma unroll
    for (int q = 0; q < 2; q++) {
      aR[q] = fmaf(v.x, pr[q], fmaf(-v.y, pq[q], aR[q]));
      aI[q] = fmaf(v.x, pq[q], fmaf(v.y, pr[q], aI[q]));
      float npr = pr[q] * sr[q] - pq[q] * si[q];
      float npi = pr[q] * si[q] + pq[q] * sr[q];
      pr[q] = npr; pq[q] = npi;
    }
  }
  #pragma unroll
  for (int q = 0; q < 2; q++) {
    int j = jg * 2 + q;
    float2* o = reinterpret_cast<float2*>(xf + (((size_t)bc * 32 + j) * 16 + kx) * 2);
    *o = make_float2(aR[q], aI[q]);
  }
}

// ---------------- CFT H-pass: cft1 -> flat ----------------
__global__ void k_cfth(const float* __restrict__ cft1, float* __restrict__ flat) {
  int t = threadIdx.x;
  int bc = blockIdx.x * 2 + (t >> 5);
  int tt = t & 31;
  int f1 = tt >> 3, f2 = (tt >> 1) & 3, ri = tt & 1;
  const float* s = cft1 + (size_t)bc * 1024;
  float acc = 0.f;
  for (int h = 0; h < 128; h++) {
    float r = s[h * 8 + f2], im = s[h * 8 + 4 + f2];
    float kr = g_tabs.cfth[h][f1], ki = g_tabs.cfth[h][4 + f1];
    float e0 = (ri == 0) ? kr : ki;
    float e1 = (ri == 0) ? -ki : kr;
    acc = fmaf(r, e0, fmaf(im, e1, acc));
  }
  int b = bc >> 6, c = bc & 63;
  flat[(size_t)b * 2048 + ((c * 4 + f1) * 4 + f2) * 2 + ri] = acc;
}

// ---------------- MLP: flat -> corr (exact-erf GELU) ----------------
__global__ __launch_bounds__(256) void k_mlp(const float* __restrict__ flat,
                                             const float* __restrict__ w1,
                                             const float* __restrict__ b1,
                                             const float* __restrict__ w2,
                                             const float* __restrict__ b2,
                                             float* __restrict__ corr) {
  __shared__ float fs[2048];
  __shared__ float hs[256];
  int b = blockIdx.x, t = threadIdx.x;
  #pragma unroll
  for (int k = 0; k < 8; k++) fs[t + k * 256] = flat[(size_t)b * 2048 + t + k * 256];
  __syncthreads();
  float acc = b1[t];
  for (int k = 0; k < 2048; k++) acc = fmaf(fs[k], w1[(size_t)k * 256 + t], acc);
  float ge = 0.5f * acc * (1.0f + erff(acc * 0.70710678118654752f));
  hs[t] = ge;
  __syncthreads();
  if (t < 64) {
    float a2 = b2[t];
    for (int k = 0; k < 256; k++) a2 = fmaf(hs[k], w2[(size_t)k * 64 + t], a2);
    corr[(size_t)b * 64 + t] = a2;
  }
}

// ---------------- stage C: mode-mixing einsum over C ----------------
__global__ __launch_bounds__(256) void k_stageC(const float* __restrict__ xf,
                                                const float* __restrict__ w1,
                                                const float* __restrict__ w2,
                                                float* __restrict__ outft) {
  __shared__ float xfs[64 * 32];       // [c][kx*2+ri]
  int bid = blockIdx.x;
  int sw = (bid & 7) * 128 + (bid >> 3);   // bijective (1024 % 8 == 0)
  int j = sw >> 5, b = sw & 31;
  int t = threadIdx.x;
  #pragma unroll
  for (int k2 = 0; k2 < 4; k2++) {
    int id = t + k2 * 256;             // 1024 float2
    int c = id >> 4, kxi = id & 15;
    const float2 v = *reinterpret_cast<const float2*>(
        xf + (((size_t)b * 64 + c) * 32 + j) * 32 + kxi * 2);
    reinterpret_cast<float2*>(xfs)[id] = v;
  }
  __syncthreads();
  int kx = t & 15, og = t >> 4;
  const float* wsel = (j < 16) ? w1 : w2;
  int jr = (j < 16) ? j : j - 16;
  float aR[4], aI[4];
  #pragma unroll
  for (int i = 0; i < 4; i++) { aR[i] = 0.f; aI[i] = 0.f; }
  for (int c = 0; c < 64; c++) {
    float xr = xfs[c * 32 + kx * 2], xi = xfs[c * 32 + kx * 2 + 1];
    #pragma unroll
    for (int i = 0; i < 4; i++) {
      int o = og * 4 + i;
      const float2 wv = *reinterpret_cast<const float2*>(
          wsel + ((((size_t)c * 64 + o) * 16 + jr) * 16 + kx) * 2);
      aR[i] = fmaf(xr, wv.x, fmaf(-xi, wv.y, aR[i]));
      aI[i] = fmaf(xr, wv.y, fmaf(xi, wv.x, aI[i]));
    }
  }
  #pragma unroll
  for (int i = 0; i < 4; i++) {
    int o = og * 4 + i;
    float2* dst = reinterpret_cast<float2*>(outft + (((size_t)b * 64 + o) * 32 + j) * 32 + kx * 2);
    *dst = make_float2(aR[i], aI[i]);
  }
}

// ---------------- stage D: inverse DFT over ky (32 modes -> 128 h), 1/H folded ----------------
__global__ __launch_bounds__(256) void k_stageD(const float* __restrict__ outft,
                                                float* __restrict__ y) {
  int bo = blockIdx.x;
  int t = threadIdx.x;
  int kx = t & 15, hg = t >> 4;
  int h0 = hg * 8;
  float aR[8], aI[8];
  #pragma unroll
  for (int k = 0; k < 8; k++) { aR[k] = 0.f; aI[k] = 0.f; }
  const float* src = outft + (size_t)bo * 1024 + kx * 2;
  for (int jj = 0; jj < 32; jj++) {
    const float2 c = *reinterpret_cast<const float2*>(src + jj * 32);
    int ky = (jj < 16) ? jj : jj + 96;
    int r0 = (ky * h0) & 127;
    float angb = TWO_PI_F * (1.0f / 128.0f) * (float)r0;
    float br, bi;
    __sincosf(angb, &bi, &br);                  // e^{+2pi i ky h0/128}
    float angs = TWO_PI_F * (1.0f / 128.0f) * (float)(ky & 127);
    float sti, strr;
    __sincosf(angs, &sti, &strr);               // e^{+2pi i ky/128}
    #pragma unroll
    for (int k = 0; k < 8; k++) {
      aR[k] = fmaf(c.x, br, fmaf(-c.y, bi, aR[k]));
      aI[k] = fmaf(c.x, bi, fmaf(c.y, br, aI[k]));
      float nbr = br * strr - bi * sti;
      float nbi = br * sti + bi * strr;
      br = nbr; bi = nbi;
    }
  }
  float* dst = y + ((size_t)bo * 128 + h0) * 32 + kx * 2;
  #pragma unroll
  for (int k = 0; k < 8; k++) {
    *reinterpret_cast<float2*>(dst + k * 32) =
        make_float2(aR[k] * 0.0078125f, aI[k] * 0.0078125f);
  }
}

// ---------------- stage E: inverse rfft over w (c2r: Im(DC) dropped) + corr ----------------
__global__ __launch_bounds__(256) void k_stageE(const float* __restrict__ y,
                                                const float* __restrict__ corr,
                                                float* __restrict__ out) {
  int bo = blockIdx.x;
  int t = threadIdx.x;
  int w = t & 127, hh = t >> 7;
  float cph[16], sph[16];
  #pragma unroll
  for (int kx = 0; kx < 16; kx++) {
    int r = (kx * w) & 127;
    float ang = TWO_PI_F * (1.0f / 128.0f) * (float)r;
    float s, c;
    __sincosf(ang, &s, &c);
    cph[kx] = c; sph[kx] = s;
  }
  float corrv = corr[bo];
  const float* ybase = y + (size_t)bo * 128 * 32;
  float* obase = out + (size_t)bo * 128 * 128;
  for (int k = 0; k < 64; k++) {
    int h = 2 * k + hh;                 // wave-uniform h -> scalar y loads
    const float* yr = ybase + h * 32;
    float acc = yr[0];                  // DC: real part only (c2r semantics)
    #pragma unroll
    for (int kx = 1; kx < 16; kx++) {
      float a = 2.0f * yr[kx * 2];
      float bim = 2.0f * yr[kx * 2 + 1];
      acc = fmaf(a, cph[kx], acc);
      acc = fmaf(-bim, sph[kx], acc);
    }
    obase[h * 128 + w] = acc * 0.0078125f + corrv;
  }
}

extern "C" void kernel_launch(void* const* d_in, const int* in_sizes, int n_in,
                              void* d_out, int out_size, void* d_ws, size_t ws_size,
                              hipStream_t stream) {
  const float* x   = (const float*)d_in[0];
  const float* w1  = (const float*)d_in[1];
  const float* w2  = (const float*)d_in[2];
  const float* l1w = (const float*)d_in[3];
  const float* l1b = (const float*)d_in[4];
  const float* l2w = (const float*)d_in[5];
  const float* l2b = (const float*)d_in[6];
  float* out = (float*)d_out;
  float* ws  = (float*)d_ws;

  float* flat  = ws + WSO_FLAT;
  float* corr  = ws + WSO_CORR;
  float* cft1  = ws + WSO_CFT1;
  float* xf    = ws + WSO_XF;
  float* y     = ws + WSO_Y;
  float* outft = ws + WSO_OUTFT;
  float* xw    = out;   // d_out used as scratch for xw; fully rewritten by stage E

  k_stageA<<<dim3(4096), dim3(256), 0, stream>>>(x, xw, cft1);
  k_stageB<<<dim3(2048), dim3(256), 0, stream>>>(xw, xf);
  k_cfth<<<dim3(1024), dim3(64), 0, stream>>>(cft1, flat);
  k_mlp<<<dim3(32), dim3(256), 0, stream>>>(flat, l1w, l1b, l2w, l2b, corr);
  k_stageC<<<dim3(1024), dim3(256), 0, stream>>>(xf, w1, w2, outft);
  k_stageD<<<dim3(2048), dim3(256), 0, stream>>>(outft, y);
  k_stageE<<<dim3(2048), dim3(256), 0, stream>>>(y, corr, out);
}

// Round 4
// 329.289 us; speedup vs baseline: 1.7690x; 1.2454x over previous
//
#include <hip/hip_runtime.h>
#include <math.h>

#define PI_F 3.14159265358979323846f
#define TWO_PI_F 6.28318530717958647692f

// problem sizes
constexpr int Bn = 32, Cn = 64, On = 64, Hn = 128, Wn = 128;

// workspace float offsets (small region < WSO_BIG)
constexpr size_t WSO_FLAT  = 0;                        // 32*2048 = 65536
constexpr size_t WSO_CORR  = 65536;                    // 32*64   = 2048
constexpr size_t WSO_HS    = 67584;                    // 32*256  = 8192 (ends 75776)
constexpr size_t WSO_BIG   = 81920;
constexpr size_t SZ_QTR    = (size_t)2097152;          // 2M floats
constexpr size_t WSO_CFT1  = WSO_BIG;                  // [2048][128][8]
constexpr size_t WSO_XF    = WSO_BIG + SZ_QTR;         // [32][64][32][16][2]
constexpr size_t WSO_Y     = WSO_BIG;                  // alias: cft1+xf dead by stage D
constexpr size_t WSO_OUTFT = WSO_BIG + 4 * SZ_QTR;     // [32][64][32][16][2]

// ================= compile-time tables =================
struct Tabs {
  float ktab[40][128];
  float cfth[128][8];
};

constexpr double D_PI = 3.14159265358979323846;

constexpr double d_red(double x) {
  while (x >  D_PI) x -= 2.0 * D_PI;
  while (x < -D_PI) x += 2.0 * D_PI;
  return x;
}
constexpr double d_sin(double x) {
  x = d_red(x);
  double x2 = x * x, t = x, s = x;
  for (int n = 1; n <= 10; n++) { t *= -x2 / (double)((2 * n) * (2 * n + 1)); s += t; }
  return s;
}
constexpr double d_cos(double x) {
  x = d_red(x);
  double x2 = x * x, t = 1.0, s = 1.0;
  for (int n = 1; n <= 10; n++) { t *= -x2 / (double)((2 * n - 1) * (2 * n)); s += t; }
  return s;
}

constexpr Tabs make_tabs() {
  Tabs T{};
  double twc[128] = {}, tws[128] = {};
  for (int r = 0; r < 128; r++) {
    double a = 2.0 * D_PI * (double)r / 128.0;
    twc[r] = d_cos(a); tws[r] = d_sin(a);
  }
  for (int kx = 0; kx < 16; kx++)
    for (int w = 0; w < 128; w++) {
      int r = (kx * w) & 127;
      T.ktab[2 * kx][w]     = (float)twc[r];
      T.ktab[2 * kx + 1][w] = (float)(-tws[r]);
    }
  double node[8] = {}, theta[8] = {};
  for (int m = 0; m < 8; m++) { theta[m] = (2.0 * m + 1.0) * D_PI / 16.0; node[m] = -d_cos(theta[m]); }
  double Tch[8][8] = {};
  for (int k = 0; k < 8; k++)
    for (int m = 0; m < 8; m++) Tch[k][m] = d_cos((double)k * (D_PI - theta[m]));
  int LE[4][8] = {}, RI[4][8] = {};
  float WL[4][8] = {}, WR[4][8] = {};
  for (int l = 0; l < 4; l++)
    for (int m = 0; m < 8; m++) {
      float tseg = (float)(0.25 * (double)l + 0.125 * (node[m] + 1.0));
      int ri = (int)(tseg * 127.0f) - 2; if (ri < 0) ri = 0;
      while (ri < 127 && ((float)ri * (1.0f / 127.0f)) < tseg) ri++;
      int le = ri - 1; if (le < 0) le = 0;
      float tl = (float)le * (1.0f / 127.0f), tr = (float)ri * (1.0f / 127.0f);
      float den = (tr - tl < 1e-8f) ? 1.0f : (tr - tl);
      float wr = (tseg - tl) / den;
      LE[l][m] = le; RI[l][m] = ri; WR[l][m] = wr; WL[l][m] = 1.0f - wr;
    }
  for (int p = 0; p < 2; p++)
    for (int f = 0; f < 4; f++) {
      double fval = (p == 0) ? (double)f
                             : ((f == 0) ? 0.0 : (f == 1) ? 1.0 : (f == 2) ? -2.0 : -1.0);
      double wp = fval * (2.0 * D_PI * 0.125);
      double Wr[8] = {}, Wi[8] = {};
      for (int k = 0; k < 8; k++) {
        double sr = 0.0, si = 0.0;
        for (int m = 0; m < 8; m++) {
          sr += Tch[k][m] * d_cos(node[m] * wp);
          si += Tch[k][m] * (-d_sin(node[m] * wp));
        }
        Wr[k] = sr * 0.125; Wi[k] = si * 0.125;
      }
      for (int l = 0; l < 4; l++) {
        double ph = -2.0 * D_PI * (0.25 * (double)l) * fval;
        double cr = d_cos(ph), ci = d_sin(ph);
        for (int m = 0; m < 8; m++) {
          double coefR = Wr[m] * cr - Wi[m] * ci;
          double coefI = Wr[m] * ci + Wi[m] * cr;
          int le = LE[l][m], ri = RI[l][m];
          if (p == 0) {
            T.ktab[32 + f][le] += (float)(WL[l][m] * coefR);
            T.ktab[36 + f][le] += (float)(WL[l][m] * coefI);
            T.ktab[32 + f][ri] += (float)(WR[l][m] * coefR);
            T.ktab[36 + f][ri] += (float)(WR[l][m] * coefI);
          } else {
            T.cfth[le][f]     += (float)(WL[l][m] * coefR);
            T.cfth[le][4 + f] += (float)(WL[l][m] * coefI);
            T.cfth[ri][f]     += (float)(WR[l][m] * coefR);
            T.cfth[ri][4 + f] += (float)(WR[l][m] * coefI);
          }
        }
      }
    }
  return T;
}

__constant__ Tabs g_tabs = make_tabs();

// ---------------- stage A: row DFT (16 kx modes) + CFT W-pass, fused ----------------
__global__ __launch_bounds__(256) void k_stageA(const float* __restrict__ x,
                                                float* __restrict__ xw,
                                                float* __restrict__ cft1) {
  __shared__ float tile[64 * 129];
  int t = threadIdx.x;
  const float* xblk = x + (size_t)blockIdx.x * 64 * 128;
  #pragma unroll
  for (int k2 = 0; k2 < 8; k2++) {
    int f4 = t + k2 * 256;             // 2048 float4
    int row = f4 >> 5, c4 = f4 & 31;
    const float4 v = *reinterpret_cast<const float4*>(xblk + row * 128 + c4 * 4);
    float* dst = &tile[row * 129 + c4 * 4];
    dst[0] = v.x; dst[1] = v.y; dst[2] = v.z; dst[3] = v.w;
  }
  __syncthreads();

  int p = t & 63;
  int gu = __builtin_amdgcn_readfirstlane(t >> 6);   // wave-uniform out-group 0..3
  const float* Kb = &g_tabs.ktab[0][0] + (size_t)gu * 10 * 128;
  float acc[10];
  #pragma unroll
  for (int i = 0; i < 10; i++) acc[i] = 0.f;
  const float* r0 = &tile[p * 129];
  #pragma unroll 4
  for (int w = 0; w < 128; w++) {
    float s0 = r0[w];
    #pragma unroll
    for (int i = 0; i < 10; i++) acc[i] = fmaf(s0, Kb[i * 128 + w], acc[i]);
  }

  int bc = blockIdx.x >> 1;
  int h = ((blockIdx.x & 1) << 6) + p;
  #pragma unroll
  for (int i = 0; i < 10; i++) {
    int j = gu * 10 + i;
    if (j < 32) {
      int kx = j >> 1, ri = j & 1;
      xw[(((size_t)bc * 128 + h) * 16 + kx) * 2 + ri] = acc[i];
    } else {
      cft1[((size_t)bc * 128 + h) * 8 + (j - 32)] = acc[i];
    }
  }
}

// ---------------- stage B: forward DFT over h (32 ky modes) via phasor rotation ----------------
__global__ __launch_bounds__(256) void k_stageB(const float* __restrict__ xw,
                                                float* __restrict__ xf) {
  int t = threadIdx.x;
  int bc = blockIdx.x;
  int kx = t & 15, jg = t >> 4;        // jg 0..15, j = jg*2+q
  float pr[2], pq[2], sr[2], si[2], aR[2], aI[2];
  #pragma unroll
  for (int q = 0; q < 2; q++) {
    int j = jg * 2 + q;
    int ky = (j < 16) ? j : j + 96;
    float ang = TWO_PI_F * (float)ky * (1.0f / 128.0f);
    float s, c;
    __sincosf(ang, &s, &c);
    sr[q] = c; si[q] = -s;             // e^{-2pi i ky/128}
    pr[q] = 1.f; pq[q] = 0.f; aR[q] = 0.f; aI[q] = 0.f;
  }
  const float* base = xw + (size_t)bc * 128 * 32 + kx * 2;
  for (int h = 0; h < 128; h++) {
    const float2 v = *reinterpret_cast<const float2*>(base + h * 32);
    #pragma unroll
    for (int q = 0; q < 2; q++) {
      aR[q] = fmaf(v.x, pr[q], fmaf(-v.y, pq[q], aR[q]));
      aI[q] = fmaf(v.x, pq[q], fmaf(v.y, pr[q], aI[q]));
      float npr = pr[q] * sr[q] - pq[q] * si[q];
      float npi = pr[q] * si[q] + pq[q] * sr[q];
      pr[q] = npr; pq[q] = npi;
    }
  }
  #pragma unroll
  for (int q = 0; q < 2; q++) {
    int j = jg * 2 + q;
    float2* o = reinterpret_cast<float2*>(xf + (((size_t)bc * 32 + j) * 16 + kx) * 2);
    *o = make_float2(aR[q], aI[q]);
  }
}

// ---------------- CFT H-pass: cft1 -> flat ----------------
__global__ void k_cfth(const float* __restrict__ cft1, float* __restrict__ flat) {
  int t = threadIdx.x;
  int bc = blockIdx.x * 2 + (t >> 5);
  int tt = t & 31;
  int f1 = tt >> 3, f2 = (tt >> 1) & 3, ri = tt & 1;
  const float* s = cft1 + (size_t)bc * 1024;
  float acc = 0.f;
  for (int h = 0; h < 128; h++) {
    float r = s[h * 8 + f2], im = s[h * 8 + 4 + f2];
    float kr = g_tabs.cfth[h][f1], ki = g_tabs.cfth[h][4 + f1];
    float e0 = (ri == 0) ? kr : ki;
    float e1 = (ri == 0) ? -ki : kr;
    acc = fmaf(r, e0, fmaf(im, e1, acc));
  }
  int b = bc >> 6, c = bc & 63;
  flat[(size_t)b * 2048 + ((c * 4 + f1) * 4 + f2) * 2 + ri] = acc;
}

// ---------------- MLP stage 1: flat -> hs (k-split + LDS reduce, exact-erf GELU) ----------------
__global__ __launch_bounds__(256) void k_mlp1(const float* __restrict__ flat,
                                              const float* __restrict__ w1,
                                              const float* __restrict__ b1,
                                              float* __restrict__ hs) {
  __shared__ float part[4][64];
  int bid = blockIdx.x;
  int b = bid >> 2, oc = bid & 3;
  int t = threadIdx.x;
  int ol = t & 63, kc = t >> 6;
  int o = oc * 64 + ol;
  const float* fb = flat + (size_t)b * 2048 + kc * 512;
  const float* wb = w1 + (size_t)(kc * 512) * 256 + o;
  float acc = 0.f;
  for (int k = 0; k < 512; k++) acc = fmaf(fb[k], wb[(size_t)k * 256], acc);
  part[kc][ol] = acc;
  __syncthreads();
  if (t < 64) {
    float a = part[0][t] + part[1][t] + part[2][t] + part[3][t] + b1[oc * 64 + t];
    hs[(size_t)b * 256 + oc * 64 + t] = 0.5f * a * (1.0f + erff(a * 0.70710678118654752f));
  }
}

// ---------------- MLP stage 2: hs -> corr ----------------
__global__ void k_mlp2(const float* __restrict__ hs,
                       const float* __restrict__ w2,
                       const float* __restrict__ b2,
                       float* __restrict__ corr) {
  int b = blockIdx.x, t = threadIdx.x;   // 64 threads
  const float* hb = hs + (size_t)b * 256;
  float acc = b2[t];
  for (int k = 0; k < 256; k++) acc = fmaf(hb[k], w2[(size_t)k * 64 + t], acc);
  corr[(size_t)b * 64 + t] = acc;
}

// ---------------- stage C: mode-mixing einsum over C ----------------
__global__ __launch_bounds__(256) void k_stageC(const float* __restrict__ xf,
                                                const float* __restrict__ w1,
                                                const float* __restrict__ w2,
                                                float* __restrict__ outft) {
  __shared__ float xfs[64 * 32];       // [c][kx*2+ri]
  int bid = blockIdx.x;
  int sw = (bid & 7) * 128 + (bid >> 3);   // bijective (1024 % 8 == 0)
  int j = sw >> 5, b = sw & 31;
  int t = threadIdx.x;
  #pragma unroll
  for (int k2 = 0; k2 < 4; k2++) {
    int id = t + k2 * 256;             // 1024 float2
    int c = id >> 4, kxi = id & 15;
    const float2 v = *reinterpret_cast<const float2*>(
        xf + (((size_t)b * 64 + c) * 32 + j) * 32 + kxi * 2);
    reinterpret_cast<float2*>(xfs)[id] = v;
  }
  __syncthreads();
  int kx = t & 15, og = t >> 4;
  const float* wsel = (j < 16) ? w1 : w2;
  int jr = (j < 16) ? j : j - 16;
  float aR[4], aI[4];
  #pragma unroll
  for (int i = 0; i < 4; i++) { aR[i] = 0.f; aI[i] = 0.f; }
  for (int c = 0; c < 64; c++) {
    float xr = xfs[c * 32 + kx * 2], xi = xfs[c * 32 + kx * 2 + 1];
    #pragma unroll
    for (int i = 0; i < 4; i++) {
      int o = og * 4 + i;
      const float2 wv = *reinterpret_cast<const float2*>(
          wsel + ((((size_t)c * 64 + o) * 16 + jr) * 16 + kx) * 2);
      aR[i] = fmaf(xr, wv.x, fmaf(-xi, wv.y, aR[i]));
      aI[i] = fmaf(xr, wv.y, fmaf(xi, wv.x, aI[i]));
    }
  }
  #pragma unroll
  for (int i = 0; i < 4; i++) {
    int o = og * 4 + i;
    float2* dst = reinterpret_cast<float2*>(outft + (((size_t)b * 64 + o) * 32 + j) * 32 + kx * 2);
    *dst = make_float2(aR[i], aI[i]);
  }
}

// ---------------- stage D: inverse DFT over ky (32 modes -> 128 h), 1/H folded ----------------
__global__ __launch_bounds__(256) void k_stageD(const float* __restrict__ outft,
                                                float* __restrict__ y) {
  int bo = blockIdx.x;
  int t = threadIdx.x;
  int kx = t & 15, hg = t >> 4;
  int h0 = hg * 8;
  float aR[8], aI[8];
  #pragma unroll
  for (int k = 0; k < 8; k++) { aR[k] = 0.f; aI[k] = 0.f; }
  const float* src = outft + (size_t)bo * 1024 + kx * 2;
  for (int jj = 0; jj < 32; jj++) {
    const float2 c = *reinterpret_cast<const float2*>(src + jj * 32);
    int ky = (jj < 16) ? jj : jj + 96;
    int r0 = (ky * h0) & 127;
    float angb = TWO_PI_F * (1.0f / 128.0f) * (float)r0;
    float br, bi;
    __sincosf(angb, &bi, &br);                  // e^{+2pi i ky h0/128}
    float angs = TWO_PI_F * (1.0f / 128.0f) * (float)(ky & 127);
    float sti, strr;
    __sincosf(angs, &sti, &strr);               // e^{+2pi i ky/128}
    #pragma unroll
    for (int k = 0; k < 8; k++) {
      aR[k] = fmaf(c.x, br, fmaf(-c.y, bi, aR[k]));
      aI[k] = fmaf(c.x, bi, fmaf(c.y, br, aI[k]));
      float nbr = br * strr - bi * sti;
      float nbi = br * sti + bi * strr;
      br = nbr; bi = nbi;
    }
  }
  float* dst = y + ((size_t)bo * 128 + h0) * 32 + kx * 2;
  #pragma unroll
  for (int k = 0; k < 8; k++) {
    *reinterpret_cast<float2*>(dst + k * 32) =
        make_float2(aR[k] * 0.0078125f, aI[k] * 0.0078125f);
  }
}

// ---------------- stage E: inverse rfft over w + corr ----------------
// Each thread: one row-load serves TWO outputs (w, w+64) via (-1)^kx symmetry.
__global__ __launch_bounds__(256) void k_stageE(const float* __restrict__ y,
                                                const float* __restrict__ corr,
                                                float* __restrict__ out) {
  int bo = blockIdx.x;
  int t = threadIdx.x;
  int w0 = t & 63, grp = t >> 6;       // grp wave-uniform
  float cph[16], sph[16];
  cph[0] = 1.f; sph[0] = 0.f;
  #pragma unroll
  for (int kx = 1; kx < 16; kx++) {
    int r = (kx * w0) & 127;
    float ang = TWO_PI_F * (1.0f / 128.0f) * (float)r;
    float s, c;
    __sincosf(ang, &s, &c);
    cph[kx] = 2.0f * c; sph[kx] = 2.0f * s;   // fold the 2x of c2r symmetry
  }
  float corrv = corr[bo];
  const float* ybase = y + (size_t)bo * 4096;
  float* obase = out + (size_t)bo * 16384;
  for (int k = 0; k < 32; k++) {
    int h = 4 * k + grp;
    const float4* yr4 = reinterpret_cast<const float4*>(ybase + h * 32);
    float r[32];
    #pragma unroll
    for (int i = 0; i < 8; i++) {
      float4 v = yr4[i];
      r[4 * i] = v.x; r[4 * i + 1] = v.y; r[4 * i + 2] = v.z; r[4 * i + 3] = v.w;
    }
    float acc0 = r[0], acc1 = r[0];    // DC: real part only (c2r semantics)
    #pragma unroll
    for (int kx = 1; kx < 16; kx++) {
      float term = r[2 * kx] * cph[kx];
      term = fmaf(-r[2 * kx + 1], sph[kx], term);
      acc0 += term;
      if (kx & 1) acc1 -= term; else acc1 += term;
    }
    obase[h * 128 + w0]      = fmaf(acc0, 0.0078125f, corrv);
    obase[h * 128 + w0 + 64] = fmaf(acc1, 0.0078125f, corrv);
  }
}

extern "C" void kernel_launch(void* const* d_in, const int* in_sizes, int n_in,
                              void* d_out, int out_size, void* d_ws, size_t ws_size,
                              hipStream_t stream) {
  const float* x   = (const float*)d_in[0];
  const float* w1  = (const float*)d_in[1];
  const float* w2  = (const float*)d_in[2];
  const float* l1w = (const float*)d_in[3];
  const float* l1b = (const float*)d_in[4];
  const float* l2w = (const float*)d_in[5];
  const float* l2b = (const float*)d_in[6];
  float* out = (float*)d_out;
  float* ws  = (float*)d_ws;

  float* flat  = ws + WSO_FLAT;
  float* corr  = ws + WSO_CORR;
  float* hs    = ws + WSO_HS;
  float* cft1  = ws + WSO_CFT1;
  float* xf    = ws + WSO_XF;
  float* y     = ws + WSO_Y;
  float* outft = ws + WSO_OUTFT;
  float* xw    = out;   // d_out used as scratch for xw; fully rewritten by stage E

  k_stageA<<<dim3(4096), dim3(256), 0, stream>>>(x, xw, cft1);
  k_stageB<<<dim3(2048), dim3(256), 0, stream>>>(xw, xf);
  k_cfth<<<dim3(1024), dim3(64), 0, stream>>>(cft1, flat);
  k_mlp1<<<dim3(128), dim3(256), 0, stream>>>(flat, l1w, l1b, hs);
  k_mlp2<<<dim3(32), dim3(64), 0, stream>>>(hs, l2w, l2b, corr);
  k_stageC<<<dim3(1024), dim3(256), 0, stream>>>(xf, w1, w2, outft);
  k_stageD<<<dim3(2048), dim3(256), 0, stream>>>(outft, y);
  k_stageE<<<dim3(2048), dim3(256), 0, stream>>>(y, corr, out);
}

// Round 5
// 311.469 us; speedup vs baseline: 1.8702x; 1.0572x over previous
//
#include <hip/hip_runtime.h>
#include <math.h>

#define PI_F 3.14159265358979323846f
#define TWO_PI_F 6.28318530717958647692f

// problem sizes
constexpr int Bn = 32, Cn = 64, On = 64, Hn = 128, Wn = 128;

// workspace float offsets (small region < WSO_BIG)
constexpr size_t WSO_FLAT  = 0;                        // 32*2048 = 65536
constexpr size_t WSO_CORR  = 65536;                    // 32*64   = 2048
constexpr size_t WSO_HS    = 67584;                    // 32*256  = 8192 (ends 75776)
constexpr size_t WSO_BIG   = 81920;
constexpr size_t SZ_QTR    = (size_t)2097152;          // 2M floats
constexpr size_t WSO_CFT1  = WSO_BIG;                  // [2048][128][8]
constexpr size_t WSO_XF    = WSO_BIG + SZ_QTR;         // [32][64][32][16][2]
constexpr size_t WSO_Y     = WSO_BIG;                  // alias: cft1+xf dead by stage D
constexpr size_t WSO_OUTFT = WSO_BIG + 4 * SZ_QTR;     // [32][64][32][16][2]

// ================= compile-time tables =================
// ktw[w][j]: j=2kx+0 -> cos, j=2kx+1 -> -sin of 2*pi*kx*w/128 (j<32);
//            j=32+f real CFT-W, j=36+f imag CFT-W.  (TRANSPOSED: contiguous over j)
// cfth[w][f(0..3)]=real, [w][4+f]=imag, fsel = {0,1,-2,-1}
struct Tabs {
  float ktw[128][40];
  float cfth[128][8];
};

constexpr double D_PI = 3.14159265358979323846;

constexpr double d_red(double x) {
  while (x >  D_PI) x -= 2.0 * D_PI;
  while (x < -D_PI) x += 2.0 * D_PI;
  return x;
}
constexpr double d_sin(double x) {
  x = d_red(x);
  double x2 = x * x, t = x, s = x;
  for (int n = 1; n <= 10; n++) { t *= -x2 / (double)((2 * n) * (2 * n + 1)); s += t; }
  return s;
}
constexpr double d_cos(double x) {
  x = d_red(x);
  double x2 = x * x, t = 1.0, s = 1.0;
  for (int n = 1; n <= 10; n++) { t *= -x2 / (double)((2 * n - 1) * (2 * n)); s += t; }
  return s;
}

constexpr Tabs make_tabs() {
  Tabs T{};
  double twc[128] = {}, tws[128] = {};
  for (int r = 0; r < 128; r++) {
    double a = 2.0 * D_PI * (double)r / 128.0;
    twc[r] = d_cos(a); tws[r] = d_sin(a);
  }
  for (int kx = 0; kx < 16; kx++)
    for (int w = 0; w < 128; w++) {
      int r = (kx * w) & 127;
      T.ktw[w][2 * kx]     = (float)twc[r];
      T.ktw[w][2 * kx + 1] = (float)(-tws[r]);
    }
  double node[8] = {}, theta[8] = {};
  for (int m = 0; m < 8; m++) { theta[m] = (2.0 * m + 1.0) * D_PI / 16.0; node[m] = -d_cos(theta[m]); }
  double Tch[8][8] = {};
  for (int k = 0; k < 8; k++)
    for (int m = 0; m < 8; m++) Tch[k][m] = d_cos((double)k * (D_PI - theta[m]));
  int LE[4][8] = {}, RI[4][8] = {};
  float WL[4][8] = {}, WR[4][8] = {};
  for (int l = 0; l < 4; l++)
    for (int m = 0; m < 8; m++) {
      float tseg = (float)(0.25 * (double)l + 0.125 * (node[m] + 1.0));
      int ri = (int)(tseg * 127.0f) - 2; if (ri < 0) ri = 0;
      while (ri < 127 && ((float)ri * (1.0f / 127.0f)) < tseg) ri++;
      int le = ri - 1; if (le < 0) le = 0;
      float tl = (float)le * (1.0f / 127.0f), tr = (float)ri * (1.0f / 127.0f);
      float den = (tr - tl < 1e-8f) ? 1.0f : (tr - tl);
      float wr = (tseg - tl) / den;
      LE[l][m] = le; RI[l][m] = ri; WR[l][m] = wr; WL[l][m] = 1.0f - wr;
    }
  for (int p = 0; p < 2; p++)
    for (int f = 0; f < 4; f++) {
      double fval = (p == 0) ? (double)f
                             : ((f == 0) ? 0.0 : (f == 1) ? 1.0 : (f == 2) ? -2.0 : -1.0);
      double wp = fval * (2.0 * D_PI * 0.125);
      double Wr[8] = {}, Wi[8] = {};
      for (int k = 0; k < 8; k++) {
        double sr = 0.0, si = 0.0;
        for (int m = 0; m < 8; m++) {
          sr += Tch[k][m] * d_cos(node[m] * wp);
          si += Tch[k][m] * (-d_sin(node[m] * wp));
        }
        Wr[k] = sr * 0.125; Wi[k] = si * 0.125;
      }
      for (int l = 0; l < 4; l++) {
        double ph = -2.0 * D_PI * (0.25 * (double)l) * fval;
        double cr = d_cos(ph), ci = d_sin(ph);
        for (int m = 0; m < 8; m++) {
          double coefR = Wr[m] * cr - Wi[m] * ci;
          double coefI = Wr[m] * ci + Wi[m] * cr;
          int le = LE[l][m], ri = RI[l][m];
          if (p == 0) {
            T.ktw[le][32 + f] += (float)(WL[l][m] * coefR);
            T.ktw[le][36 + f] += (float)(WL[l][m] * coefI);
            T.ktw[ri][32 + f] += (float)(WR[l][m] * coefR);
            T.ktw[ri][36 + f] += (float)(WR[l][m] * coefI);
          } else {
            T.cfth[le][f]     += (float)(WL[l][m] * coefR);
            T.cfth[le][4 + f] += (float)(WL[l][m] * coefI);
            T.cfth[ri][f]     += (float)(WR[l][m] * coefR);
            T.cfth[ri][4 + f] += (float)(WR[l][m] * coefI);
          }
        }
      }
    }
  return T;
}

__constant__ Tabs g_tabs = make_tabs();

// ---------------- stage A: row DFT (16 kx modes) + CFT W-pass, fused ----------------
// One thread per row. Row chunk in VGPRs (float4 loads); twiddles wave-uniform
// from __constant__ (s_load_dwordx16 blocks, scalar pipe); acc[40] statically
// indexed. No LDS, no barriers. Coalesced float4 row-major writes.
__global__ __launch_bounds__(256) void k_stageA(const float* __restrict__ x,
                                                float* __restrict__ xw,
                                                float* __restrict__ cft1) {
  size_t row = (size_t)blockIdx.x * 256 + threadIdx.x;   // 262144 rows
  const float* xr = x + row * 128;
  float acc[40];
  #pragma unroll
  for (int j = 0; j < 40; j++) acc[j] = 0.f;
  for (int wc = 0; wc < 128; wc += 8) {
    float4 v0 = *reinterpret_cast<const float4*>(xr + wc);
    float4 v1 = *reinterpret_cast<const float4*>(xr + wc + 4);
    float xv[8] = {v0.x, v0.y, v0.z, v0.w, v1.x, v1.y, v1.z, v1.w};
    #pragma unroll
    for (int wi = 0; wi < 8; wi++) {
      #pragma unroll
      for (int j = 0; j < 40; j++)
        acc[j] = fmaf(xv[wi], g_tabs.ktw[wc + wi][j], acc[j]);
    }
  }
  float4* xo = reinterpret_cast<float4*>(xw + row * 32);
  #pragma unroll
  for (int i = 0; i < 8; i++)
    xo[i] = make_float4(acc[4 * i], acc[4 * i + 1], acc[4 * i + 2], acc[4 * i + 3]);
  float4* co = reinterpret_cast<float4*>(cft1 + row * 8);
  co[0] = make_float4(acc[32], acc[33], acc[34], acc[35]);
  co[1] = make_float4(acc[36], acc[37], acc[38], acc[39]);
}

// ---------------- stage B: forward DFT over h (32 ky modes) via phasor rotation ----------------
__global__ __launch_bounds__(256) void k_stageB(const float* __restrict__ xw,
                                                float* __restrict__ xf) {
  int t = threadIdx.x;
  int bc = blockIdx.x;
  int kx = t & 15, jg = t >> 4;        // jg 0..15, j = jg*2+q
  float pr[2], pq[2], sr[2], si[2], aR[2], aI[2];
  #pragma unroll
  for (int q = 0; q < 2; q++) {
    int j = jg * 2 + q;
    int ky = (j < 16) ? j : j + 96;
    float ang = TWO_PI_F * (float)ky * (1.0f / 128.0f);
    float s, c;
    __sincosf(ang, &s, &c);
    sr[q] = c; si[q] = -s;             // e^{-2pi i ky/128}
    pr[q] = 1.f; pq[q] = 0.f; aR[q] = 0.f; aI[q] = 0.f;
  }
  const float* base = xw + (size_t)bc * 128 * 32 + kx * 2;
  for (int h = 0; h < 128; h++) {
    const float2 v = *reinterpret_cast<const float2*>(base + h * 32);
    #pragma unroll
    for (int q = 0; q < 2; q++) {
      aR[q] = fmaf(v.x, pr[q], fmaf(-v.y, pq[q], aR[q]));
      aI[q] = fmaf(v.x, pq[q], fmaf(v.y, pr[q], aI[q]));
      float npr = pr[q] * sr[q] - pq[q] * si[q];
      float npi = pr[q] * si[q] + pq[q] * sr[q];
      pr[q] = npr; pq[q] = npi;
    }
  }
  #pragma unroll
  for (int q = 0; q < 2; q++) {
    int j = jg * 2 + q;
    float2* o = reinterpret_cast<float2*>(xf + (((size_t)bc * 32 + j) * 16 + kx) * 2);
    *o = make_float2(aR[q], aI[q]);
  }
}

// ---------------- CFT H-pass: cft1 -> flat ----------------
__global__ void k_cfth(const float* __restrict__ cft1, float* __restrict__ flat) {
  int t = threadIdx.x;
  int bc = blockIdx.x * 2 + (t >> 5);
  int tt = t & 31;
  int f1 = tt >> 3, f2 = (tt >> 1) & 3, ri = tt & 1;
  const float* s = cft1 + (size_t)bc * 1024;
  float acc = 0.f;
  for (int h = 0; h < 128; h++) {
    float r = s[h * 8 + f2], im = s[h * 8 + 4 + f2];
    float kr = g_tabs.cfth[h][f1], ki = g_tabs.cfth[h][4 + f1];
    float e0 = (ri == 0) ? kr : ki;
    float e1 = (ri == 0) ? -ki : kr;
    acc = fmaf(r, e0, fmaf(im, e1, acc));
  }
  int b = bc >> 6, c = bc & 63;
  flat[(size_t)b * 2048 + ((c * 4 + f1) * 4 + f2) * 2 + ri] = acc;
}

// ---------------- MLP stage 1: flat -> hs (k-split + LDS reduce, exact-erf GELU) ----------------
__global__ __launch_bounds__(256) void k_mlp1(const float* __restrict__ flat,
                                              const float* __restrict__ w1,
                                              const float* __restrict__ b1,
                                              float* __restrict__ hs) {
  __shared__ float part[4][64];
  int bid = blockIdx.x;
  int b = bid >> 2, oc = bid & 3;
  int t = threadIdx.x;
  int ol = t & 63, kc = t >> 6;
  int o = oc * 64 + ol;
  const float* fb = flat + (size_t)b * 2048 + kc * 512;
  const float* wb = w1 + (size_t)(kc * 512) * 256 + o;
  float acc = 0.f;
  for (int k = 0; k < 512; k++) acc = fmaf(fb[k], wb[(size_t)k * 256], acc);
  part[kc][ol] = acc;
  __syncthreads();
  if (t < 64) {
    float a = part[0][t] + part[1][t] + part[2][t] + part[3][t] + b1[oc * 64 + t];
    hs[(size_t)b * 256 + oc * 64 + t] = 0.5f * a * (1.0f + erff(a * 0.70710678118654752f));
  }
}

// ---------------- MLP stage 2: hs -> corr ----------------
__global__ void k_mlp2(const float* __restrict__ hs,
                       const float* __restrict__ w2,
                       const float* __restrict__ b2,
                       float* __restrict__ corr) {
  int b = blockIdx.x, t = threadIdx.x;   // 64 threads
  const float* hb = hs + (size_t)b * 256;
  float acc = b2[t];
  for (int k = 0; k < 256; k++) acc = fmaf(hb[k], w2[(size_t)k * 64 + t], acc);
  corr[(size_t)b * 64 + t] = acc;
}

// ---------------- stage C: mode-mixing einsum over C ----------------
__global__ __launch_bounds__(256) void k_stageC(const float* __restrict__ xf,
                                                const float* __restrict__ w1,
                                                const float* __restrict__ w2,
                                                float* __restrict__ outft) {
  __shared__ float xfs[64 * 32];       // [c][kx*2+ri]
  int bid = blockIdx.x;
  int sw = (bid & 7) * 128 + (bid >> 3);   // bijective (1024 % 8 == 0)
  int j = sw >> 5, b = sw & 31;
  int t = threadIdx.x;
  #pragma unroll
  for (int k2 = 0; k2 < 4; k2++) {
    int id = t + k2 * 256;             // 1024 float2
    int c = id >> 4, kxi = id & 15;
    const float2 v = *reinterpret_cast<const float2*>(
        xf + (((size_t)b * 64 + c) * 32 + j) * 32 + kxi * 2);
    reinterpret_cast<float2*>(xfs)[id] = v;
  }
  __syncthreads();
  int kx = t & 15, og = t >> 4;
  const float* wsel = (j < 16) ? w1 : w2;
  int jr = (j < 16) ? j : j - 16;
  float aR[4], aI[4];
  #pragma unroll
  for (int i = 0; i < 4; i++) { aR[i] = 0.f; aI[i] = 0.f; }
  for (int c = 0; c < 64; c++) {
    float xr = xfs[c * 32 + kx * 2], xi = xfs[c * 32 + kx * 2 + 1];
    #pragma unroll
    for (int i = 0; i < 4; i++) {
      int o = og * 4 + i;
      const float2 wv = *reinterpret_cast<const float2*>(
          wsel + ((((size_t)c * 64 + o) * 16 + jr) * 16 + kx) * 2);
      aR[i] = fmaf(xr, wv.x, fmaf(-xi, wv.y, aR[i]));
      aI[i] = fmaf(xr, wv.y, fmaf(xi, wv.x, aI[i]));
    }
  }
  #pragma unroll
  for (int i = 0; i < 4; i++) {
    int o = og * 4 + i;
    float2* dst = reinterpret_cast<float2*>(outft + (((size_t)b * 64 + o) * 32 + j) * 32 + kx * 2);
    *dst = make_float2(aR[i], aI[i]);
  }
}

// ---------------- stage D: inverse DFT over ky (32 modes -> 128 h), 1/H folded ----------------
__global__ __launch_bounds__(256) void k_stageD(const float* __restrict__ outft,
                                                float* __restrict__ y) {
  int bo = blockIdx.x;
  int t = threadIdx.x;
  int kx = t & 15, hg = t >> 4;
  int h0 = hg * 8;
  float aR[8], aI[8];
  #pragma unroll
  for (int k = 0; k < 8; k++) { aR[k] = 0.f; aI[k] = 0.f; }
  const float* src = outft + (size_t)bo * 1024 + kx * 2;
  for (int jj = 0; jj < 32; jj++) {
    const float2 c = *reinterpret_cast<const float2*>(src + jj * 32);
    int ky = (jj < 16) ? jj : jj + 96;
    int r0 = (ky * h0) & 127;
    float angb = TWO_PI_F * (1.0f / 128.0f) * (float)r0;
    float br, bi;
    __sincosf(angb, &bi, &br);                  // e^{+2pi i ky h0/128}
    float angs = TWO_PI_F * (1.0f / 128.0f) * (float)(ky & 127);
    float sti, strr;
    __sincosf(angs, &sti, &strr);               // e^{+2pi i ky/128}
    #pragma unroll
    for (int k = 0; k < 8; k++) {
      aR[k] = fmaf(c.x, br, fmaf(-c.y, bi, aR[k]));
      aI[k] = fmaf(c.x, bi, fmaf(c.y, br, aI[k]));
      float nbr = br * strr - bi * sti;
      float nbi = br * sti + bi * strr;
      br = nbr; bi = nbi;
    }
  }
  float* dst = y + ((size_t)bo * 128 + h0) * 32 + kx * 2;
  #pragma unroll
  for (int k = 0; k < 8; k++) {
    *reinterpret_cast<float2*>(dst + k * 32) =
        make_float2(aR[k] * 0.0078125f, aI[k] * 0.0078125f);
  }
}

// ---------------- stage E: inverse rfft over w + corr ----------------
// Each thread: one row-load serves TWO outputs (w, w+64) via (-1)^kx symmetry.
__global__ __launch_bounds__(256) void k_stageE(const float* __restrict__ y,
                                                const float* __restrict__ corr,
                                                float* __restrict__ out) {
  int bo = blockIdx.x;
  int t = threadIdx.x;
  int w0 = t & 63, grp = t >> 6;       // grp wave-uniform
  float cph[16], sph[16];
  cph[0] = 1.f; sph[0] = 0.f;
  #pragma unroll
  for (int kx = 1; kx < 16; kx++) {
    int r = (kx * w0) & 127;
    float ang = TWO_PI_F * (1.0f / 128.0f) * (float)r;
    float s, c;
    __sincosf(ang, &s, &c);
    cph[kx] = 2.0f * c; sph[kx] = 2.0f * s;   // fold the 2x of c2r symmetry
  }
  float corrv = corr[bo];
  const float* ybase = y + (size_t)bo * 4096;
  float* obase = out + (size_t)bo * 16384;
  for (int k = 0; k < 32; k++) {
    int h = 4 * k + grp;
    const float4* yr4 = reinterpret_cast<const float4*>(ybase + h * 32);
    float r[32];
    #pragma unroll
    for (int i = 0; i < 8; i++) {
      float4 v = yr4[i];
      r[4 * i] = v.x; r[4 * i + 1] = v.y; r[4 * i + 2] = v.z; r[4 * i + 3] = v.w;
    }
    float acc0 = r[0], acc1 = r[0];    // DC: real part only (c2r semantics)
    #pragma unroll
    for (int kx = 1; kx < 16; kx++) {
      float term = r[2 * kx] * cph[kx];
      term = fmaf(-r[2 * kx + 1], sph[kx], term);
      acc0 += term;
      if (kx & 1) acc1 -= term; else acc1 += term;
    }
    obase[h * 128 + w0]      = fmaf(acc0, 0.0078125f, corrv);
    obase[h * 128 + w0 + 64] = fmaf(acc1, 0.0078125f, corrv);
  }
}

extern "C" void kernel_launch(void* const* d_in, const int* in_sizes, int n_in,
                              void* d_out, int out_size, void* d_ws, size_t ws_size,
                              hipStream_t stream) {
  const float* x   = (const float*)d_in[0];
  const float* w1  = (const float*)d_in[1];
  const float* w2  = (const float*)d_in[2];
  const float* l1w = (const float*)d_in[3];
  const float* l1b = (const float*)d_in[4];
  const float* l2w = (const float*)d_in[5];
  const float* l2b = (const float*)d_in[6];
  float* out = (float*)d_out;
  float* ws  = (float*)d_ws;

  float* flat  = ws + WSO_FLAT;
  float* corr  = ws + WSO_CORR;
  float* hs    = ws + WSO_HS;
  float* cft1  = ws + WSO_CFT1;
  float* xf    = ws + WSO_XF;
  float* y     = ws + WSO_Y;
  float* outft = ws + WSO_OUTFT;
  float* xw    = out;   // d_out used as scratch for xw; fully rewritten by stage E

  k_stageA<<<dim3(1024), dim3(256), 0, stream>>>(x, xw, cft1);
  k_stageB<<<dim3(2048), dim3(256), 0, stream>>>(xw, xf);
  k_cfth<<<dim3(1024), dim3(64), 0, stream>>>(cft1, flat);
  k_mlp1<<<dim3(128), dim3(256), 0, stream>>>(flat, l1w, l1b, hs);
  k_mlp2<<<dim3(32), dim3(64), 0, stream>>>(hs, l2w, l2b, corr);
  k_stageC<<<dim3(1024), dim3(256), 0, stream>>>(xf, w1, w2, outft);
  k_stageD<<<dim3(2048), dim3(256), 0, stream>>>(outft, y);
  k_stageE<<<dim3(2048), dim3(256), 0, stream>>>(y, corr, out);
}

// Round 6
// 260.355 us; speedup vs baseline: 2.2374x; 1.1963x over previous
//
#include <hip/hip_runtime.h>
#include <math.h>

#define PI_F 3.14159265358979323846f
#define TWO_PI_F 6.28318530717958647692f

// problem sizes
constexpr int Bn = 32, Cn = 64, On = 64, Hn = 128, Wn = 128;

// workspace float offsets (small region < WSO_BIG)
constexpr size_t WSO_FLAT  = 0;                        // 32*2048 = 65536
constexpr size_t WSO_CORR  = 65536;                    // 32*64   = 2048
constexpr size_t WSO_HS    = 67584;                    // 32*256  = 8192 (ends 75776)
constexpr size_t WSO_BIG   = 81920;
constexpr size_t SZ_QTR    = (size_t)2097152;          // 2M floats
constexpr size_t WSO_CFT1  = WSO_BIG;                  // [2048][128][8]
constexpr size_t WSO_XF    = WSO_BIG + SZ_QTR;         // [32][64][32][16][2]
constexpr size_t WSO_OUTFT = WSO_BIG + 4 * SZ_QTR;     // [32][64][32][16][2]

// ================= compile-time tables =================
// ktw[w][j]: j=2kx+0 -> cos, j=2kx+1 -> -sin of 2*pi*kx*w/128 (j<32);
//            j=32+f real CFT-W, j=36+f imag CFT-W.  (TRANSPOSED: contiguous over j)
// cfth[w][f(0..3)]=real, [w][4+f]=imag, fsel = {0,1,-2,-1}
struct Tabs {
  float ktw[128][40];
  float cfth[128][8];
};

constexpr double D_PI = 3.14159265358979323846;

constexpr double d_red(double x) {
  while (x >  D_PI) x -= 2.0 * D_PI;
  while (x < -D_PI) x += 2.0 * D_PI;
  return x;
}
constexpr double d_sin(double x) {
  x = d_red(x);
  double x2 = x * x, t = x, s = x;
  for (int n = 1; n <= 10; n++) { t *= -x2 / (double)((2 * n) * (2 * n + 1)); s += t; }
  return s;
}
constexpr double d_cos(double x) {
  x = d_red(x);
  double x2 = x * x, t = 1.0, s = 1.0;
  for (int n = 1; n <= 10; n++) { t *= -x2 / (double)((2 * n - 1) * (2 * n)); s += t; }
  return s;
}

constexpr Tabs make_tabs() {
  Tabs T{};
  double twc[128] = {}, tws[128] = {};
  for (int r = 0; r < 128; r++) {
    double a = 2.0 * D_PI * (double)r / 128.0;
    twc[r] = d_cos(a); tws[r] = d_sin(a);
  }
  for (int kx = 0; kx < 16; kx++)
    for (int w = 0; w < 128; w++) {
      int r = (kx * w) & 127;
      T.ktw[w][2 * kx]     = (float)twc[r];
      T.ktw[w][2 * kx + 1] = (float)(-tws[r]);
    }
  double node[8] = {}, theta[8] = {};
  for (int m = 0; m < 8; m++) { theta[m] = (2.0 * m + 1.0) * D_PI / 16.0; node[m] = -d_cos(theta[m]); }
  double Tch[8][8] = {};
  for (int k = 0; k < 8; k++)
    for (int m = 0; m < 8; m++) Tch[k][m] = d_cos((double)k * (D_PI - theta[m]));
  int LE[4][8] = {}, RI[4][8] = {};
  float WL[4][8] = {}, WR[4][8] = {};
  for (int l = 0; l < 4; l++)
    for (int m = 0; m < 8; m++) {
      float tseg = (float)(0.25 * (double)l + 0.125 * (node[m] + 1.0));
      int ri = (int)(tseg * 127.0f) - 2; if (ri < 0) ri = 0;
      while (ri < 127 && ((float)ri * (1.0f / 127.0f)) < tseg) ri++;
      int le = ri - 1; if (le < 0) le = 0;
      float tl = (float)le * (1.0f / 127.0f), tr = (float)ri * (1.0f / 127.0f);
      float den = (tr - tl < 1e-8f) ? 1.0f : (tr - tl);
      float wr = (tseg - tl) / den;
      LE[l][m] = le; RI[l][m] = ri; WR[l][m] = wr; WL[l][m] = 1.0f - wr;
    }
  for (int p = 0; p < 2; p++)
    for (int f = 0; f < 4; f++) {
      double fval = (p == 0) ? (double)f
                             : ((f == 0) ? 0.0 : (f == 1) ? 1.0 : (f == 2) ? -2.0 : -1.0);
      double wp = fval * (2.0 * D_PI * 0.125);
      double Wr[8] = {}, Wi[8] = {};
      for (int k = 0; k < 8; k++) {
        double sr = 0.0, si = 0.0;
        for (int m = 0; m < 8; m++) {
          sr += Tch[k][m] * d_cos(node[m] * wp);
          si += Tch[k][m] * (-d_sin(node[m] * wp));
        }
        Wr[k] = sr * 0.125; Wi[k] = si * 0.125;
      }
      for (int l = 0; l < 4; l++) {
        double ph = -2.0 * D_PI * (0.25 * (double)l) * fval;
        double cr = d_cos(ph), ci = d_sin(ph);
        for (int m = 0; m < 8; m++) {
          double coefR = Wr[m] * cr - Wi[m] * ci;
          double coefI = Wr[m] * ci + Wi[m] * cr;
          int le = LE[l][m], ri = RI[l][m];
          if (p == 0) {
            T.ktw[le][32 + f] += (float)(WL[l][m] * coefR);
            T.ktw[le][36 + f] += (float)(WL[l][m] * coefI);
            T.ktw[ri][32 + f] += (float)(WR[l][m] * coefR);
            T.ktw[ri][36 + f] += (float)(WR[l][m] * coefI);
          } else {
            T.cfth[le][f]     += (float)(WL[l][m] * coefR);
            T.cfth[le][4 + f] += (float)(WL[l][m] * coefI);
            T.cfth[ri][f]     += (float)(WR[l][m] * coefR);
            T.cfth[ri][4 + f] += (float)(WR[l][m] * coefI);
          }
        }
      }
    }
  return T;
}

__constant__ Tabs g_tabs = make_tabs();

// ---------------- stage A: row DFT (16 kx modes) + CFT W-pass, fused ----------------
// One thread per row. Row chunk in VGPRs (float4 loads); twiddles wave-uniform
// from __constant__ (scalar pipe); acc[40] statically indexed. No LDS/barriers.
__global__ __launch_bounds__(256) void k_stageA(const float* __restrict__ x,
                                                float* __restrict__ xw,
                                                float* __restrict__ cft1) {
  size_t row = (size_t)blockIdx.x * 256 + threadIdx.x;   // 262144 rows
  const float* xr = x + row * 128;
  float acc[40];
  #pragma unroll
  for (int j = 0; j < 40; j++) acc[j] = 0.f;
  for (int wc = 0; wc < 128; wc += 8) {
    float4 v0 = *reinterpret_cast<const float4*>(xr + wc);
    float4 v1 = *reinterpret_cast<const float4*>(xr + wc + 4);
    float xv[8] = {v0.x, v0.y, v0.z, v0.w, v1.x, v1.y, v1.z, v1.w};
    #pragma unroll
    for (int wi = 0; wi < 8; wi++) {
      #pragma unroll
      for (int j = 0; j < 40; j++)
        acc[j] = fmaf(xv[wi], g_tabs.ktw[wc + wi][j], acc[j]);
    }
  }
  float4* xo = reinterpret_cast<float4*>(xw + row * 32);
  #pragma unroll
  for (int i = 0; i < 8; i++)
    xo[i] = make_float4(acc[4 * i], acc[4 * i + 1], acc[4 * i + 2], acc[4 * i + 3]);
  float4* co = reinterpret_cast<float4*>(cft1 + row * 8);
  co[0] = make_float4(acc[32], acc[33], acc[34], acc[35]);
  co[1] = make_float4(acc[36], acc[37], acc[38], acc[39]);
}

// ---------------- stage B: forward DFT over h (32 ky modes) via phasor rotation ----------------
__global__ __launch_bounds__(256) void k_stageB(const float* __restrict__ xw,
                                                float* __restrict__ xf) {
  int t = threadIdx.x;
  int bc = blockIdx.x;
  int kx = t & 15, jg = t >> 4;        // jg 0..15, j = jg*2+q
  float pr[2], pq[2], sr[2], si[2], aR[2], aI[2];
  #pragma unroll
  for (int q = 0; q < 2; q++) {
    int j = jg * 2 + q;
    int ky = (j < 16) ? j : j + 96;
    float ang = TWO_PI_F * (float)ky * (1.0f / 128.0f);
    float s, c;
    __sincosf(ang, &s, &c);
    sr[q] = c; si[q] = -s;             // e^{-2pi i ky/128}
    pr[q] = 1.f; pq[q] = 0.f; aR[q] = 0.f; aI[q] = 0.f;
  }
  const float* base = xw + (size_t)bc * 128 * 32 + kx * 2;
  for (int h = 0; h < 128; h++) {
    const float2 v = *reinterpret_cast<const float2*>(base + h * 32);
    #pragma unroll
    for (int q = 0; q < 2; q++) {
      aR[q] = fmaf(v.x, pr[q], fmaf(-v.y, pq[q], aR[q]));
      aI[q] = fmaf(v.x, pq[q], fmaf(v.y, pr[q], aI[q]));
      float npr = pr[q] * sr[q] - pq[q] * si[q];
      float npi = pr[q] * si[q] + pq[q] * sr[q];
      pr[q] = npr; pq[q] = npi;
    }
  }
  #pragma unroll
  for (int q = 0; q < 2; q++) {
    int j = jg * 2 + q;
    float2* o = reinterpret_cast<float2*>(xf + (((size_t)bc * 32 + j) * 16 + kx) * 2);
    *o = make_float2(aR[q], aI[q]);
  }
}

// ---------------- CFT H-pass: cft1 -> flat ----------------
__global__ void k_cfth(const float* __restrict__ cft1, float* __restrict__ flat) {
  int t = threadIdx.x;
  int bc = blockIdx.x * 2 + (t >> 5);
  int tt = t & 31;
  int f1 = tt >> 3, f2 = (tt >> 1) & 3, ri = tt & 1;
  const float* s = cft1 + (size_t)bc * 1024;
  float acc = 0.f;
  for (int h = 0; h < 128; h++) {
    float r = s[h * 8 + f2], im = s[h * 8 + 4 + f2];
    float kr = g_tabs.cfth[h][f1], ki = g_tabs.cfth[h][4 + f1];
    float e0 = (ri == 0) ? kr : ki;
    float e1 = (ri == 0) ? -ki : kr;
    acc = fmaf(r, e0, fmaf(im, e1, acc));
  }
  int b = bc >> 6, c = bc & 63;
  flat[(size_t)b * 2048 + ((c * 4 + f1) * 4 + f2) * 2 + ri] = acc;
}

// ---------------- MLP stage 1: flat -> hs (k-split + LDS reduce, exact-erf GELU) ----------------
__global__ __launch_bounds__(256) void k_mlp1(const float* __restrict__ flat,
                                              const float* __restrict__ w1,
                                              const float* __restrict__ b1,
                                              float* __restrict__ hs) {
  __shared__ float part[4][64];
  int bid = blockIdx.x;
  int b = bid >> 2, oc = bid & 3;
  int t = threadIdx.x;
  int ol = t & 63, kc = t >> 6;
  int o = oc * 64 + ol;
  const float* fb = flat + (size_t)b * 2048 + kc * 512;
  const float* wb = w1 + (size_t)(kc * 512) * 256 + o;
  float acc = 0.f;
  for (int k = 0; k < 512; k++) acc = fmaf(fb[k], wb[(size_t)k * 256], acc);
  part[kc][ol] = acc;
  __syncthreads();
  if (t < 64) {
    float a = part[0][t] + part[1][t] + part[2][t] + part[3][t] + b1[oc * 64 + t];
    hs[(size_t)b * 256 + oc * 64 + t] = 0.5f * a * (1.0f + erff(a * 0.70710678118654752f));
  }
}

// ---------------- MLP stage 2: hs -> corr ----------------
__global__ void k_mlp2(const float* __restrict__ hs,
                       const float* __restrict__ w2,
                       const float* __restrict__ b2,
                       float* __restrict__ corr) {
  int b = blockIdx.x, t = threadIdx.x;   // 64 threads
  const float* hb = hs + (size_t)b * 256;
  float acc = b2[t];
  for (int k = 0; k < 256; k++) acc = fmaf(hb[k], w2[(size_t)k * 64 + t], acc);
  corr[(size_t)b * 64 + t] = acc;
}

// ---------------- stage C: mode-mixing einsum over C ----------------
__global__ __launch_bounds__(256) void k_stageC(const float* __restrict__ xf,
                                                const float* __restrict__ w1,
                                                const float* __restrict__ w2,
                                                float* __restrict__ outft) {
  __shared__ float xfs[64 * 32];       // [c][kx*2+ri]
  int bid = blockIdx.x;
  int sw = (bid & 7) * 128 + (bid >> 3);   // bijective (1024 % 8 == 0)
  int j = sw >> 5, b = sw & 31;
  int t = threadIdx.x;
  #pragma unroll
  for (int k2 = 0; k2 < 4; k2++) {
    int id = t + k2 * 256;             // 1024 float2
    int c = id >> 4, kxi = id & 15;
    const float2 v = *reinterpret_cast<const float2*>(
        xf + (((size_t)b * 64 + c) * 32 + j) * 32 + kxi * 2);
    reinterpret_cast<float2*>(xfs)[id] = v;
  }
  __syncthreads();
  int kx = t & 15, og = t >> 4;
  const float* wsel = (j < 16) ? w1 : w2;
  int jr = (j < 16) ? j : j - 16;
  float aR[4], aI[4];
  #pragma unroll
  for (int i = 0; i < 4; i++) { aR[i] = 0.f; aI[i] = 0.f; }
  for (int c = 0; c < 64; c++) {
    float xr = xfs[c * 32 + kx * 2], xi = xfs[c * 32 + kx * 2 + 1];
    #pragma unroll
    for (int i = 0; i < 4; i++) {
      int o = og * 4 + i;
      const float2 wv = *reinterpret_cast<const float2*>(
          wsel + ((((size_t)c * 64 + o) * 16 + jr) * 16 + kx) * 2);
      aR[i] = fmaf(xr, wv.x, fmaf(-xi, wv.y, aR[i]));
      aI[i] = fmaf(xr, wv.y, fmaf(xi, wv.x, aI[i]));
    }
  }
  #pragma unroll
  for (int i = 0; i < 4; i++) {
    int o = og * 4 + i;
    float2* dst = reinterpret_cast<float2*>(outft + (((size_t)b * 64 + o) * 32 + j) * 32 + kx * 2);
    *dst = make_float2(aR[i], aI[i]);
  }
}

// ---------------- stage DE (fused): inverse ky-DFT into LDS, then inverse rfft-w + corr ----------------
// Phase 1 == old k_stageD (writes LDS instead of global y); phase 2 == old k_stageE
// (reads LDS broadcast rows instead of global y). Math bit-identical.
__global__ __launch_bounds__(256) void k_stageDE(const float* __restrict__ outft,
                                                 const float* __restrict__ corr,
                                                 float* __restrict__ out) {
  __shared__ float yl[128][36];        // 36-float pad: 16B-aligned rows, bank spread
  int bo = blockIdx.x;
  int t = threadIdx.x;

  {                                    // ---- phase 1: inverse DFT over ky ----
    int kx = t & 15, hg = t >> 4;
    int h0 = hg * 8;
    float aR[8], aI[8];
    #pragma unroll
    for (int k = 0; k < 8; k++) { aR[k] = 0.f; aI[k] = 0.f; }
    const float* src = outft + (size_t)bo * 1024 + kx * 2;
    for (int jj = 0; jj < 32; jj++) {
      const float2 c = *reinterpret_cast<const float2*>(src + jj * 32);
      int ky = (jj < 16) ? jj : jj + 96;
      int r0 = (ky * h0) & 127;
      float angb = TWO_PI_F * (1.0f / 128.0f) * (float)r0;
      float br, bi;
      __sincosf(angb, &bi, &br);                  // e^{+2pi i ky h0/128}
      float angs = TWO_PI_F * (1.0f / 128.0f) * (float)(ky & 127);
      float sti, strr;
      __sincosf(angs, &sti, &strr);               // e^{+2pi i ky/128}
      #pragma unroll
      for (int k = 0; k < 8; k++) {
        aR[k] = fmaf(c.x, br, fmaf(-c.y, bi, aR[k]));
        aI[k] = fmaf(c.x, bi, fmaf(c.y, br, aI[k]));
        float nbr = br * strr - bi * sti;
        float nbi = br * sti + bi * strr;
        br = nbr; bi = nbi;
      }
    }
    #pragma unroll
    for (int k = 0; k < 8; k++) {
      yl[h0 + k][kx * 2]     = aR[k] * 0.0078125f;
      yl[h0 + k][kx * 2 + 1] = aI[k] * 0.0078125f;
    }
  }
  __syncthreads();

  // ---- phase 2: inverse rfft over w (c2r: Im(DC) dropped) + corr ----
  int w0 = t & 63, grp = t >> 6;       // grp wave-uniform
  float cph[16], sph[16];
  cph[0] = 1.f; sph[0] = 0.f;
  #pragma unroll
  for (int kx = 1; kx < 16; kx++) {
    int r = (kx * w0) & 127;
    float ang = TWO_PI_F * (1.0f / 128.0f) * (float)r;
    float s, c;
    __sincosf(ang, &s, &c);
    cph[kx] = 2.0f * c; sph[kx] = 2.0f * s;   // fold the 2x of c2r symmetry
  }
  float corrv = corr[bo];
  float* obase = out + (size_t)bo * 16384;
  for (int k = 0; k < 32; k++) {
    int h = 4 * k + grp;
    const float* r = yl[h];            // broadcast LDS reads (same addr per wave)
    float acc0 = r[0], acc1 = r[0];    // DC: real part only (c2r semantics)
    #pragma unroll
    for (int kx = 1; kx < 16; kx++) {
      float term = r[2 * kx] * cph[kx];
      term = fmaf(-r[2 * kx + 1], sph[kx], term);
      acc0 += term;
      if (kx & 1) acc1 -= term; else acc1 += term;
    }
    obase[h * 128 + w0]      = fmaf(acc0, 0.0078125f, corrv);
    obase[h * 128 + w0 + 64] = fmaf(acc1, 0.0078125f, corrv);
  }
}

extern "C" void kernel_launch(void* const* d_in, const int* in_sizes, int n_in,
                              void* d_out, int out_size, void* d_ws, size_t ws_size,
                              hipStream_t stream) {
  const float* x   = (const float*)d_in[0];
  const float* w1  = (const float*)d_in[1];
  const float* w2  = (const float*)d_in[2];
  const float* l1w = (const float*)d_in[3];
  const float* l1b = (const float*)d_in[4];
  const float* l2w = (const float*)d_in[5];
  const float* l2b = (const float*)d_in[6];
  float* out = (float*)d_out;
  float* ws  = (float*)d_ws;

  float* flat  = ws + WSO_FLAT;
  float* corr  = ws + WSO_CORR;
  float* hs    = ws + WSO_HS;
  float* cft1  = ws + WSO_CFT1;
  float* xf    = ws + WSO_XF;
  float* outft = ws + WSO_OUTFT;
  float* xw    = out;   // d_out used as scratch for xw; fully rewritten by stage DE

  k_stageA<<<dim3(1024), dim3(256), 0, stream>>>(x, xw, cft1);
  k_stageB<<<dim3(2048), dim3(256), 0, stream>>>(xw, xf);
  k_cfth<<<dim3(1024), dim3(64), 0, stream>>>(cft1, flat);
  k_mlp1<<<dim3(128), dim3(256), 0, stream>>>(flat, l1w, l1b, hs);
  k_mlp2<<<dim3(32), dim3(64), 0, stream>>>(hs, l2w, l2b, corr);
  k_stageC<<<dim3(1024), dim3(256), 0, stream>>>(xf, w1, w2, outft);
  k_stageDE<<<dim3(2048), dim3(256), 0, stream>>>(outft, corr, out);
}

// Round 7
// 248.055 us; speedup vs baseline: 2.3483x; 1.0496x over previous
//
#include <hip/hip_runtime.h>
#include <math.h>

#define PI_F 3.14159265358979323846f
#define TWO_PI_F 6.28318530717958647692f

// problem sizes
constexpr int Bn = 32, Cn = 64, On = 64, Hn = 128, Wn = 128;

// workspace float offsets (small region < WSO_BIG)
constexpr size_t WSO_FLAT  = 0;                        // 32*2048 = 65536
constexpr size_t WSO_CORR  = 65536;                    // 32*64   = 2048
constexpr size_t WSO_HS    = 67584;                    // 32*256  = 8192 (ends 75776)
constexpr size_t WSO_BIG   = 81920;
constexpr size_t SZ_QTR    = (size_t)2097152;          // 2M floats
constexpr size_t WSO_CFT1  = WSO_BIG;                  // [2048][128][8]
constexpr size_t WSO_XF    = WSO_BIG + SZ_QTR;         // [32][64][32][16][2]
constexpr size_t WSO_OUTFT = WSO_BIG + 4 * SZ_QTR;     // [32][64][32][16][2]

// ================= compile-time tables =================
// ktw[w][j]: j=2kx+0 -> cos, j=2kx+1 -> -sin of 2*pi*kx*w/128 (j<32);
//            j=32+f real CFT-W, j=36+f imag CFT-W.
// cfth[w][f(0..3)]=real, [w][4+f]=imag, fsel = {0,1,-2,-1}
struct Tabs {
  float ktw[128][40];
  float cfth[128][8];
};

constexpr double D_PI = 3.14159265358979323846;

constexpr double d_red(double x) {
  while (x >  D_PI) x -= 2.0 * D_PI;
  while (x < -D_PI) x += 2.0 * D_PI;
  return x;
}
constexpr double d_sin(double x) {
  x = d_red(x);
  double x2 = x * x, t = x, s = x;
  for (int n = 1; n <= 10; n++) { t *= -x2 / (double)((2 * n) * (2 * n + 1)); s += t; }
  return s;
}
constexpr double d_cos(double x) {
  x = d_red(x);
  double x2 = x * x, t = 1.0, s = 1.0;
  for (int n = 1; n <= 10; n++) { t *= -x2 / (double)((2 * n - 1) * (2 * n)); s += t; }
  return s;
}

constexpr Tabs make_tabs() {
  Tabs T{};
  double twc[128] = {}, tws[128] = {};
  for (int r = 0; r < 128; r++) {
    double a = 2.0 * D_PI * (double)r / 128.0;
    twc[r] = d_cos(a); tws[r] = d_sin(a);
  }
  for (int kx = 0; kx < 16; kx++)
    for (int w = 0; w < 128; w++) {
      int r = (kx * w) & 127;
      T.ktw[w][2 * kx]     = (float)twc[r];
      T.ktw[w][2 * kx + 1] = (float)(-tws[r]);
    }
  double node[8] = {}, theta[8] = {};
  for (int m = 0; m < 8; m++) { theta[m] = (2.0 * m + 1.0) * D_PI / 16.0; node[m] = -d_cos(theta[m]); }
  double Tch[8][8] = {};
  for (int k = 0; k < 8; k++)
    for (int m = 0; m < 8; m++) Tch[k][m] = d_cos((double)k * (D_PI - theta[m]));
  int LE[4][8] = {}, RI[4][8] = {};
  float WL[4][8] = {}, WR[4][8] = {};
  for (int l = 0; l < 4; l++)
    for (int m = 0; m < 8; m++) {
      float tseg = (float)(0.25 * (double)l + 0.125 * (node[m] + 1.0));
      int ri = (int)(tseg * 127.0f) - 2; if (ri < 0) ri = 0;
      while (ri < 127 && ((float)ri * (1.0f / 127.0f)) < tseg) ri++;
      int le = ri - 1; if (le < 0) le = 0;
      float tl = (float)le * (1.0f / 127.0f), tr = (float)ri * (1.0f / 127.0f);
      float den = (tr - tl < 1e-8f) ? 1.0f : (tr - tl);
      float wr = (tseg - tl) / den;
      LE[l][m] = le; RI[l][m] = ri; WR[l][m] = wr; WL[l][m] = 1.0f - wr;
    }
  for (int p = 0; p < 2; p++)
    for (int f = 0; f < 4; f++) {
      double fval = (p == 0) ? (double)f
                             : ((f == 0) ? 0.0 : (f == 1) ? 1.0 : (f == 2) ? -2.0 : -1.0);
      double wp = fval * (2.0 * D_PI * 0.125);
      double Wr[8] = {}, Wi[8] = {};
      for (int k = 0; k < 8; k++) {
        double sr = 0.0, si = 0.0;
        for (int m = 0; m < 8; m++) {
          sr += Tch[k][m] * d_cos(node[m] * wp);
          si += Tch[k][m] * (-d_sin(node[m] * wp));
        }
        Wr[k] = sr * 0.125; Wi[k] = si * 0.125;
      }
      for (int l = 0; l < 4; l++) {
        double ph = -2.0 * D_PI * (0.25 * (double)l) * fval;
        double cr = d_cos(ph), ci = d_sin(ph);
        for (int m = 0; m < 8; m++) {
          double coefR = Wr[m] * cr - Wi[m] * ci;
          double coefI = Wr[m] * ci + Wi[m] * cr;
          int le = LE[l][m], ri = RI[l][m];
          if (p == 0) {
            T.ktw[le][32 + f] += (float)(WL[l][m] * coefR);
            T.ktw[le][36 + f] += (float)(WL[l][m] * coefI);
            T.ktw[ri][32 + f] += (float)(WR[l][m] * coefR);
            T.ktw[ri][36 + f] += (float)(WR[l][m] * coefI);
          } else {
            T.cfth[le][f]     += (float)(WL[l][m] * coefR);
            T.cfth[le][4 + f] += (float)(WL[l][m] * coefI);
            T.cfth[ri][f]     += (float)(WR[l][m] * coefR);
            T.cfth[ri][4 + f] += (float)(WR[l][m] * coefI);
          }
        }
      }
    }
  return T;
}

__constant__ Tabs g_tabs = make_tabs();

// ---- bf16 split helpers (RNE via bit trick) ----
constexpr unsigned short cf2bf(float f) {
  unsigned u = __builtin_bit_cast(unsigned, f);
  u += 0x7FFFu + ((u >> 16) & 1u);
  return (unsigned short)(u >> 16);
}
constexpr float cbf2f(unsigned short h) {
  return __builtin_bit_cast(float, (unsigned)h << 16);
}

// B-fragment table for stage-A MFMA GEMM: [262144 x 128] * [128 x 40(+8 pad)]
// mfma_f32_16x16x32_bf16 layout: A row = lane&15, k = (lane>>4)*8+j;
// B col = lane&15, same k; D col = lane&15, row = (lane>>4)*4+i.  (m89/m91)
struct alignas(16) BTab {
  unsigned short v[4][2][3][64][8];   // [kstep][hi/lo][jtile][lane][j]
};

constexpr BTab make_btab() {
  BTab B{};
  Tabs T = make_tabs();
  for (int ks = 0; ks < 4; ks++)
    for (int jt = 0; jt < 3; jt++)
      for (int lane = 0; lane < 64; lane++)
        for (int j = 0; j < 8; j++) {
          int col = jt * 16 + (lane & 15);
          int k = ks * 32 + (lane >> 4) * 8 + j;
          float val = (col < 40) ? T.ktw[k][col] : 0.0f;
          unsigned short h = cf2bf(val);
          B.v[ks][0][jt][lane][j] = h;
          B.v[ks][1][jt][lane][j] = cf2bf(val - cbf2f(h));
        }
  return B;
}

__constant__ BTab g_btab = make_btab();

typedef __attribute__((ext_vector_type(8))) __bf16 bf16x8;
typedef __attribute__((ext_vector_type(8))) unsigned short ushort8;
typedef __attribute__((ext_vector_type(4))) float f32x4;

__device__ __forceinline__ unsigned short f2bf(float f) {
  unsigned u = __builtin_bit_cast(unsigned, f);
  u += 0x7FFFu + ((u >> 16) & 1u);
  return (unsigned short)(u >> 16);
}
__device__ __forceinline__ float bf2f(unsigned short h) {
  return __builtin_bit_cast(float, (unsigned)h << 16);
}

// ---------------- stage A: row DFT + CFT W-pass as split-bf16 MFMA GEMM ----------------
// One wave per 16 rows. A-frags from global (32B/lane chunks, full-line use);
// B-frags from __constant__ in HW fragment order (1KB contiguous per load inst).
// x*k = xhi*khi + xlo*khi + xhi*klo  (error ~2^-18, f32-equivalent).
__global__ __launch_bounds__(256) void k_stageA(const float* __restrict__ x,
                                                float* __restrict__ xw,
                                                float* __restrict__ cft1) {
  int t = threadIdx.x;
  int lane = t & 63, wid = t >> 6;
  int rb = blockIdx.x * 64 + wid * 16;         // wave's 16-row tile
  int r = lane & 15;                            // A row within tile
  int kg = lane >> 4;                           // k-group
  const float* arow = x + (size_t)(rb + r) * 128 + kg * 8;

  bf16x8 ahi[4], alo[4];
  #pragma unroll
  for (int ks = 0; ks < 4; ks++) {
    float4 v0 = *reinterpret_cast<const float4*>(arow + ks * 32);
    float4 v1 = *reinterpret_cast<const float4*>(arow + ks * 32 + 4);
    float xv[8] = {v0.x, v0.y, v0.z, v0.w, v1.x, v1.y, v1.z, v1.w};
    ushort8 hu, lu;
    #pragma unroll
    for (int j = 0; j < 8; j++) {
      unsigned short h = f2bf(xv[j]);
      hu[j] = h;
      lu[j] = f2bf(xv[j] - bf2f(h));
    }
    ahi[ks] = __builtin_bit_cast(bf16x8, hu);
    alo[ks] = __builtin_bit_cast(bf16x8, lu);
  }

  #pragma unroll
  for (int jt = 0; jt < 3; jt++) {
    f32x4 acc = {0.f, 0.f, 0.f, 0.f};
    #pragma unroll
    for (int ks = 0; ks < 4; ks++) {
      bf16x8 bhi = __builtin_bit_cast(bf16x8,
          *reinterpret_cast<const ushort8*>(&g_btab.v[ks][0][jt][lane][0]));
      bf16x8 blo = __builtin_bit_cast(bf16x8,
          *reinterpret_cast<const ushort8*>(&g_btab.v[ks][1][jt][lane][0]));
      acc = __builtin_amdgcn_mfma_f32_16x16x32_bf16(ahi[ks], bhi, acc, 0, 0, 0);
      acc = __builtin_amdgcn_mfma_f32_16x16x32_bf16(alo[ks], bhi, acc, 0, 0, 0);
      acc = __builtin_amdgcn_mfma_f32_16x16x32_bf16(ahi[ks], blo, acc, 0, 0, 0);
    }
    int col = lane & 15;
    int rq = lane >> 4;
    #pragma unroll
    for (int i = 0; i < 4; i++) {
      size_t row = (size_t)rb + rq * 4 + i;
      if (jt < 2) {
        xw[row * 32 + jt * 16 + col] = acc[i];
      } else if (col < 8) {
        cft1[row * 8 + col] = acc[i];
      }
    }
  }
}

// ---------------- stage B: forward DFT over h (32 ky modes) via phasor rotation ----------------
__global__ __launch_bounds__(256) void k_stageB(const float* __restrict__ xw,
                                                float* __restrict__ xf) {
  int t = threadIdx.x;
  int bc = blockIdx.x;
  int kx = t & 15, jg = t >> 4;        // jg 0..15, j = jg*2+q
  float pr[2], pq[2], sr[2], si[2], aR[2], aI[2];
  #pragma unroll
  for (int q = 0; q < 2; q++) {
    int j = jg * 2 + q;
    int ky = (j < 16) ? j : j + 96;
    float ang = TWO_PI_F * (float)ky * (1.0f / 128.0f);
    float s, c;
    __sincosf(ang, &s, &c);
    sr[q] = c; si[q] = -s;             // e^{-2pi i ky/128}
    pr[q] = 1.f; pq[q] = 0.f; aR[q] = 0.f; aI[q] = 0.f;
  }
  const float* base = xw + (size_t)bc * 128 * 32 + kx * 2;
  for (int h = 0; h < 128; h++) {
    const float2 v = *reinterpret_cast<const float2*>(base + h * 32);
    #pragma unroll
    for (int q = 0; q < 2; q++) {
      aR[q] = fmaf(v.x, pr[q], fmaf(-v.y, pq[q], aR[q]));
      aI[q] = fmaf(v.x, pq[q], fmaf(v.y, pr[q], aI[q]));
      float npr = pr[q] * sr[q] - pq[q] * si[q];
      float npi = pr[q] * si[q] + pq[q] * sr[q];
      pr[q] = npr; pq[q] = npi;
    }
  }
  #pragma unroll
  for (int q = 0; q < 2; q++) {
    int j = jg * 2 + q;
    float2* o = reinterpret_cast<float2*>(xf + (((size_t)bc * 32 + j) * 16 + kx) * 2);
    *o = make_float2(aR[q], aI[q]);
  }
}

// ---------------- CFT H-pass: cft1 -> flat ----------------
__global__ void k_cfth(const float* __restrict__ cft1, float* __restrict__ flat) {
  int t = threadIdx.x;
  int bc = blockIdx.x * 2 + (t >> 5);
  int tt = t & 31;
  int f1 = tt >> 3, f2 = (tt >> 1) & 3, ri = tt & 1;
  const float* s = cft1 + (size_t)bc * 1024;
  float acc = 0.f;
  for (int h = 0; h < 128; h++) {
    float r = s[h * 8 + f2], im = s[h * 8 + 4 + f2];
    float kr = g_tabs.cfth[h][f1], ki = g_tabs.cfth[h][4 + f1];
    float e0 = (ri == 0) ? kr : ki;
    float e1 = (ri == 0) ? -ki : kr;
    acc = fmaf(r, e0, fmaf(im, e1, acc));
  }
  int b = bc >> 6, c = bc & 63;
  flat[(size_t)b * 2048 + ((c * 4 + f1) * 4 + f2) * 2 + ri] = acc;
}

// ---------------- MLP stage 1: flat -> hs (k-split + LDS reduce, exact-erf GELU) ----------------
__global__ __launch_bounds__(256) void k_mlp1(const float* __restrict__ flat,
                                              const float* __restrict__ w1,
                                              const float* __restrict__ b1,
                                              float* __restrict__ hs) {
  __shared__ float part[4][64];
  int bid = blockIdx.x;
  int b = bid >> 2, oc = bid & 3;
  int t = threadIdx.x;
  int ol = t & 63, kc = t >> 6;
  int o = oc * 64 + ol;
  const float* fb = flat + (size_t)b * 2048 + kc * 512;
  const float* wb = w1 + (size_t)(kc * 512) * 256 + o;
  float acc = 0.f;
  for (int k = 0; k < 512; k++) acc = fmaf(fb[k], wb[(size_t)k * 256], acc);
  part[kc][ol] = acc;
  __syncthreads();
  if (t < 64) {
    float a = part[0][t] + part[1][t] + part[2][t] + part[3][t] + b1[oc * 64 + t];
    hs[(size_t)b * 256 + oc * 64 + t] = 0.5f * a * (1.0f + erff(a * 0.70710678118654752f));
  }
}

// ---------------- MLP stage 2: hs -> corr ----------------
__global__ void k_mlp2(const float* __restrict__ hs,
                       const float* __restrict__ w2,
                       const float* __restrict__ b2,
                       float* __restrict__ corr) {
  int b = blockIdx.x, t = threadIdx.x;   // 64 threads
  const float* hb = hs + (size_t)b * 256;
  float acc = b2[t];
  for (int k = 0; k < 256; k++) acc = fmaf(hb[k], w2[(size_t)k * 64 + t], acc);
  corr[(size_t)b * 64 + t] = acc;
}

// ---------------- stage C: mode-mixing einsum over C ----------------
__global__ __launch_bounds__(256) void k_stageC(const float* __restrict__ xf,
                                                const float* __restrict__ w1,
                                                const float* __restrict__ w2,
                                                float* __restrict__ outft) {
  __shared__ float xfs[64 * 32];       // [c][kx*2+ri]
  int bid = blockIdx.x;
  int sw = (bid & 7) * 128 + (bid >> 3);   // bijective (1024 % 8 == 0)
  int j = sw >> 5, b = sw & 31;
  int t = threadIdx.x;
  #pragma unroll
  for (int k2 = 0; k2 < 4; k2++) {
    int id = t + k2 * 256;             // 1024 float2
    int c = id >> 4, kxi = id & 15;
    const float2 v = *reinterpret_cast<const float2*>(
        xf + (((size_t)b * 64 + c) * 32 + j) * 32 + kxi * 2);
    reinterpret_cast<float2*>(xfs)[id] = v;
  }
  __syncthreads();
  int kx = t & 15, og = t >> 4;
  const float* wsel = (j < 16) ? w1 : w2;
  int jr = (j < 16) ? j : j - 16;
  float aR[4], aI[4];
  #pragma unroll
  for (int i = 0; i < 4; i++) { aR[i] = 0.f; aI[i] = 0.f; }
  for (int c = 0; c < 64; c++) {
    float xr = xfs[c * 32 + kx * 2], xi = xfs[c * 32 + kx * 2 + 1];
    #pragma unroll
    for (int i = 0; i < 4; i++) {
      int o = og * 4 + i;
      const float2 wv = *reinterpret_cast<const float2*>(
          wsel + ((((size_t)c * 64 + o) * 16 + jr) * 16 + kx) * 2);
      aR[i] = fmaf(xr, wv.x, fmaf(-xi, wv.y, aR[i]));
      aI[i] = fmaf(xr, wv.y, fmaf(xi, wv.x, aI[i]));
    }
  }
  #pragma unroll
  for (int i = 0; i < 4; i++) {
    int o = og * 4 + i;
    float2* dst = reinterpret_cast<float2*>(outft + (((size_t)b * 64 + o) * 32 + j) * 32 + kx * 2);
    *dst = make_float2(aR[i], aI[i]);
  }
}

// ---------------- stage DE (fused): inverse ky-DFT into LDS, then inverse rfft-w + corr ----------------
__global__ __launch_bounds__(256) void k_stageDE(const float* __restrict__ outft,
                                                 const float* __restrict__ corr,
                                                 float* __restrict__ out) {
  __shared__ float yl[128][36];        // 36-float pad: 16B-aligned rows, bank spread
  int bo = blockIdx.x;
  int t = threadIdx.x;

  {                                    // ---- phase 1: inverse DFT over ky ----
    int kx = t & 15, hg = t >> 4;
    int h0 = hg * 8;
    float aR[8], aI[8];
    #pragma unroll
    for (int k = 0; k < 8; k++) { aR[k] = 0.f; aI[k] = 0.f; }
    const float* src = outft + (size_t)bo * 1024 + kx * 2;
    for (int jj = 0; jj < 32; jj++) {
      const float2 c = *reinterpret_cast<const float2*>(src + jj * 32);
      int ky = (jj < 16) ? jj : jj + 96;
      int r0 = (ky * h0) & 127;
      float angb = TWO_PI_F * (1.0f / 128.0f) * (float)r0;
      float br, bi;
      __sincosf(angb, &bi, &br);                  // e^{+2pi i ky h0/128}
      float angs = TWO_PI_F * (1.0f / 128.0f) * (float)(ky & 127);
      float sti, strr;
      __sincosf(angs, &sti, &strr);               // e^{+2pi i ky/128}
      #pragma unroll
      for (int k = 0; k < 8; k++) {
        aR[k] = fmaf(c.x, br, fmaf(-c.y, bi, aR[k]));
        aI[k] = fmaf(c.x, bi, fmaf(c.y, br, aI[k]));
        float nbr = br * strr - bi * sti;
        float nbi = br * sti + bi * strr;
        br = nbr; bi = nbi;
      }
    }
    #pragma unroll
    for (int k = 0; k < 8; k++) {
      yl[h0 + k][kx * 2]     = aR[k] * 0.0078125f;
      yl[h0 + k][kx * 2 + 1] = aI[k] * 0.0078125f;
    }
  }
  __syncthreads();

  // ---- phase 2: inverse rfft over w (c2r: Im(DC) dropped) + corr ----
  int w0 = t & 63, grp = t >> 6;       // grp wave-uniform
  float cph[16], sph[16];
  cph[0] = 1.f; sph[0] = 0.f;
  #pragma unroll
  for (int kx = 1; kx < 16; kx++) {
    int r = (kx * w0) & 127;
    float ang = TWO_PI_F * (1.0f / 128.0f) * (float)r;
    float s, c;
    __sincosf(ang, &s, &c);
    cph[kx] = 2.0f * c; sph[kx] = 2.0f * s;   // fold the 2x of c2r symmetry
  }
  float corrv = corr[bo];
  float* obase = out + (size_t)bo * 16384;
  for (int k = 0; k < 32; k++) {
    int h = 4 * k + grp;
    const float* r = yl[h];            // broadcast LDS reads (same addr per wave)
    float acc0 = r[0], acc1 = r[0];    // DC: real part only (c2r semantics)
    #pragma unroll
    for (int kx = 1; kx < 16; kx++) {
      float term = r[2 * kx] * cph[kx];
      term = fmaf(-r[2 * kx + 1], sph[kx], term);
      acc0 += term;
      if (kx & 1) acc1 -= term; else acc1 += term;
    }
    obase[h * 128 + w0]      = fmaf(acc0, 0.0078125f, corrv);
    obase[h * 128 + w0 + 64] = fmaf(acc1, 0.0078125f, corrv);
  }
}

extern "C" void kernel_launch(void* const* d_in, const int* in_sizes, int n_in,
                              void* d_out, int out_size, void* d_ws, size_t ws_size,
                              hipStream_t stream) {
  const float* x   = (const float*)d_in[0];
  const float* w1  = (const float*)d_in[1];
  const float* w2  = (const float*)d_in[2];
  const float* l1w = (const float*)d_in[3];
  const float* l1b = (const float*)d_in[4];
  const float* l2w = (const float*)d_in[5];
  const float* l2b = (const float*)d_in[6];
  float* out = (float*)d_out;
  float* ws  = (float*)d_ws;

  float* flat  = ws + WSO_FLAT;
  float* corr  = ws + WSO_CORR;
  float* hs    = ws + WSO_HS;
  float* cft1  = ws + WSO_CFT1;
  float* xf    = ws + WSO_XF;
  float* outft = ws + WSO_OUTFT;
  float* xw    = out;   // d_out used as scratch for xw; fully rewritten by stage DE

  k_stageA<<<dim3(4096), dim3(256), 0, stream>>>(x, xw, cft1);
  k_stageB<<<dim3(2048), dim3(256), 0, stream>>>(xw, xf);
  k_cfth<<<dim3(1024), dim3(64), 0, stream>>>(cft1, flat);
  k_mlp1<<<dim3(128), dim3(256), 0, stream>>>(flat, l1w, l1b, hs);
  k_mlp2<<<dim3(32), dim3(64), 0, stream>>>(hs, l2w, l2b, corr);
  k_stageC<<<dim3(1024), dim3(256), 0, stream>>>(xf, w1, w2, outft);
  k_stageDE<<<dim3(2048), dim3(256), 0, stream>>>(outft, corr, out);
}

// Round 8
// 203.119 us; speedup vs baseline: 2.8678x; 1.2212x over previous
//
#include <hip/hip_runtime.h>
#include <math.h>

#define PI_F 3.14159265358979323846f
#define TWO_PI_F 6.28318530717958647692f

// problem sizes
constexpr int Bn = 32, Cn = 64, On = 64, Hn = 128, Wn = 128;

// workspace float offsets (small region < WSO_BIG)
constexpr size_t WSO_FLAT  = 0;                        // 32*2048 = 65536
constexpr size_t WSO_CORR  = 65536;                    // 32*64   = 2048
constexpr size_t WSO_HS    = 67584;                    // 32*256  = 8192 (ends 75776)
constexpr size_t WSO_BIG   = 81920;
constexpr size_t SZ_QTR    = (size_t)2097152;          // 2M floats
constexpr size_t WSO_CFT1  = WSO_BIG;                  // [2048][128][8]
constexpr size_t WSO_XF    = WSO_BIG + SZ_QTR;         // [32][64][32][16][2]
constexpr size_t WSO_OUTFT = WSO_BIG + 4 * SZ_QTR;     // [2048][1024] B-frag order

// ================= compile-time tables =================
struct Tabs {
  float ktw[128][40];
  float cfth[128][8];
};

constexpr double D_PI = 3.14159265358979323846;

constexpr double d_red(double x) {
  while (x >  D_PI) x -= 2.0 * D_PI;
  while (x < -D_PI) x += 2.0 * D_PI;
  return x;
}
constexpr double d_sin(double x) {
  x = d_red(x);
  double x2 = x * x, t = x, s = x;
  for (int n = 1; n <= 10; n++) { t *= -x2 / (double)((2 * n) * (2 * n + 1)); s += t; }
  return s;
}
constexpr double d_cos(double x) {
  x = d_red(x);
  double x2 = x * x, t = 1.0, s = 1.0;
  for (int n = 1; n <= 10; n++) { t *= -x2 / (double)((2 * n - 1) * (2 * n)); s += t; }
  return s;
}

constexpr Tabs make_tabs() {
  Tabs T{};
  double twc[128] = {}, tws[128] = {};
  for (int r = 0; r < 128; r++) {
    double a = 2.0 * D_PI * (double)r / 128.0;
    twc[r] = d_cos(a); tws[r] = d_sin(a);
  }
  for (int kx = 0; kx < 16; kx++)
    for (int w = 0; w < 128; w++) {
      int r = (kx * w) & 127;
      T.ktw[w][2 * kx]     = (float)twc[r];
      T.ktw[w][2 * kx + 1] = (float)(-tws[r]);
    }
  double node[8] = {}, theta[8] = {};
  for (int m = 0; m < 8; m++) { theta[m] = (2.0 * m + 1.0) * D_PI / 16.0; node[m] = -d_cos(theta[m]); }
  double Tch[8][8] = {};
  for (int k = 0; k < 8; k++)
    for (int m = 0; m < 8; m++) Tch[k][m] = d_cos((double)k * (D_PI - theta[m]));
  int LE[4][8] = {}, RI[4][8] = {};
  float WL[4][8] = {}, WR[4][8] = {};
  for (int l = 0; l < 4; l++)
    for (int m = 0; m < 8; m++) {
      float tseg = (float)(0.25 * (double)l + 0.125 * (node[m] + 1.0));
      int ri = (int)(tseg * 127.0f) - 2; if (ri < 0) ri = 0;
      while (ri < 127 && ((float)ri * (1.0f / 127.0f)) < tseg) ri++;
      int le = ri - 1; if (le < 0) le = 0;
      float tl = (float)le * (1.0f / 127.0f), tr = (float)ri * (1.0f / 127.0f);
      float den = (tr - tl < 1e-8f) ? 1.0f : (tr - tl);
      float wr = (tseg - tl) / den;
      LE[l][m] = le; RI[l][m] = ri; WR[l][m] = wr; WL[l][m] = 1.0f - wr;
    }
  for (int p = 0; p < 2; p++)
    for (int f = 0; f < 4; f++) {
      double fval = (p == 0) ? (double)f
                             : ((f == 0) ? 0.0 : (f == 1) ? 1.0 : (f == 2) ? -2.0 : -1.0);
      double wp = fval * (2.0 * D_PI * 0.125);
      double Wr[8] = {}, Wi[8] = {};
      for (int k = 0; k < 8; k++) {
        double sr = 0.0, si = 0.0;
        for (int m = 0; m < 8; m++) {
          sr += Tch[k][m] * d_cos(node[m] * wp);
          si += Tch[k][m] * (-d_sin(node[m] * wp));
        }
        Wr[k] = sr * 0.125; Wi[k] = si * 0.125;
      }
      for (int l = 0; l < 4; l++) {
        double ph = -2.0 * D_PI * (0.25 * (double)l) * fval;
        double cr = d_cos(ph), ci = d_sin(ph);
        for (int m = 0; m < 8; m++) {
          double coefR = Wr[m] * cr - Wi[m] * ci;
          double coefI = Wr[m] * ci + Wi[m] * cr;
          int le = LE[l][m], ri = RI[l][m];
          if (p == 0) {
            T.ktw[le][32 + f] += (float)(WL[l][m] * coefR);
            T.ktw[le][36 + f] += (float)(WL[l][m] * coefI);
            T.ktw[ri][32 + f] += (float)(WR[l][m] * coefR);
            T.ktw[ri][36 + f] += (float)(WR[l][m] * coefI);
          } else {
            T.cfth[le][f]     += (float)(WL[l][m] * coefR);
            T.cfth[le][4 + f] += (float)(WL[l][m] * coefI);
            T.cfth[ri][f]     += (float)(WR[l][m] * coefR);
            T.cfth[ri][4 + f] += (float)(WR[l][m] * coefI);
          }
        }
      }
    }
  return T;
}

__constant__ Tabs g_tabs = make_tabs();

// ---- bf16 split helpers (RNE via bit trick) ----
constexpr unsigned short cf2bf(float f) {
  unsigned u = __builtin_bit_cast(unsigned, f);
  u += 0x7FFFu + ((u >> 16) & 1u);
  return (unsigned short)(u >> 16);
}
constexpr float cbf2f(unsigned short h) {
  return __builtin_bit_cast(float, (unsigned)h << 16);
}

// -------- stage A B-table: [262144 x 128] * [128 x 40(+8 pad)] --------
// mfma_f32_16x16x32_bf16: A row=lane&15, k=(lane>>4)*8+j; B col=lane&15, same k;
// D col=lane&15, row=(lane>>4)*4+i.  (verified m89/m91 + round-6 pass)
struct alignas(16) BTab {
  unsigned short v[4][2][3][64][8];   // [kstep][hi/lo][jtile][lane][j]
};

constexpr BTab make_btab() {
  BTab B{};
  Tabs T = make_tabs();
  for (int ks = 0; ks < 4; ks++)
    for (int jt = 0; jt < 3; jt++)
      for (int lane = 0; lane < 64; lane++)
        for (int j = 0; j < 8; j++) {
          int col = jt * 16 + (lane & 15);
          int k = ks * 32 + (lane >> 4) * 8 + j;
          float val = (col < 40) ? T.ktw[k][col] : 0.0f;
          unsigned short h = cf2bf(val);
          B.v[ks][0][jt][lane][j] = h;
          B.v[ks][1][jt][lane][j] = cf2bf(val - cbf2f(h));
        }
  return B;
}

__constant__ BTab g_btab = make_btab();

// -------- stage DE GEMM1 A-table: W1[256 r=(u*128+h)][64 k=(2jj+u')] * (1/128) --------
// r<128: yR[h] row = [cos(a), -sin(a)]; r>=128: yI row = [sin(a), cos(a)], a=2pi ky h/128
struct alignas(16) W1Tab {
  unsigned short v[16][2][2][64][8];  // [mtile][kstep][hi/lo][lane][j]
};
constexpr W1Tab make_w1tab() {
  W1Tab T{};
  double twc[128] = {}, tws[128] = {};
  for (int r = 0; r < 128; r++) {
    double a = 2.0 * D_PI * (double)r / 128.0;
    twc[r] = d_cos(a); tws[r] = d_sin(a);
  }
  for (int mt = 0; mt < 16; mt++)
    for (int ks = 0; ks < 2; ks++)
      for (int lane = 0; lane < 64; lane++)
        for (int j = 0; j < 8; j++) {
          int r = mt * 16 + (lane & 15);
          int k = ks * 32 + (lane >> 4) * 8 + j;
          int jj = k >> 1, u = k & 1;
          int ky = (jj < 16) ? jj : jj + 96;
          int h = r & 127;
          int idx = (ky * h) & 127;
          double c = twc[idx], s = tws[idx];
          double val = (r < 128) ? ((u == 0) ? c : -s)
                                 : ((u == 0) ? s : c);
          float f = (float)(val * (1.0 / 128.0));
          unsigned short hi = cf2bf(f);
          T.v[mt][ks][0][lane][j] = hi;
          T.v[mt][ks][1][lane][j] = cf2bf(f - cbf2f(hi));
        }
  return T;
}
__constant__ W1Tab g_w1tab = make_w1tab();

// -------- stage DE GEMM2 B-table: W2[32 k][128 w] * (1/128), c2r folded --------
// k=0: 1; k=1: 0 (Im DC dropped); k=2kx: 2cos(2pi kx w/128); k=2kx+1: -2sin(...)
struct alignas(16) W2Tab {
  unsigned short v[8][2][64][8];      // [ntile][hi/lo][lane][j]
};
constexpr W2Tab make_w2tab() {
  W2Tab T{};
  double twc[128] = {}, tws[128] = {};
  for (int r = 0; r < 128; r++) {
    double a = 2.0 * D_PI * (double)r / 128.0;
    twc[r] = d_cos(a); tws[r] = d_sin(a);
  }
  for (int nt = 0; nt < 8; nt++)
    for (int lane = 0; lane < 64; lane++)
      for (int j = 0; j < 8; j++) {
        int w = nt * 16 + (lane & 15);
        int k = (lane >> 4) * 8 + j;
        int kx = k >> 1, u = k & 1;
        double val;
        if (kx == 0) val = (u == 0) ? 1.0 : 0.0;
        else {
          int idx = (kx * w) & 127;
          val = (u == 0) ? 2.0 * twc[idx] : -2.0 * tws[idx];
        }
        float f = (float)(val * (1.0 / 128.0));
        unsigned short hi = cf2bf(f);
        T.v[nt][0][lane][j] = hi;
        T.v[nt][1][lane][j] = cf2bf(f - cbf2f(hi));
      }
  return T;
}
__constant__ W2Tab g_w2tab = make_w2tab();

typedef __attribute__((ext_vector_type(8))) __bf16 bf16x8;
typedef __attribute__((ext_vector_type(8))) unsigned short ushort8;
typedef __attribute__((ext_vector_type(4))) float f32x4;

__device__ __forceinline__ unsigned short f2bf(float f) {
  unsigned u = __builtin_bit_cast(unsigned, f);
  u += 0x7FFFu + ((u >> 16) & 1u);
  return (unsigned short)(u >> 16);
}
__device__ __forceinline__ float bf2f(unsigned short h) {
  return __builtin_bit_cast(float, (unsigned)h << 16);
}

// ---------------- stage A: row DFT + CFT W-pass as split-bf16 MFMA GEMM ----------------
__global__ __launch_bounds__(256) void k_stageA(const float* __restrict__ x,
                                                float* __restrict__ xw,
                                                float* __restrict__ cft1) {
  int t = threadIdx.x;
  int lane = t & 63, wid = t >> 6;
  int rb = blockIdx.x * 64 + wid * 16;         // wave's 16-row tile
  int r = lane & 15;
  int kg = lane >> 4;
  const float* arow = x + (size_t)(rb + r) * 128 + kg * 8;

  bf16x8 ahi[4], alo[4];
  #pragma unroll
  for (int ks = 0; ks < 4; ks++) {
    float4 v0 = *reinterpret_cast<const float4*>(arow + ks * 32);
    float4 v1 = *reinterpret_cast<const float4*>(arow + ks * 32 + 4);
    float xv[8] = {v0.x, v0.y, v0.z, v0.w, v1.x, v1.y, v1.z, v1.w};
    ushort8 hu, lu;
    #pragma unroll
    for (int j = 0; j < 8; j++) {
      unsigned short h = f2bf(xv[j]);
      hu[j] = h;
      lu[j] = f2bf(xv[j] - bf2f(h));
    }
    ahi[ks] = __builtin_bit_cast(bf16x8, hu);
    alo[ks] = __builtin_bit_cast(bf16x8, lu);
  }

  #pragma unroll
  for (int jt = 0; jt < 3; jt++) {
    f32x4 acc = {0.f, 0.f, 0.f, 0.f};
    #pragma unroll
    for (int ks = 0; ks < 4; ks++) {
      bf16x8 bhi = __builtin_bit_cast(bf16x8,
          *reinterpret_cast<const ushort8*>(&g_btab.v[ks][0][jt][lane][0]));
      bf16x8 blo = __builtin_bit_cast(bf16x8,
          *reinterpret_cast<const ushort8*>(&g_btab.v[ks][1][jt][lane][0]));
      acc = __builtin_amdgcn_mfma_f32_16x16x32_bf16(ahi[ks], bhi, acc, 0, 0, 0);
      acc = __builtin_amdgcn_mfma_f32_16x16x32_bf16(alo[ks], bhi, acc, 0, 0, 0);
      acc = __builtin_amdgcn_mfma_f32_16x16x32_bf16(ahi[ks], blo, acc, 0, 0, 0);
    }
    int col = lane & 15;
    int rq = lane >> 4;
    #pragma unroll
    for (int i = 0; i < 4; i++) {
      size_t row = (size_t)rb + rq * 4 + i;
      if (jt < 2) {
        xw[row * 32 + jt * 16 + col] = acc[i];
      } else if (col < 8) {
        cft1[row * 8 + col] = acc[i];
      }
    }
  }
}

// ---------------- stage B: forward DFT over h (32 ky modes) via phasor rotation ----------------
__global__ __launch_bounds__(256) void k_stageB(const float* __restrict__ xw,
                                                float* __restrict__ xf) {
  int t = threadIdx.x;
  int bc = blockIdx.x;
  int kx = t & 15, jg = t >> 4;        // jg 0..15, j = jg*2+q
  float pr[2], pq[2], sr[2], si[2], aR[2], aI[2];
  #pragma unroll
  for (int q = 0; q < 2; q++) {
    int j = jg * 2 + q;
    int ky = (j < 16) ? j : j + 96;
    float ang = TWO_PI_F * (float)ky * (1.0f / 128.0f);
    float s, c;
    __sincosf(ang, &s, &c);
    sr[q] = c; si[q] = -s;             // e^{-2pi i ky/128}
    pr[q] = 1.f; pq[q] = 0.f; aR[q] = 0.f; aI[q] = 0.f;
  }
  const float* base = xw + (size_t)bc * 128 * 32 + kx * 2;
  for (int h = 0; h < 128; h++) {
    const float2 v = *reinterpret_cast<const float2*>(base + h * 32);
    #pragma unroll
    for (int q = 0; q < 2; q++) {
      aR[q] = fmaf(v.x, pr[q], fmaf(-v.y, pq[q], aR[q]));
      aI[q] = fmaf(v.x, pq[q], fmaf(v.y, pr[q], aI[q]));
      float npr = pr[q] * sr[q] - pq[q] * si[q];
      float npi = pr[q] * si[q] + pq[q] * sr[q];
      pr[q] = npr; pq[q] = npi;
    }
  }
  #pragma unroll
  for (int q = 0; q < 2; q++) {
    int j = jg * 2 + q;
    float2* o = reinterpret_cast<float2*>(xf + (((size_t)bc * 32 + j) * 16 + kx) * 2);
    *o = make_float2(aR[q], aI[q]);
  }
}

// ---------------- CFT H-pass: cft1 -> flat ----------------
__global__ void k_cfth(const float* __restrict__ cft1, float* __restrict__ flat) {
  int t = threadIdx.x;
  int bc = blockIdx.x * 2 + (t >> 5);
  int tt = t & 31;
  int f1 = tt >> 3, f2 = (tt >> 1) & 3, ri = tt & 1;
  const float* s = cft1 + (size_t)bc * 1024;
  float acc = 0.f;
  for (int h = 0; h < 128; h++) {
    float r = s[h * 8 + f2], im = s[h * 8 + 4 + f2];
    float kr = g_tabs.cfth[h][f1], ki = g_tabs.cfth[h][4 + f1];
    float e0 = (ri == 0) ? kr : ki;
    float e1 = (ri == 0) ? -ki : kr;
    acc = fmaf(r, e0, fmaf(im, e1, acc));
  }
  int b = bc >> 6, c = bc & 63;
  flat[(size_t)b * 2048 + ((c * 4 + f1) * 4 + f2) * 2 + ri] = acc;
}

// ---------------- MLP stage 1: flat -> hs ----------------
__global__ __launch_bounds__(256) void k_mlp1(const float* __restrict__ flat,
                                              const float* __restrict__ w1,
                                              const float* __restrict__ b1,
                                              float* __restrict__ hs) {
  __shared__ float part[4][64];
  int bid = blockIdx.x;
  int b = bid >> 2, oc = bid & 3;
  int t = threadIdx.x;
  int ol = t & 63, kc = t >> 6;
  int o = oc * 64 + ol;
  const float* fb = flat + (size_t)b * 2048 + kc * 512;
  const float* wb = w1 + (size_t)(kc * 512) * 256 + o;
  float acc = 0.f;
  for (int k = 0; k < 512; k++) acc = fmaf(fb[k], wb[(size_t)k * 256], acc);
  part[kc][ol] = acc;
  __syncthreads();
  if (t < 64) {
    float a = part[0][t] + part[1][t] + part[2][t] + part[3][t] + b1[oc * 64 + t];
    hs[(size_t)b * 256 + oc * 64 + t] = 0.5f * a * (1.0f + erff(a * 0.70710678118654752f));
  }
}

// ---------------- MLP stage 2: hs -> corr ----------------
__global__ void k_mlp2(const float* __restrict__ hs,
                       const float* __restrict__ w2,
                       const float* __restrict__ b2,
                       float* __restrict__ corr) {
  int b = blockIdx.x, t = threadIdx.x;   // 64 threads
  const float* hb = hs + (size_t)b * 256;
  float acc = b2[t];
  for (int k = 0; k < 256; k++) acc = fmaf(hb[k], w2[(size_t)k * 64 + t], acc);
  corr[(size_t)b * 64 + t] = acc;
}

// ---------------- stage C: mode-mixing einsum over C ----------------
// Output written in stage-DE GEMM1 B-fragment order:
// addr = bo*1024 + (j>>4)*512 + ((((j>>2)&3)<<4)|kx)*8 + (j&3)*2 + u
// (bijective with k=2j+u: k=ks*32+(lane>>4)*8+jslot, n=lane&15)
__global__ __launch_bounds__(256) void k_stageC(const float* __restrict__ xf,
                                                const float* __restrict__ w1,
                                                const float* __restrict__ w2,
                                                float* __restrict__ outft) {
  __shared__ float xfs[64 * 32];       // [c][kx*2+ri]
  int bid = blockIdx.x;
  int sw = (bid & 7) * 128 + (bid >> 3);   // bijective (1024 % 8 == 0)
  int j = sw >> 5, b = sw & 31;
  int t = threadIdx.x;
  #pragma unroll
  for (int k2 = 0; k2 < 4; k2++) {
    int id = t + k2 * 256;             // 1024 float2
    int c = id >> 4, kxi = id & 15;
    const float2 v = *reinterpret_cast<const float2*>(
        xf + (((size_t)b * 64 + c) * 32 + j) * 32 + kxi * 2);
    reinterpret_cast<float2*>(xfs)[id] = v;
  }
  __syncthreads();
  int kx = t & 15, og = t >> 4;
  const float* wsel = (j < 16) ? w1 : w2;
  int jr = (j < 16) ? j : j - 16;
  float aR[4], aI[4];
  #pragma unroll
  for (int i = 0; i < 4; i++) { aR[i] = 0.f; aI[i] = 0.f; }
  for (int c = 0; c < 64; c++) {
    float xr = xfs[c * 32 + kx * 2], xi = xfs[c * 32 + kx * 2 + 1];
    #pragma unroll
    for (int i = 0; i < 4; i++) {
      int o = og * 4 + i;
      const float2 wv = *reinterpret_cast<const float2*>(
          wsel + ((((size_t)c * 64 + o) * 16 + jr) * 16 + kx) * 2);
      aR[i] = fmaf(xr, wv.x, fmaf(-xi, wv.y, aR[i]));
      aI[i] = fmaf(xr, wv.y, fmaf(xi, wv.x, aI[i]));
    }
  }
  int boff = (j >> 4) * 512 + ((((j >> 2) & 3) << 4) | kx) * 8 + (j & 3) * 2;
  #pragma unroll
  for (int i = 0; i < 4; i++) {
    int o = og * 4 + i;
    float2* dst = reinterpret_cast<float2*>(outft + (size_t)(b * 64 + o) * 1024 + boff);
    *dst = make_float2(aR[i], aI[i]);
  }
}

// ---------------- stage DE: two chained split-bf16 MFMA GEMMs per (b,o) ----------------
// GEMM1: Y[256][16kx] = W1[256][64] * S[64][32->16]   (Y in LDS, f32)
// GEMM2: OUT[128h][128w] = Y2[128][32] * W2[32][128] + corr
__global__ __launch_bounds__(256) void k_stageDE(const float* __restrict__ outft,
                                                 const float* __restrict__ corr,
                                                 float* __restrict__ out) {
  __shared__ float Yl[256 * 17];
  int t = threadIdx.x;
  int lane = t & 63, wid = t >> 6;
  int bo = blockIdx.x;
  const float* src = outft + (size_t)bo * 1024;

  // load S fragments (contiguous 32B/lane thanks to stage-C layout), split bf16
  bf16x8 shi[2], slo[2];
  #pragma unroll
  for (int ks = 0; ks < 2; ks++) {
    float4 v0 = *reinterpret_cast<const float4*>(src + ks * 512 + lane * 8);
    float4 v1 = *reinterpret_cast<const float4*>(src + ks * 512 + lane * 8 + 4);
    float xv[8] = {v0.x, v0.y, v0.z, v0.w, v1.x, v1.y, v1.z, v1.w};
    ushort8 hu, lu;
    #pragma unroll
    for (int j = 0; j < 8; j++) {
      unsigned short h = f2bf(xv[j]);
      hu[j] = h;
      lu[j] = f2bf(xv[j] - bf2f(h));
    }
    shi[ks] = __builtin_bit_cast(bf16x8, hu);
    slo[ks] = __builtin_bit_cast(bf16x8, lu);
  }

  // GEMM1: wave wid owns m-tiles wid*4 .. wid*4+3
  #pragma unroll
  for (int mtl = 0; mtl < 4; mtl++) {
    int mt = wid * 4 + mtl;
    f32x4 acc = {0.f, 0.f, 0.f, 0.f};
    #pragma unroll
    for (int ks = 0; ks < 2; ks++) {
      bf16x8 whi = __builtin_bit_cast(bf16x8,
          *reinterpret_cast<const ushort8*>(&g_w1tab.v[mt][ks][0][lane][0]));
      bf16x8 wlo = __builtin_bit_cast(bf16x8,
          *reinterpret_cast<const ushort8*>(&g_w1tab.v[mt][ks][1][lane][0]));
      acc = __builtin_amdgcn_mfma_f32_16x16x32_bf16(whi, shi[ks], acc, 0, 0, 0);
      acc = __builtin_amdgcn_mfma_f32_16x16x32_bf16(wlo, shi[ks], acc, 0, 0, 0);
      acc = __builtin_amdgcn_mfma_f32_16x16x32_bf16(whi, slo[ks], acc, 0, 0, 0);
    }
    #pragma unroll
    for (int i = 0; i < 4; i++)
      Yl[(mt * 16 + (lane >> 4) * 4 + i) * 17 + (lane & 15)] = acc[i];
  }
  __syncthreads();

  float corrv = corr[bo];
  float* obase = out + (size_t)bo * 16384;

  // GEMM2: wave wid owns m-tiles wid*2, wid*2+1 (h rows), all 8 n-tiles (w cols)
  #pragma unroll
  for (int mtl = 0; mtl < 2; mtl++) {
    int mt2 = wid * 2 + mtl;
    int h = mt2 * 16 + (lane & 15);
    ushort8 ahiU, aloU;
    #pragma unroll
    for (int j = 0; j < 8; j++) {
      int k = (lane >> 4) * 8 + j;
      float v = Yl[((k & 1) * 128 + h) * 17 + (k >> 1)];
      unsigned short hi = f2bf(v);
      ahiU[j] = hi;
      aloU[j] = f2bf(v - bf2f(hi));
    }
    bf16x8 ahi = __builtin_bit_cast(bf16x8, ahiU);
    bf16x8 alo = __builtin_bit_cast(bf16x8, aloU);
    #pragma unroll
    for (int nt = 0; nt < 8; nt++) {
      bf16x8 bhi = __builtin_bit_cast(bf16x8,
          *reinterpret_cast<const ushort8*>(&g_w2tab.v[nt][0][lane][0]));
      bf16x8 blo = __builtin_bit_cast(bf16x8,
          *reinterpret_cast<const ushort8*>(&g_w2tab.v[nt][1][lane][0]));
      f32x4 acc = {corrv, corrv, corrv, corrv};
      acc = __builtin_amdgcn_mfma_f32_16x16x32_bf16(ahi, bhi, acc, 0, 0, 0);
      acc = __builtin_amdgcn_mfma_f32_16x16x32_bf16(alo, bhi, acc, 0, 0, 0);
      acc = __builtin_amdgcn_mfma_f32_16x16x32_bf16(ahi, blo, acc, 0, 0, 0);
      #pragma unroll
      for (int i = 0; i < 4; i++)
        obase[(mt2 * 16 + (lane >> 4) * 4 + i) * 128 + nt * 16 + (lane & 15)] = acc[i];
    }
  }
}

extern "C" void kernel_launch(void* const* d_in, const int* in_sizes, int n_in,
                              void* d_out, int out_size, void* d_ws, size_t ws_size,
                              hipStream_t stream) {
  const float* x   = (const float*)d_in[0];
  const float* w1  = (const float*)d_in[1];
  const float* w2  = (const float*)d_in[2];
  const float* l1w = (const float*)d_in[3];
  const float* l1b = (const float*)d_in[4];
  const float* l2w = (const float*)d_in[5];
  const float* l2b = (const float*)d_in[6];
  float* out = (float*)d_out;
  float* ws  = (float*)d_ws;

  float* flat  = ws + WSO_FLAT;
  float* corr  = ws + WSO_CORR;
  float* hs    = ws + WSO_HS;
  float* cft1  = ws + WSO_CFT1;
  float* xf    = ws + WSO_XF;
  float* outft = ws + WSO_OUTFT;
  float* xw    = out;   // d_out used as scratch for xw; fully rewritten by stage DE

  k_stageA<<<dim3(4096), dim3(256), 0, stream>>>(x, xw, cft1);
  k_stageB<<<dim3(2048), dim3(256), 0, stream>>>(xw, xf);
  k_cfth<<<dim3(1024), dim3(64), 0, stream>>>(cft1, flat);
  k_mlp1<<<dim3(128), dim3(256), 0, stream>>>(flat, l1w, l1b, hs);
  k_mlp2<<<dim3(32), dim3(64), 0, stream>>>(hs, l2w, l2b, corr);
  k_stageC<<<dim3(1024), dim3(256), 0, stream>>>(xf, w1, w2, outft);
  k_stageDE<<<dim3(2048), dim3(256), 0, stream>>>(outft, corr, out);
}

// Round 9
// 146.707 us; speedup vs baseline: 3.9706x; 1.3845x over previous
//
#include <hip/hip_runtime.h>
#include <math.h>

#define PI_F 3.14159265358979323846f
#define TWO_PI_F 6.28318530717958647692f

// problem sizes
constexpr int Bn = 32, Cn = 64, On = 64, Hn = 128, Wn = 128;

// workspace float offsets (small region < WSO_BIG)
constexpr size_t WSO_FLAT  = 0;                        // 32*2048 = 65536
constexpr size_t WSO_CORR  = 65536;                    // 32*64   = 2048
constexpr size_t WSO_HS    = 67584;                    // 32*256  = 8192
constexpr size_t WSO_BIG   = 81920;
constexpr size_t SZ_QTR    = (size_t)2097152;          // 2M floats
constexpr size_t WSO_XF    = WSO_BIG + SZ_QTR;         // [2048][32][16][2]
constexpr size_t WSO_OUTFT = WSO_BIG + 4 * SZ_QTR;     // [2048][1024] B-frag order

// ================= compile-time tables =================
struct Tabs {
  float ktw[128][40];
  float cfth[128][8];
};

constexpr double D_PI = 3.14159265358979323846;

constexpr double d_red(double x) {
  while (x >  D_PI) x -= 2.0 * D_PI;
  while (x < -D_PI) x += 2.0 * D_PI;
  return x;
}
constexpr double d_sin(double x) {
  x = d_red(x);
  double x2 = x * x, t = x, s = x;
  for (int n = 1; n <= 10; n++) { t *= -x2 / (double)((2 * n) * (2 * n + 1)); s += t; }
  return s;
}
constexpr double d_cos(double x) {
  x = d_red(x);
  double x2 = x * x, t = 1.0, s = 1.0;
  for (int n = 1; n <= 10; n++) { t *= -x2 / (double)((2 * n - 1) * (2 * n)); s += t; }
  return s;
}

constexpr Tabs make_tabs() {
  Tabs T{};
  double twc[128] = {}, tws[128] = {};
  for (int r = 0; r < 128; r++) {
    double a = 2.0 * D_PI * (double)r / 128.0;
    twc[r] = d_cos(a); tws[r] = d_sin(a);
  }
  for (int kx = 0; kx < 16; kx++)
    for (int w = 0; w < 128; w++) {
      int r = (kx * w) & 127;
      T.ktw[w][2 * kx]     = (float)twc[r];
      T.ktw[w][2 * kx + 1] = (float)(-tws[r]);
    }
  double node[8] = {}, theta[8] = {};
  for (int m = 0; m < 8; m++) { theta[m] = (2.0 * m + 1.0) * D_PI / 16.0; node[m] = -d_cos(theta[m]); }
  double Tch[8][8] = {};
  for (int k = 0; k < 8; k++)
    for (int m = 0; m < 8; m++) Tch[k][m] = d_cos((double)k * (D_PI - theta[m]));
  int LE[4][8] = {}, RI[4][8] = {};
  float WL[4][8] = {}, WR[4][8] = {};
  for (int l = 0; l < 4; l++)
    for (int m = 0; m < 8; m++) {
      float tseg = (float)(0.25 * (double)l + 0.125 * (node[m] + 1.0));
      int ri = (int)(tseg * 127.0f) - 2; if (ri < 0) ri = 0;
      while (ri < 127 && ((float)ri * (1.0f / 127.0f)) < tseg) ri++;
      int le = ri - 1; if (le < 0) le = 0;
      float tl = (float)le * (1.0f / 127.0f), tr = (float)ri * (1.0f / 127.0f);
      float den = (tr - tl < 1e-8f) ? 1.0f : (tr - tl);
      float wr = (tseg - tl) / den;
      LE[l][m] = le; RI[l][m] = ri; WR[l][m] = wr; WL[l][m] = 1.0f - wr;
    }
  for (int p = 0; p < 2; p++)
    for (int f = 0; f < 4; f++) {
      double fval = (p == 0) ? (double)f
                             : ((f == 0) ? 0.0 : (f == 1) ? 1.0 : (f == 2) ? -2.0 : -1.0);
      double wp = fval * (2.0 * D_PI * 0.125);
      double Wr[8] = {}, Wi[8] = {};
      for (int k = 0; k < 8; k++) {
        double sr = 0.0, si = 0.0;
        for (int m = 0; m < 8; m++) {
          sr += Tch[k][m] * d_cos(node[m] * wp);
          si += Tch[k][m] * (-d_sin(node[m] * wp));
        }
        Wr[k] = sr * 0.125; Wi[k] = si * 0.125;
      }
      for (int l = 0; l < 4; l++) {
        double ph = -2.0 * D_PI * (0.25 * (double)l) * fval;
        double cr = d_cos(ph), ci = d_sin(ph);
        for (int m = 0; m < 8; m++) {
          double coefR = Wr[m] * cr - Wi[m] * ci;
          double coefI = Wr[m] * ci + Wi[m] * cr;
          int le = LE[l][m], ri = RI[l][m];
          if (p == 0) {
            T.ktw[le][32 + f] += (float)(WL[l][m] * coefR);
            T.ktw[le][36 + f] += (float)(WL[l][m] * coefI);
            T.ktw[ri][32 + f] += (float)(WR[l][m] * coefR);
            T.ktw[ri][36 + f] += (float)(WR[l][m] * coefI);
          } else {
            T.cfth[le][f]     += (float)(WL[l][m] * coefR);
            T.cfth[le][4 + f] += (float)(WL[l][m] * coefI);
            T.cfth[ri][f]     += (float)(WR[l][m] * coefR);
            T.cfth[ri][4 + f] += (float)(WR[l][m] * coefI);
          }
        }
      }
    }
  return T;
}

// ---- bf16 split helpers (RNE via bit trick) ----
constexpr unsigned short cf2bf(float f) {
  unsigned u = __builtin_bit_cast(unsigned, f);
  u += 0x7FFFu + ((u >> 16) & 1u);
  return (unsigned short)(u >> 16);
}
constexpr float cbf2f(unsigned short h) {
  return __builtin_bit_cast(float, (unsigned)h << 16);
}

// -------- cfth coefficient table (f32) --------
struct CfthT { float v[128][8]; };
constexpr CfthT make_cfth() {
  CfthT C{};
  Tabs T = make_tabs();
  for (int h = 0; h < 128; h++)
    for (int q = 0; q < 8; q++) C.v[h][q] = T.cfth[h][q];
  return C;
}
__constant__ CfthT g_cfth = make_cfth();

// -------- stage A B-table: [rows x 128] * [128 x 40(+8 pad)] --------
// mfma_f32_16x16x32_bf16: A row=lane&15, k=(lane>>4)*8+j; B col=lane&15, same k;
// D col=lane&15, row=(lane>>4)*4+i.  (verified rounds 6-8)
struct alignas(16) BTab {
  unsigned short v[4][2][3][64][8];   // [kstep][hi/lo][jtile][lane][j]
};
constexpr BTab make_btab() {
  BTab B{};
  Tabs T = make_tabs();
  for (int ks = 0; ks < 4; ks++)
    for (int jt = 0; jt < 3; jt++)
      for (int lane = 0; lane < 64; lane++)
        for (int j = 0; j < 8; j++) {
          int col = jt * 16 + (lane & 15);
          int k = ks * 32 + (lane >> 4) * 8 + j;
          float val = (col < 40) ? T.ktw[k][col] : 0.0f;
          unsigned short h = cf2bf(val);
          B.v[ks][0][jt][lane][j] = h;
          B.v[ks][1][jt][lane][j] = cf2bf(val - cbf2f(h));
        }
  return B;
}
__constant__ BTab g_btab = make_btab();

// -------- fwd B-part A-table: TB[64 m=(ri*32+j)][256 k=(2h+u)] --------
// ri=0 (xfR): u0 -> cos th, u1 -> sin th;  ri=1 (xfI): u0 -> -sin, u1 -> cos
// th = 2pi ky_j h / 128, ky_j = j<16 ? j : j+96
struct alignas(16) TBTab {
  unsigned short v[4][8][2][64][8];   // [mtile][kstep][hi/lo][lane][j]
};
constexpr TBTab make_tbtab() {
  TBTab T{};
  double twc[128] = {}, tws[128] = {};
  for (int r = 0; r < 128; r++) {
    double a = 2.0 * D_PI * (double)r / 128.0;
    twc[r] = d_cos(a); tws[r] = d_sin(a);
  }
  for (int mt = 0; mt < 4; mt++)
    for (int ks = 0; ks < 8; ks++)
      for (int lane = 0; lane < 64; lane++)
        for (int js = 0; js < 8; js++) {
          int m = mt * 16 + (lane & 15);
          int j = m & 31, ri = m >> 5;
          int k = ks * 32 + (lane >> 4) * 8 + js;
          int h = k >> 1, u = k & 1;
          int ky = (j < 16) ? j : j + 96;
          int idx = (ky * h) & 127;
          double c = twc[idx], s = tws[idx];
          double val = (ri == 0) ? ((u == 0) ? c : s)
                                 : ((u == 0) ? -s : c);
          float f = (float)val;
          unsigned short hi = cf2bf(f);
          T.v[mt][ks][0][lane][js] = hi;
          T.v[mt][ks][1][lane][js] = cf2bf(f - cbf2f(hi));
        }
  return T;
}
__constant__ TBTab g_tbtab = make_tbtab();

// -------- stage DE GEMM1 A-table: W1[256 r=(u*128+h)][64 k=(2jj+u')] * (1/128) --------
struct alignas(16) W1Tab {
  unsigned short v[16][2][2][64][8];  // [mtile][kstep][hi/lo][lane][j]
};
constexpr W1Tab make_w1tab() {
  W1Tab T{};
  double twc[128] = {}, tws[128] = {};
  for (int r = 0; r < 128; r++) {
    double a = 2.0 * D_PI * (double)r / 128.0;
    twc[r] = d_cos(a); tws[r] = d_sin(a);
  }
  for (int mt = 0; mt < 16; mt++)
    for (int ks = 0; ks < 2; ks++)
      for (int lane = 0; lane < 64; lane++)
        for (int j = 0; j < 8; j++) {
          int r = mt * 16 + (lane & 15);
          int k = ks * 32 + (lane >> 4) * 8 + j;
          int jj = k >> 1, u = k & 1;
          int ky = (jj < 16) ? jj : jj + 96;
          int h = r & 127;
          int idx = (ky * h) & 127;
          double c = twc[idx], s = tws[idx];
          double val = (r < 128) ? ((u == 0) ? c : -s)
                                 : ((u == 0) ? s : c);
          float f = (float)(val * (1.0 / 128.0));
          unsigned short hi = cf2bf(f);
          T.v[mt][ks][0][lane][j] = hi;
          T.v[mt][ks][1][lane][j] = cf2bf(f - cbf2f(hi));
        }
  return T;
}
__constant__ W1Tab g_w1tab = make_w1tab();

// -------- stage DE GEMM2 B-table: W2[32 k][128 w] * (1/128), c2r folded --------
struct alignas(16) W2Tab {
  unsigned short v[8][2][64][8];      // [ntile][hi/lo][lane][j]
};
constexpr W2Tab make_w2tab() {
  W2Tab T{};
  double twc[128] = {}, tws[128] = {};
  for (int r = 0; r < 128; r++) {
    double a = 2.0 * D_PI * (double)r / 128.0;
    twc[r] = d_cos(a); tws[r] = d_sin(a);
  }
  for (int nt = 0; nt < 8; nt++)
    for (int lane = 0; lane < 64; lane++)
      for (int j = 0; j < 8; j++) {
        int w = nt * 16 + (lane & 15);
        int k = (lane >> 4) * 8 + j;
        int kx = k >> 1, u = k & 1;
        double val;
        if (kx == 0) val = (u == 0) ? 1.0 : 0.0;
        else {
          int idx = (kx * w) & 127;
          val = (u == 0) ? 2.0 * twc[idx] : -2.0 * tws[idx];
        }
        float f = (float)(val * (1.0 / 128.0));
        unsigned short hi = cf2bf(f);
        T.v[nt][0][lane][j] = hi;
        T.v[nt][1][lane][j] = cf2bf(f - cbf2f(hi));
      }
  return T;
}
__constant__ W2Tab g_w2tab = make_w2tab();

typedef __attribute__((ext_vector_type(8))) __bf16 bf16x8;
typedef __attribute__((ext_vector_type(8))) unsigned short ushort8;
typedef __attribute__((ext_vector_type(4))) float f32x4;

__device__ __forceinline__ unsigned short f2bf(float f) {
  unsigned u = __builtin_bit_cast(unsigned, f);
  u += 0x7FFFu + ((u >> 16) & 1u);
  return (unsigned short)(u >> 16);
}
__device__ __forceinline__ float bf2f(unsigned short h) {
  return __builtin_bit_cast(float, (unsigned)h << 16);
}

// ---------------- fwd: fused stage A + stage B + CFT H-pass, one block per (b,c) ----------------
// A-part: [128 rows x 128] * [128 x 40] MFMA GEMM -> LDS xwl[128][32] + cftl[128][8]
// B-part: xf[64 m][16 kx] = TB[64][256(h,u)] * xwl[256][16] MFMA GEMM (twiddles const)
// cft-part: reduce cftl over h with g_cfth -> flat (32 values per bc)
__global__ __launch_bounds__(256) void k_fwd(const float* __restrict__ x,
                                             float* __restrict__ xf,
                                             float* __restrict__ flat) {
  __shared__ float xwl[128][34];       // [h][j=2kx+u], pad 34 (2-way conflicts = free)
  __shared__ float cftl[128][9];
  __shared__ float cpart[8][33];
  int t = threadIdx.x;
  int lane = t & 63, wid = t >> 6;
  int bc = blockIdx.x;
  const float* xb = x + (size_t)bc * 16384;

  // ---- A-part: 2 row-tiles per wave ----
  #pragma unroll
  for (int tl = 0; tl < 2; tl++) {
    int rt = wid * 2 + tl;
    int r = lane & 15, kg = lane >> 4;
    const float* arow = xb + (rt * 16 + r) * 128 + kg * 8;
    bf16x8 ahi[4], alo[4];
    #pragma unroll
    for (int ks = 0; ks < 4; ks++) {
      float4 v0 = *reinterpret_cast<const float4*>(arow + ks * 32);
      float4 v1 = *reinterpret_cast<const float4*>(arow + ks * 32 + 4);
      float xv[8] = {v0.x, v0.y, v0.z, v0.w, v1.x, v1.y, v1.z, v1.w};
      ushort8 hu, lu;
      #pragma unroll
      for (int j = 0; j < 8; j++) {
        unsigned short h = f2bf(xv[j]);
        hu[j] = h;
        lu[j] = f2bf(xv[j] - bf2f(h));
      }
      ahi[ks] = __builtin_bit_cast(bf16x8, hu);
      alo[ks] = __builtin_bit_cast(bf16x8, lu);
    }
    #pragma unroll
    for (int jt = 0; jt < 3; jt++) {
      f32x4 acc = {0.f, 0.f, 0.f, 0.f};
      #pragma unroll
      for (int ks = 0; ks < 4; ks++) {
        bf16x8 bhi = __builtin_bit_cast(bf16x8,
            *reinterpret_cast<const ushort8*>(&g_btab.v[ks][0][jt][lane][0]));
        bf16x8 blo = __builtin_bit_cast(bf16x8,
            *reinterpret_cast<const ushort8*>(&g_btab.v[ks][1][jt][lane][0]));
        acc = __builtin_amdgcn_mfma_f32_16x16x32_bf16(ahi[ks], bhi, acc, 0, 0, 0);
        acc = __builtin_amdgcn_mfma_f32_16x16x32_bf16(alo[ks], bhi, acc, 0, 0, 0);
        acc = __builtin_amdgcn_mfma_f32_16x16x32_bf16(ahi[ks], blo, acc, 0, 0, 0);
      }
      int col = lane & 15, rq = lane >> 4;
      #pragma unroll
      for (int i = 0; i < 4; i++) {
        int rl = rt * 16 + rq * 4 + i;
        if (jt < 2) xwl[rl][jt * 16 + col] = acc[i];
        else if (col < 8) cftl[rl][col] = acc[i];
      }
    }
  }
  __syncthreads();

  // ---- cft partial reduce (all 256 threads) ----
  {
    int o = t & 31, seg = t >> 5;
    int f1 = o >> 3, f2 = (o >> 1) & 3, ri = o & 1;
    float acc = 0.f;
    #pragma unroll
    for (int hh = 0; hh < 16; hh++) {
      int h = seg * 16 + hh;
      float rr = cftl[h][f2], im = cftl[h][4 + f2];
      float kr = g_cfth.v[h][f1], ki = g_cfth.v[h][4 + f1];
      float e0 = ri ? ki : kr;
      float e1 = ri ? kr : -ki;
      acc = fmaf(rr, e0, fmaf(im, e1, acc));
    }
    cpart[seg][o] = acc;
  }

  // ---- B-part: wave wid owns m-tile wid ----
  {
    int kx = lane & 15, g = lane >> 4;
    f32x4 acc = {0.f, 0.f, 0.f, 0.f};
    #pragma unroll
    for (int ks = 0; ks < 8; ks++) {
      int h0 = ks * 16 + g * 4;
      ushort8 bhU, blU;
      #pragma unroll
      for (int rr = 0; rr < 4; rr++) {
        float2 p = *reinterpret_cast<const float2*>(&xwl[h0 + rr][2 * kx]);
        unsigned short hx = f2bf(p.x);
        bhU[2 * rr] = hx; blU[2 * rr] = f2bf(p.x - bf2f(hx));
        unsigned short hy = f2bf(p.y);
        bhU[2 * rr + 1] = hy; blU[2 * rr + 1] = f2bf(p.y - bf2f(hy));
      }
      bf16x8 bhi = __builtin_bit_cast(bf16x8, bhU);
      bf16x8 blo = __builtin_bit_cast(bf16x8, blU);
      bf16x8 thi = __builtin_bit_cast(bf16x8,
          *reinterpret_cast<const ushort8*>(&g_tbtab.v[wid][ks][0][lane][0]));
      bf16x8 tlo = __builtin_bit_cast(bf16x8,
          *reinterpret_cast<const ushort8*>(&g_tbtab.v[wid][ks][1][lane][0]));
      acc = __builtin_amdgcn_mfma_f32_16x16x32_bf16(thi, bhi, acc, 0, 0, 0);
      acc = __builtin_amdgcn_mfma_f32_16x16x32_bf16(tlo, bhi, acc, 0, 0, 0);
      acc = __builtin_amdgcn_mfma_f32_16x16x32_bf16(thi, blo, acc, 0, 0, 0);
    }
    #pragma unroll
    for (int i = 0; i < 4; i++) {
      int m = wid * 16 + (lane >> 4) * 4 + i;
      int j = m & 31, ri = m >> 5;
      xf[((size_t)bc * 32 + j) * 32 + kx * 2 + ri] = acc[i];
    }
  }
  __syncthreads();

  if (t < 32) {
    float s = 0.f;
    #pragma unroll
    for (int seg = 0; seg < 8; seg++) s += cpart[seg][t];
    int b = bc >> 6, c = bc & 63;
    int f1 = t >> 3, f2 = (t >> 1) & 3, ri = t & 1;
    flat[(size_t)b * 2048 + ((c * 4 + f1) * 4 + f2) * 2 + ri] = s;
  }
}

// ---------------- MLP stage 1: flat -> hs ----------------
__global__ __launch_bounds__(256) void k_mlp1(const float* __restrict__ flat,
                                              const float* __restrict__ w1,
                                              const float* __restrict__ b1,
                                              float* __restrict__ hs) {
  __shared__ float part[4][64];
  int bid = blockIdx.x;
  int b = bid >> 2, oc = bid & 3;
  int t = threadIdx.x;
  int ol = t & 63, kc = t >> 6;
  int o = oc * 64 + ol;
  const float* fb = flat + (size_t)b * 2048 + kc * 512;
  const float* wb = w1 + (size_t)(kc * 512) * 256 + o;
  float acc = 0.f;
  for (int k = 0; k < 512; k++) acc = fmaf(fb[k], wb[(size_t)k * 256], acc);
  part[kc][ol] = acc;
  __syncthreads();
  if (t < 64) {
    float a = part[0][t] + part[1][t] + part[2][t] + part[3][t] + b1[oc * 64 + t];
    hs[(size_t)b * 256 + oc * 64 + t] = 0.5f * a * (1.0f + erff(a * 0.70710678118654752f));
  }
}

// ---------------- MLP stage 2: hs -> corr ----------------
__global__ void k_mlp2(const float* __restrict__ hs,
                       const float* __restrict__ w2,
                       const float* __restrict__ b2,
                       float* __restrict__ corr) {
  int b = blockIdx.x, t = threadIdx.x;   // 64 threads
  const float* hb = hs + (size_t)b * 256;
  float acc = b2[t];
  for (int k = 0; k < 256; k++) acc = fmaf(hb[k], w2[(size_t)k * 64 + t], acc);
  corr[(size_t)b * 64 + t] = acc;
}

// ---------------- stage C: mode-mixing einsum over C ----------------
// Output written in stage-DE GEMM1 B-fragment order (verified round 8).
__global__ __launch_bounds__(256) void k_stageC(const float* __restrict__ xf,
                                                const float* __restrict__ w1,
                                                const float* __restrict__ w2,
                                                float* __restrict__ outft) {
  __shared__ float xfs[64 * 32];       // [c][kx*2+ri]
  int bid = blockIdx.x;
  int sw = (bid & 7) * 128 + (bid >> 3);   // bijective (1024 % 8 == 0)
  int j = sw >> 5, b = sw & 31;
  int t = threadIdx.x;
  #pragma unroll
  for (int k2 = 0; k2 < 4; k2++) {
    int id = t + k2 * 256;             // 1024 float2
    int c = id >> 4, kxi = id & 15;
    const float2 v = *reinterpret_cast<const float2*>(
        xf + (((size_t)b * 64 + c) * 32 + j) * 32 + kxi * 2);
    reinterpret_cast<float2*>(xfs)[id] = v;
  }
  __syncthreads();
  int kx = t & 15, og = t >> 4;
  const float* wsel = (j < 16) ? w1 : w2;
  int jr = (j < 16) ? j : j - 16;
  float aR[4], aI[4];
  #pragma unroll
  for (int i = 0; i < 4; i++) { aR[i] = 0.f; aI[i] = 0.f; }
  for (int c = 0; c < 64; c++) {
    float xr = xfs[c * 32 + kx * 2], xi = xfs[c * 32 + kx * 2 + 1];
    #pragma unroll
    for (int i = 0; i < 4; i++) {
      int o = og * 4 + i;
      const float2 wv = *reinterpret_cast<const float2*>(
          wsel + ((((size_t)c * 64 + o) * 16 + jr) * 16 + kx) * 2);
      aR[i] = fmaf(xr, wv.x, fmaf(-xi, wv.y, aR[i]));
      aI[i] = fmaf(xr, wv.y, fmaf(xi, wv.x, aI[i]));
    }
  }
  int boff = (j >> 4) * 512 + ((((j >> 2) & 3) << 4) | kx) * 8 + (j & 3) * 2;
  #pragma unroll
  for (int i = 0; i < 4; i++) {
    int o = og * 4 + i;
    float2* dst = reinterpret_cast<float2*>(outft + (size_t)(b * 64 + o) * 1024 + boff);
    *dst = make_float2(aR[i], aI[i]);
  }
}

// ---------------- stage DE: two chained split-bf16 MFMA GEMMs per (b,o) ----------------
__global__ __launch_bounds__(256) void k_stageDE(const float* __restrict__ outft,
                                                 const float* __restrict__ corr,
                                                 float* __restrict__ out) {
  __shared__ float Yl[256 * 17];
  int t = threadIdx.x;
  int lane = t & 63, wid = t >> 6;
  int bo = blockIdx.x;
  const float* src = outft + (size_t)bo * 1024;

  bf16x8 shi[2], slo[2];
  #pragma unroll
  for (int ks = 0; ks < 2; ks++) {
    float4 v0 = *reinterpret_cast<const float4*>(src + ks * 512 + lane * 8);
    float4 v1 = *reinterpret_cast<const float4*>(src + ks * 512 + lane * 8 + 4);
    float xv[8] = {v0.x, v0.y, v0.z, v0.w, v1.x, v1.y, v1.z, v1.w};
    ushort8 hu, lu;
    #pragma unroll
    for (int j = 0; j < 8; j++) {
      unsigned short h = f2bf(xv[j]);
      hu[j] = h;
      lu[j] = f2bf(xv[j] - bf2f(h));
    }
    shi[ks] = __builtin_bit_cast(bf16x8, hu);
    slo[ks] = __builtin_bit_cast(bf16x8, lu);
  }

  #pragma unroll
  for (int mtl = 0; mtl < 4; mtl++) {
    int mt = wid * 4 + mtl;
    f32x4 acc = {0.f, 0.f, 0.f, 0.f};
    #pragma unroll
    for (int ks = 0; ks < 2; ks++) {
      bf16x8 whi = __builtin_bit_cast(bf16x8,
          *reinterpret_cast<const ushort8*>(&g_w1tab.v[mt][ks][0][lane][0]));
      bf16x8 wlo = __builtin_bit_cast(bf16x8,
          *reinterpret_cast<const ushort8*>(&g_w1tab.v[mt][ks][1][lane][0]));
      acc = __builtin_amdgcn_mfma_f32_16x16x32_bf16(whi, shi[ks], acc, 0, 0, 0);
      acc = __builtin_amdgcn_mfma_f32_16x16x32_bf16(wlo, shi[ks], acc, 0, 0, 0);
      acc = __builtin_amdgcn_mfma_f32_16x16x32_bf16(whi, slo[ks], acc, 0, 0, 0);
    }
    #pragma unroll
    for (int i = 0; i < 4; i++)
      Yl[(mt * 16 + (lane >> 4) * 4 + i) * 17 + (lane & 15)] = acc[i];
  }
  __syncthreads();

  float corrv = corr[bo];
  float* obase = out + (size_t)bo * 16384;

  #pragma unroll
  for (int mtl = 0; mtl < 2; mtl++) {
    int mt2 = wid * 2 + mtl;
    int h = mt2 * 16 + (lane & 15);
    ushort8 ahiU, aloU;
    #pragma unroll
    for (int j = 0; j < 8; j++) {
      int k = (lane >> 4) * 8 + j;
      float v = Yl[((k & 1) * 128 + h) * 17 + (k >> 1)];
      unsigned short hi = f2bf(v);
      ahiU[j] = hi;
      aloU[j] = f2bf(v - bf2f(hi));
    }
    bf16x8 ahi = __builtin_bit_cast(bf16x8, ahiU);
    bf16x8 alo = __builtin_bit_cast(bf16x8, aloU);
    #pragma unroll
    for (int nt = 0; nt < 8; nt++) {
      bf16x8 bhi = __builtin_bit_cast(bf16x8,
          *reinterpret_cast<const ushort8*>(&g_w2tab.v[nt][0][lane][0]));
      bf16x8 blo = __builtin_bit_cast(bf16x8,
          *reinterpret_cast<const ushort8*>(&g_w2tab.v[nt][1][lane][0]));
      f32x4 acc = {corrv, corrv, corrv, corrv};
      acc = __builtin_amdgcn_mfma_f32_16x16x32_bf16(ahi, bhi, acc, 0, 0, 0);
      acc = __builtin_amdgcn_mfma_f32_16x16x32_bf16(alo, bhi, acc, 0, 0, 0);
      acc = __builtin_amdgcn_mfma_f32_16x16x32_bf16(ahi, blo, acc, 0, 0, 0);
      #pragma unroll
      for (int i = 0; i < 4; i++)
        obase[(mt2 * 16 + (lane >> 4) * 4 + i) * 128 + nt * 16 + (lane & 15)] = acc[i];
    }
  }
}

extern "C" void kernel_launch(void* const* d_in, const int* in_sizes, int n_in,
                              void* d_out, int out_size, void* d_ws, size_t ws_size,
                              hipStream_t stream) {
  const float* x   = (const float*)d_in[0];
  const float* w1  = (const float*)d_in[1];
  const float* w2  = (const float*)d_in[2];
  const float* l1w = (const float*)d_in[3];
  const float* l1b = (const float*)d_in[4];
  const float* l2w = (const float*)d_in[5];
  const float* l2b = (const float*)d_in[6];
  float* out = (float*)d_out;
  float* ws  = (float*)d_ws;

  float* flat  = ws + WSO_FLAT;
  float* corr  = ws + WSO_CORR;
  float* hs    = ws + WSO_HS;
  float* xf    = ws + WSO_XF;
  float* outft = ws + WSO_OUTFT;

  k_fwd<<<dim3(2048), dim3(256), 0, stream>>>(x, xf, flat);
  k_mlp1<<<dim3(128), dim3(256), 0, stream>>>(flat, l1w, l1b, hs);
  k_mlp2<<<dim3(32), dim3(64), 0, stream>>>(hs, l2w, l2b, corr);
  k_stageC<<<dim3(1024), dim3(256), 0, stream>>>(xf, w1, w2, outft);
  k_stageDE<<<dim3(2048), dim3(256), 0, stream>>>(outft, corr, out);
}

// Round 10
// 143.968 us; speedup vs baseline: 4.0461x; 1.0190x over previous
//
#include <hip/hip_runtime.h>
#include <math.h>

#define PI_F 3.14159265358979323846f
#define TWO_PI_F 6.28318530717958647692f

// problem sizes
constexpr int Bn = 32, Cn = 64, On = 64, Hn = 128, Wn = 128;

// workspace float offsets (small region < WSO_BIG)
constexpr size_t WSO_FLAT  = 0;                        // 32*2048 = 65536
constexpr size_t WSO_CORR  = 65536;                    // 32*64   = 2048
constexpr size_t WSO_HS    = 67584;                    // 32*256  = 8192
constexpr size_t WSO_BIG   = 81920;
constexpr size_t SZ_QTR    = (size_t)2097152;          // 2M floats
constexpr size_t WSO_XF    = WSO_BIG + SZ_QTR;         // [2048][32][16][2]
constexpr size_t WSO_OUTFT = WSO_BIG + 4 * SZ_QTR;     // [2048][1024] B-frag order

// ================= compile-time tables =================
struct Tabs {
  float ktw[128][40];
  float cfth[128][8];
};

constexpr double D_PI = 3.14159265358979323846;

constexpr double d_red(double x) {
  while (x >  D_PI) x -= 2.0 * D_PI;
  while (x < -D_PI) x += 2.0 * D_PI;
  return x;
}
constexpr double d_sin(double x) {
  x = d_red(x);
  double x2 = x * x, t = x, s = x;
  for (int n = 1; n <= 10; n++) { t *= -x2 / (double)((2 * n) * (2 * n + 1)); s += t; }
  return s;
}
constexpr double d_cos(double x) {
  x = d_red(x);
  double x2 = x * x, t = 1.0, s = 1.0;
  for (int n = 1; n <= 10; n++) { t *= -x2 / (double)((2 * n - 1) * (2 * n)); s += t; }
  return s;
}

constexpr Tabs make_tabs() {
  Tabs T{};
  double twc[128] = {}, tws[128] = {};
  for (int r = 0; r < 128; r++) {
    double a = 2.0 * D_PI * (double)r / 128.0;
    twc[r] = d_cos(a); tws[r] = d_sin(a);
  }
  for (int kx = 0; kx < 16; kx++)
    for (int w = 0; w < 128; w++) {
      int r = (kx * w) & 127;
      T.ktw[w][2 * kx]     = (float)twc[r];
      T.ktw[w][2 * kx + 1] = (float)(-tws[r]);
    }
  double node[8] = {}, theta[8] = {};
  for (int m = 0; m < 8; m++) { theta[m] = (2.0 * m + 1.0) * D_PI / 16.0; node[m] = -d_cos(theta[m]); }
  double Tch[8][8] = {};
  for (int k = 0; k < 8; k++)
    for (int m = 0; m < 8; m++) Tch[k][m] = d_cos((double)k * (D_PI - theta[m]));
  int LE[4][8] = {}, RI[4][8] = {};
  float WL[4][8] = {}, WR[4][8] = {};
  for (int l = 0; l < 4; l++)
    for (int m = 0; m < 8; m++) {
      float tseg = (float)(0.25 * (double)l + 0.125 * (node[m] + 1.0));
      int ri = (int)(tseg * 127.0f) - 2; if (ri < 0) ri = 0;
      while (ri < 127 && ((float)ri * (1.0f / 127.0f)) < tseg) ri++;
      int le = ri - 1; if (le < 0) le = 0;
      float tl = (float)le * (1.0f / 127.0f), tr = (float)ri * (1.0f / 127.0f);
      float den = (tr - tl < 1e-8f) ? 1.0f : (tr - tl);
      float wr = (tseg - tl) / den;
      LE[l][m] = le; RI[l][m] = ri; WR[l][m] = wr; WL[l][m] = 1.0f - wr;
    }
  for (int p = 0; p < 2; p++)
    for (int f = 0; f < 4; f++) {
      double fval = (p == 0) ? (double)f
                             : ((f == 0) ? 0.0 : (f == 1) ? 1.0 : (f == 2) ? -2.0 : -1.0);
      double wp = fval * (2.0 * D_PI * 0.125);
      double Wr[8] = {}, Wi[8] = {};
      for (int k = 0; k < 8; k++) {
        double sr = 0.0, si = 0.0;
        for (int m = 0; m < 8; m++) {
          sr += Tch[k][m] * d_cos(node[m] * wp);
          si += Tch[k][m] * (-d_sin(node[m] * wp));
        }
        Wr[k] = sr * 0.125; Wi[k] = si * 0.125;
      }
      for (int l = 0; l < 4; l++) {
        double ph = -2.0 * D_PI * (0.25 * (double)l) * fval;
        double cr = d_cos(ph), ci = d_sin(ph);
        for (int m = 0; m < 8; m++) {
          double coefR = Wr[m] * cr - Wi[m] * ci;
          double coefI = Wr[m] * ci + Wi[m] * cr;
          int le = LE[l][m], ri = RI[l][m];
          if (p == 0) {
            T.ktw[le][32 + f] += (float)(WL[l][m] * coefR);
            T.ktw[le][36 + f] += (float)(WL[l][m] * coefI);
            T.ktw[ri][32 + f] += (float)(WR[l][m] * coefR);
            T.ktw[ri][36 + f] += (float)(WR[l][m] * coefI);
          } else {
            T.cfth[le][f]     += (float)(WL[l][m] * coefR);
            T.cfth[le][4 + f] += (float)(WL[l][m] * coefI);
            T.cfth[ri][f]     += (float)(WR[l][m] * coefR);
            T.cfth[ri][4 + f] += (float)(WR[l][m] * coefI);
          }
        }
      }
    }
  return T;
}

// ---- bf16 split helpers (RNE via bit trick) ----
constexpr unsigned short cf2bf(float f) {
  unsigned u = __builtin_bit_cast(unsigned, f);
  u += 0x7FFFu + ((u >> 16) & 1u);
  return (unsigned short)(u >> 16);
}
constexpr float cbf2f(unsigned short h) {
  return __builtin_bit_cast(float, (unsigned)h << 16);
}

// -------- cfth coefficient table (f32) --------
struct CfthT { float v[128][8]; };
constexpr CfthT make_cfth() {
  CfthT C{};
  Tabs T = make_tabs();
  for (int h = 0; h < 128; h++)
    for (int q = 0; q < 8; q++) C.v[h][q] = T.cfth[h][q];
  return C;
}
__constant__ CfthT g_cfth = make_cfth();

// -------- stage A B-table: [rows x 128] * [128 x 40(+8 pad)] --------
struct alignas(16) BTab {
  unsigned short v[4][2][3][64][8];   // [kstep][hi/lo][jtile][lane][j]
};
constexpr BTab make_btab() {
  BTab B{};
  Tabs T = make_tabs();
  for (int ks = 0; ks < 4; ks++)
    for (int jt = 0; jt < 3; jt++)
      for (int lane = 0; lane < 64; lane++)
        for (int j = 0; j < 8; j++) {
          int col = jt * 16 + (lane & 15);
          int k = ks * 32 + (lane >> 4) * 8 + j;
          float val = (col < 40) ? T.ktw[k][col] : 0.0f;
          unsigned short h = cf2bf(val);
          B.v[ks][0][jt][lane][j] = h;
          B.v[ks][1][jt][lane][j] = cf2bf(val - cbf2f(h));
        }
  return B;
}
__constant__ BTab g_btab = make_btab();

// -------- fwd B-part A-table: TB[64 m=(ri*32+j)][256 k=(2h+u)] --------
struct alignas(16) TBTab {
  unsigned short v[4][8][2][64][8];   // [mtile][kstep][hi/lo][lane][j]
};
constexpr TBTab make_tbtab() {
  TBTab T{};
  double twc[128] = {}, tws[128] = {};
  for (int r = 0; r < 128; r++) {
    double a = 2.0 * D_PI * (double)r / 128.0;
    twc[r] = d_cos(a); tws[r] = d_sin(a);
  }
  for (int mt = 0; mt < 4; mt++)
    for (int ks = 0; ks < 8; ks++)
      for (int lane = 0; lane < 64; lane++)
        for (int js = 0; js < 8; js++) {
          int m = mt * 16 + (lane & 15);
          int j = m & 31, ri = m >> 5;
          int k = ks * 32 + (lane >> 4) * 8 + js;
          int h = k >> 1, u = k & 1;
          int ky = (j < 16) ? j : j + 96;
          int idx = (ky * h) & 127;
          double c = twc[idx], s = tws[idx];
          double val = (ri == 0) ? ((u == 0) ? c : s)
                                 : ((u == 0) ? -s : c);
          float f = (float)val;
          unsigned short hi = cf2bf(f);
          T.v[mt][ks][0][lane][js] = hi;
          T.v[mt][ks][1][lane][js] = cf2bf(f - cbf2f(hi));
        }
  return T;
}
__constant__ TBTab g_tbtab = make_tbtab();

// -------- stage DE GEMM1 A-table: W1[256 r=(u*128+h)][64 k=(2jj+u')] * (1/128) --------
struct alignas(16) W1Tab {
  unsigned short v[16][2][2][64][8];  // [mtile][kstep][hi/lo][lane][j]
};
constexpr W1Tab make_w1tab() {
  W1Tab T{};
  double twc[128] = {}, tws[128] = {};
  for (int r = 0; r < 128; r++) {
    double a = 2.0 * D_PI * (double)r / 128.0;
    twc[r] = d_cos(a); tws[r] = d_sin(a);
  }
  for (int mt = 0; mt < 16; mt++)
    for (int ks = 0; ks < 2; ks++)
      for (int lane = 0; lane < 64; lane++)
        for (int j = 0; j < 8; j++) {
          int r = mt * 16 + (lane & 15);
          int k = ks * 32 + (lane >> 4) * 8 + j;
          int jj = k >> 1, u = k & 1;
          int ky = (jj < 16) ? jj : jj + 96;
          int h = r & 127;
          int idx = (ky * h) & 127;
          double c = twc[idx], s = tws[idx];
          double val = (r < 128) ? ((u == 0) ? c : -s)
                                 : ((u == 0) ? s : c);
          float f = (float)(val * (1.0 / 128.0));
          unsigned short hi = cf2bf(f);
          T.v[mt][ks][0][lane][j] = hi;
          T.v[mt][ks][1][lane][j] = cf2bf(f - cbf2f(hi));
        }
  return T;
}
__constant__ W1Tab g_w1tab = make_w1tab();

// -------- stage DE GEMM2 B-table: W2[32 k][128 w] * (1/128), c2r folded --------
struct alignas(16) W2Tab {
  unsigned short v[8][2][64][8];      // [ntile][hi/lo][lane][j]
};
constexpr W2Tab make_w2tab() {
  W2Tab T{};
  double twc[128] = {}, tws[128] = {};
  for (int r = 0; r < 128; r++) {
    double a = 2.0 * D_PI * (double)r / 128.0;
    twc[r] = d_cos(a); tws[r] = d_sin(a);
  }
  for (int nt = 0; nt < 8; nt++)
    for (int lane = 0; lane < 64; lane++)
      for (int j = 0; j < 8; j++) {
        int w = nt * 16 + (lane & 15);
        int k = (lane >> 4) * 8 + j;
        int kx = k >> 1, u = k & 1;
        double val;
        if (kx == 0) val = (u == 0) ? 1.0 : 0.0;
        else {
          int idx = (kx * w) & 127;
          val = (u == 0) ? 2.0 * twc[idx] : -2.0 * tws[idx];
        }
        float f = (float)(val * (1.0 / 128.0));
        unsigned short hi = cf2bf(f);
        T.v[nt][0][lane][j] = hi;
        T.v[nt][1][lane][j] = cf2bf(f - cbf2f(hi));
      }
  return T;
}
__constant__ W2Tab g_w2tab = make_w2tab();

typedef __attribute__((ext_vector_type(8))) __bf16 bf16x8;
typedef __attribute__((ext_vector_type(8))) unsigned short ushort8;
typedef __attribute__((ext_vector_type(4))) float f32x4;

__device__ __forceinline__ unsigned short f2bf(float f) {
  unsigned u = __builtin_bit_cast(unsigned, f);
  u += 0x7FFFu + ((u >> 16) & 1u);
  return (unsigned short)(u >> 16);
}
__device__ __forceinline__ float bf2f(unsigned short h) {
  return __builtin_bit_cast(float, (unsigned)h << 16);
}

// ---------------- fwd: fused stage A + stage B + CFT H-pass, one block per (b,c) ----------------
// Round-10 restructure: (1) all 16 x-loads issued before any use (16-deep VMEM ILP);
// (2) A MFMA loop shares each B-fragment across both row-tiles (2 indep acc chains);
// (3) B-part uses dual accumulator chains (ks 0-3 / 4-7) summed at the end.
__global__ __launch_bounds__(256) void k_fwd(const float* __restrict__ x,
                                             float* __restrict__ xf,
                                             float* __restrict__ flat) {
  __shared__ float xwl[128][34];       // [h][j=2kx+u], pad 34 (2-way conflicts = free)
  __shared__ float cftl[128][9];
  __shared__ float cpart[8][33];
  int t = threadIdx.x;
  int lane = t & 63, wid = t >> 6;
  int bc = blockIdx.x;
  const float* xb = x + (size_t)bc * 16384;
  int r = lane & 15, kg = lane >> 4;
  const float* a0 = xb + (wid * 32 + r) * 128 + kg * 8;
  const float* a1 = a0 + 16 * 128;

  // ---- issue ALL 16 x-loads up front ----
  float4 xa[16];
  #pragma unroll
  for (int ks = 0; ks < 4; ks++) {
    xa[2 * ks]     = *reinterpret_cast<const float4*>(a0 + ks * 32);
    xa[2 * ks + 1] = *reinterpret_cast<const float4*>(a0 + ks * 32 + 4);
  }
  #pragma unroll
  for (int ks = 0; ks < 4; ks++) {
    xa[8 + 2 * ks]     = *reinterpret_cast<const float4*>(a1 + ks * 32);
    xa[8 + 2 * ks + 1] = *reinterpret_cast<const float4*>(a1 + ks * 32 + 4);
  }

  // ---- convert to split-bf16 fragments (both tiles) ----
  bf16x8 ahi[2][4], alo[2][4];
  #pragma unroll
  for (int tl = 0; tl < 2; tl++) {
    #pragma unroll
    for (int ks = 0; ks < 4; ks++) {
      const float* p0 = reinterpret_cast<const float*>(&xa[tl * 8 + 2 * ks]);
      const float* p1 = reinterpret_cast<const float*>(&xa[tl * 8 + 2 * ks + 1]);
      ushort8 hu, lu;
      #pragma unroll
      for (int j = 0; j < 8; j++) {
        float v = (j < 4) ? p0[j] : p1[j - 4];
        unsigned short h = f2bf(v);
        hu[j] = h;
        lu[j] = f2bf(v - bf2f(h));
      }
      ahi[tl][ks] = __builtin_bit_cast(bf16x8, hu);
      alo[tl][ks] = __builtin_bit_cast(bf16x8, lu);
    }
  }

  // ---- A MFMA: share B-fragments across both tiles (2 indep chains/jt) ----
  f32x4 acc[2][3];
  #pragma unroll
  for (int tl = 0; tl < 2; tl++)
    #pragma unroll
    for (int jt = 0; jt < 3; jt++) acc[tl][jt] = f32x4{0.f, 0.f, 0.f, 0.f};
  #pragma unroll
  for (int jt = 0; jt < 3; jt++) {
    #pragma unroll
    for (int ks = 0; ks < 4; ks++) {
      bf16x8 bhi = __builtin_bit_cast(bf16x8,
          *reinterpret_cast<const ushort8*>(&g_btab.v[ks][0][jt][lane][0]));
      bf16x8 blo = __builtin_bit_cast(bf16x8,
          *reinterpret_cast<const ushort8*>(&g_btab.v[ks][1][jt][lane][0]));
      acc[0][jt] = __builtin_amdgcn_mfma_f32_16x16x32_bf16(ahi[0][ks], bhi, acc[0][jt], 0, 0, 0);
      acc[1][jt] = __builtin_amdgcn_mfma_f32_16x16x32_bf16(ahi[1][ks], bhi, acc[1][jt], 0, 0, 0);
      acc[0][jt] = __builtin_amdgcn_mfma_f32_16x16x32_bf16(alo[0][ks], bhi, acc[0][jt], 0, 0, 0);
      acc[1][jt] = __builtin_amdgcn_mfma_f32_16x16x32_bf16(alo[1][ks], bhi, acc[1][jt], 0, 0, 0);
      acc[0][jt] = __builtin_amdgcn_mfma_f32_16x16x32_bf16(ahi[0][ks], blo, acc[0][jt], 0, 0, 0);
      acc[1][jt] = __builtin_amdgcn_mfma_f32_16x16x32_bf16(ahi[1][ks], blo, acc[1][jt], 0, 0, 0);
    }
  }
  {
    int col = lane & 15, rq = lane >> 4;
    #pragma unroll
    for (int tl = 0; tl < 2; tl++) {
      int rt = wid * 2 + tl;
      #pragma unroll
      for (int jt = 0; jt < 3; jt++) {
        #pragma unroll
        for (int i = 0; i < 4; i++) {
          int rl = rt * 16 + rq * 4 + i;
          if (jt < 2) xwl[rl][jt * 16 + col] = acc[tl][jt][i];
          else if (col < 8) cftl[rl][col] = acc[tl][jt][i];
        }
      }
    }
  }
  __syncthreads();

  // ---- cft partial reduce (all 256 threads) ----
  {
    int o = t & 31, seg = t >> 5;
    int f1 = o >> 3, f2 = (o >> 1) & 3, ri = o & 1;
    float acc2 = 0.f;
    #pragma unroll
    for (int hh = 0; hh < 16; hh++) {
      int h = seg * 16 + hh;
      float rr = cftl[h][f2], im = cftl[h][4 + f2];
      float kr = g_cfth.v[h][f1], ki = g_cfth.v[h][4 + f1];
      float e0 = ri ? ki : kr;
      float e1 = ri ? kr : -ki;
      acc2 = fmaf(rr, e0, fmaf(im, e1, acc2));
    }
    cpart[seg][o] = acc2;
  }

  // ---- B-part: wave wid owns m-tile wid; dual acc chains ----
  {
    int kx = lane & 15, g = lane >> 4;
    f32x4 accA = {0.f, 0.f, 0.f, 0.f};
    f32x4 accB = {0.f, 0.f, 0.f, 0.f};
    #pragma unroll
    for (int ks2 = 0; ks2 < 4; ks2++) {
      #pragma unroll
      for (int half = 0; half < 2; half++) {
        int ks = half * 4 + ks2;
        int h0 = ks * 16 + g * 4;
        ushort8 bhU, blU;
        #pragma unroll
        for (int rr = 0; rr < 4; rr++) {
          float2 p = *reinterpret_cast<const float2*>(&xwl[h0 + rr][2 * kx]);
          unsigned short hx = f2bf(p.x);
          bhU[2 * rr] = hx; blU[2 * rr] = f2bf(p.x - bf2f(hx));
          unsigned short hy = f2bf(p.y);
          bhU[2 * rr + 1] = hy; blU[2 * rr + 1] = f2bf(p.y - bf2f(hy));
        }
        bf16x8 bhi = __builtin_bit_cast(bf16x8, bhU);
        bf16x8 blo = __builtin_bit_cast(bf16x8, blU);
        bf16x8 thi = __builtin_bit_cast(bf16x8,
            *reinterpret_cast<const ushort8*>(&g_tbtab.v[wid][ks][0][lane][0]));
        bf16x8 tlo = __builtin_bit_cast(bf16x8,
            *reinterpret_cast<const ushort8*>(&g_tbtab.v[wid][ks][1][lane][0]));
        f32x4& acc3 = half ? accB : accA;
        acc3 = __builtin_amdgcn_mfma_f32_16x16x32_bf16(thi, bhi, acc3, 0, 0, 0);
        acc3 = __builtin_amdgcn_mfma_f32_16x16x32_bf16(tlo, bhi, acc3, 0, 0, 0);
        acc3 = __builtin_amdgcn_mfma_f32_16x16x32_bf16(thi, blo, acc3, 0, 0, 0);
      }
    }
    f32x4 accS = accA + accB;
    #pragma unroll
    for (int i = 0; i < 4; i++) {
      int m = wid * 16 + (lane >> 4) * 4 + i;
      int j = m & 31, ri = m >> 5;
      xf[((size_t)bc * 32 + j) * 32 + kx * 2 + ri] = accS[i];
    }
  }
  __syncthreads();

  if (t < 32) {
    float s = 0.f;
    #pragma unroll
    for (int seg = 0; seg < 8; seg++) s += cpart[seg][t];
    int b = bc >> 6, c = bc & 63;
    int f1 = t >> 3, f2 = (t >> 1) & 3, ri = t & 1;
    flat[(size_t)b * 2048 + ((c * 4 + f1) * 4 + f2) * 2 + ri] = s;
  }
}

// ---------------- MLP stage 1: flat -> hs ----------------
__global__ __launch_bounds__(256) void k_mlp1(const float* __restrict__ flat,
                                              const float* __restrict__ w1,
                                              const float* __restrict__ b1,
                                              float* __restrict__ hs) {
  __shared__ float part[4][64];
  int bid = blockIdx.x;
  int b = bid >> 2, oc = bid & 3;
  int t = threadIdx.x;
  int ol = t & 63, kc = t >> 6;
  int o = oc * 64 + ol;
  const float* fb = flat + (size_t)b * 2048 + kc * 512;
  const float* wb = w1 + (size_t)(kc * 512) * 256 + o;
  float acc = 0.f;
  for (int k = 0; k < 512; k++) acc = fmaf(fb[k], wb[(size_t)k * 256], acc);
  part[kc][ol] = acc;
  __syncthreads();
  if (t < 64) {
    float a = part[0][t] + part[1][t] + part[2][t] + part[3][t] + b1[oc * 64 + t];
    hs[(size_t)b * 256 + oc * 64 + t] = 0.5f * a * (1.0f + erff(a * 0.70710678118654752f));
  }
}

// ---------------- MLP stage 2: hs -> corr ----------------
__global__ void k_mlp2(const float* __restrict__ hs,
                       const float* __restrict__ w2,
                       const float* __restrict__ b2,
                       float* __restrict__ corr) {
  int b = blockIdx.x, t = threadIdx.x;   // 64 threads
  const float* hb = hs + (size_t)b * 256;
  float acc = b2[t];
  for (int k = 0; k < 256; k++) acc = fmaf(hb[k], w2[(size_t)k * 64 + t], acc);
  corr[(size_t)b * 64 + t] = acc;
}

// ---------------- stage C: mode-mixing einsum over C ----------------
__global__ __launch_bounds__(256) void k_stageC(const float* __restrict__ xf,
                                                const float* __restrict__ w1,
                                                const float* __restrict__ w2,
                                                float* __restrict__ outft) {
  __shared__ float xfs[64 * 32];       // [c][kx*2+ri]
  int bid = blockIdx.x;
  int sw = (bid & 7) * 128 + (bid >> 3);   // bijective (1024 % 8 == 0)
  int j = sw >> 5, b = sw & 31;
  int t = threadIdx.x;
  #pragma unroll
  for (int k2 = 0; k2 < 4; k2++) {
    int id = t + k2 * 256;             // 1024 float2
    int c = id >> 4, kxi = id & 15;
    const float2 v = *reinterpret_cast<const float2*>(
        xf + (((size_t)b * 64 + c) * 32 + j) * 32 + kxi * 2);
    reinterpret_cast<float2*>(xfs)[id] = v;
  }
  __syncthreads();
  int kx = t & 15, og = t >> 4;
  const float* wsel = (j < 16) ? w1 : w2;
  int jr = (j < 16) ? j : j - 16;
  float aR[4], aI[4];
  #pragma unroll
  for (int i = 0; i < 4; i++) { aR[i] = 0.f; aI[i] = 0.f; }
  for (int c = 0; c < 64; c++) {
    float xr = xfs[c * 32 + kx * 2], xi = xfs[c * 32 + kx * 2 + 1];
    #pragma unroll
    for (int i = 0; i < 4; i++) {
      int o = og * 4 + i;
      const float2 wv = *reinterpret_cast<const float2*>(
          wsel + ((((size_t)c * 64 + o) * 16 + jr) * 16 + kx) * 2);
      aR[i] = fmaf(xr, wv.x, fmaf(-xi, wv.y, aR[i]));
      aI[i] = fmaf(xr, wv.y, fmaf(xi, wv.x, aI[i]));
    }
  }
  int boff = (j >> 4) * 512 + ((((j >> 2) & 3) << 4) | kx) * 8 + (j & 3) * 2;
  #pragma unroll
  for (int i = 0; i < 4; i++) {
    int o = og * 4 + i;
    float2* dst = reinterpret_cast<float2*>(outft + (size_t)(b * 64 + o) * 1024 + boff);
    *dst = make_float2(aR[i], aI[i]);
  }
}

// ---------------- stage DE: two chained split-bf16 MFMA GEMMs per (b,o) ----------------
__global__ __launch_bounds__(256) void k_stageDE(const float* __restrict__ outft,
                                                 const float* __restrict__ corr,
                                                 float* __restrict__ out) {
  __shared__ float Yl[256 * 17];
  int t = threadIdx.x;
  int lane = t & 63, wid = t >> 6;
  int bo = blockIdx.x;
  const float* src = outft + (size_t)bo * 1024;

  bf16x8 shi[2], slo[2];
  #pragma unroll
  for (int ks = 0; ks < 2; ks++) {
    float4 v0 = *reinterpret_cast<const float4*>(src + ks * 512 + lane * 8);
    float4 v1 = *reinterpret_cast<const float4*>(src + ks * 512 + lane * 8 + 4);
    float xv[8] = {v0.x, v0.y, v0.z, v0.w, v1.x, v1.y, v1.z, v1.w};
    ushort8 hu, lu;
    #pragma unroll
    for (int j = 0; j < 8; j++) {
      unsigned short h = f2bf(xv[j]);
      hu[j] = h;
      lu[j] = f2bf(xv[j] - bf2f(h));
    }
    shi[ks] = __builtin_bit_cast(bf16x8, hu);
    slo[ks] = __builtin_bit_cast(bf16x8, lu);
  }

  #pragma unroll
  for (int mtl = 0; mtl < 4; mtl++) {
    int mt = wid * 4 + mtl;
    f32x4 acc = {0.f, 0.f, 0.f, 0.f};
    #pragma unroll
    for (int ks = 0; ks < 2; ks++) {
      bf16x8 whi = __builtin_bit_cast(bf16x8,
          *reinterpret_cast<const ushort8*>(&g_w1tab.v[mt][ks][0][lane][0]));
      bf16x8 wlo = __builtin_bit_cast(bf16x8,
          *reinterpret_cast<const ushort8*>(&g_w1tab.v[mt][ks][1][lane][0]));
      acc = __builtin_amdgcn_mfma_f32_16x16x32_bf16(whi, shi[ks], acc, 0, 0, 0);
      acc = __builtin_amdgcn_mfma_f32_16x16x32_bf16(wlo, shi[ks], acc, 0, 0, 0);
      acc = __builtin_amdgcn_mfma_f32_16x16x32_bf16(whi, slo[ks], acc, 0, 0, 0);
    }
    #pragma unroll
    for (int i = 0; i < 4; i++)
      Yl[(mt * 16 + (lane >> 4) * 4 + i) * 17 + (lane & 15)] = acc[i];
  }
  __syncthreads();

  float corrv = corr[bo];
  float* obase = out + (size_t)bo * 16384;

  #pragma unroll
  for (int mtl = 0; mtl < 2; mtl++) {
    int mt2 = wid * 2 + mtl;
    int h = mt2 * 16 + (lane & 15);
    ushort8 ahiU, aloU;
    #pragma unroll
    for (int j = 0; j < 8; j++) {
      int k = (lane >> 4) * 8 + j;
      float v = Yl[((k & 1) * 128 + h) * 17 + (k >> 1)];
      unsigned short hi = f2bf(v);
      ahiU[j] = hi;
      aloU[j] = f2bf(v - bf2f(hi));
    }
    bf16x8 ahi = __builtin_bit_cast(bf16x8, ahiU);
    bf16x8 alo = __builtin_bit_cast(bf16x8, aloU);
    #pragma unroll
    for (int nt = 0; nt < 8; nt++) {
      bf16x8 bhi = __builtin_bit_cast(bf16x8,
          *reinterpret_cast<const ushort8*>(&g_w2tab.v[nt][0][lane][0]));
      bf16x8 blo = __builtin_bit_cast(bf16x8,
          *reinterpret_cast<const ushort8*>(&g_w2tab.v[nt][1][lane][0]));
      f32x4 acc = {corrv, corrv, corrv, corrv};
      acc = __builtin_amdgcn_mfma_f32_16x16x32_bf16(ahi, bhi, acc, 0, 0, 0);
      acc = __builtin_amdgcn_mfma_f32_16x16x32_bf16(alo, bhi, acc, 0, 0, 0);
      acc = __builtin_amdgcn_mfma_f32_16x16x32_bf16(ahi, blo, acc, 0, 0, 0);
      #pragma unroll
      for (int i = 0; i < 4; i++)
        obase[(mt2 * 16 + (lane >> 4) * 4 + i) * 128 + nt * 16 + (lane & 15)] = acc[i];
    }
  }
}

extern "C" void kernel_launch(void* const* d_in, const int* in_sizes, int n_in,
                              void* d_out, int out_size, void* d_ws, size_t ws_size,
                              hipStream_t stream) {
  const float* x   = (const float*)d_in[0];
  const float* w1  = (const float*)d_in[1];
  const float* w2  = (const float*)d_in[2];
  const float* l1w = (const float*)d_in[3];
  const float* l1b = (const float*)d_in[4];
  const float* l2w = (const float*)d_in[5];
  const float* l2b = (const float*)d_in[6];
  float* out = (float*)d_out;
  float* ws  = (float*)d_ws;

  float* flat  = ws + WSO_FLAT;
  float* corr  = ws + WSO_CORR;
  float* hs    = ws + WSO_HS;
  float* xf    = ws + WSO_XF;
  float* outft = ws + WSO_OUTFT;

  k_fwd<<<dim3(2048), dim3(256), 0, stream>>>(x, xf, flat);
  k_mlp1<<<dim3(128), dim3(256), 0, stream>>>(flat, l1w, l1b, hs);
  k_mlp2<<<dim3(32), dim3(64), 0, stream>>>(hs, l2w, l2b, corr);
  k_stageC<<<dim3(1024), dim3(256), 0, stream>>>(xf, w1, w2, outft);
  k_stageDE<<<dim3(2048), dim3(256), 0, stream>>>(outft, corr, out);
}